// Round 1
// baseline (3568.211 us; speedup 1.0000x reference)
//
#include <hip/hip_runtime.h>

#define EPSN   1e-5f
#define NEGS   0.2f
#define NHEADS 4
#define NGRAPH 64

// ---------- helpers ----------
__device__ __forceinline__ unsigned fenc(float f) {
    unsigned u = __float_as_uint(f);
    return (u & 0x80000000u) ? ~u : (u | 0x80000000u);
}
__device__ __forceinline__ float fdec(unsigned u) {
    return (u & 0x80000000u) ? __uint_as_float(u & 0x7fffffffu)
                             : __uint_as_float(~u);
}
__device__ __forceinline__ void edge_st(const int* __restrict__ es,
                                        const int* __restrict__ ed,
                                        int e, int E, int& s, int& t) {
    if (e < E) { s = es[e]; t = ed[e]; }
    else       { s = t = e - E; }          // self-loop
}

// ---------- degree / norm ----------
__global__ void k_init_deg(int* __restrict__ deg, int n) {
    for (int i = blockIdx.x * blockDim.x + threadIdx.x; i < n;
         i += gridDim.x * blockDim.x)
        deg[i] = 1;  // self-loop
}
__global__ void k_deg(const int* __restrict__ dst, int* __restrict__ deg, int E) {
    for (int e = blockIdx.x * blockDim.x + threadIdx.x; e < E;
         e += gridDim.x * blockDim.x)
        atomicAdd(&deg[dst[e]], 1);
}
__global__ void k_dinv(const int* __restrict__ deg, float* __restrict__ dinv, int n) {
    for (int i = blockIdx.x * blockDim.x + threadIdx.x; i < n;
         i += gridDim.x * blockDim.x)
        dinv[i] = rsqrtf((float)deg[i]);
}

// ---------- generic setters ----------
__global__ void k_setf(float* __restrict__ p, float v, long long n) {
    for (long long i = blockIdx.x * (long long)blockDim.x + threadIdx.x; i < n;
         i += (long long)gridDim.x * blockDim.x)
        p[i] = v;
}
__global__ void k_setu(unsigned* __restrict__ p, unsigned v, long long n) {
    for (long long i = blockIdx.x * (long long)blockDim.x + threadIdx.x; i < n;
         i += (long long)gridDim.x * blockDim.x)
        p[i] = v;
}

// ---------- dense matmul Y[n,M] = X[n,K] @ W[K,M] (W staged in LDS) ----------
template <int K, int M, int ROWS>
__global__ void k_matmul(const float* __restrict__ X, const float* __restrict__ W,
                         float* __restrict__ Y, int n) {
    __shared__ float Wl[K * M];
    for (int i = threadIdx.x; i < K * M; i += blockDim.x) Wl[i] = W[i];
    __syncthreads();
    const int col = threadIdx.x & (M - 1);
    const int r0  = threadIdx.x / M;
    const int NR  = 256 / M;
    const int base = blockIdx.x * ROWS;
    for (int r = r0; r < ROWS; r += NR) {
        int row = base + r;
        if (row >= n) break;
        const float* xr = X + (long long)row * K;
        float acc = 0.f;
#pragma unroll
        for (int k = 0; k < K; ++k) acc += xr[k] * Wl[k * M + col];
        Y[(long long)row * M + col] = acc;
    }
}

// ---------- init aggregation buffer with bias ----------
template <int M>
__global__ void k_initB(float* __restrict__ B, const float* __restrict__ b, int n) {
    long long total = (long long)n * M;
    for (long long i = blockIdx.x * (long long)blockDim.x + threadIdx.x; i < total;
         i += (long long)gridDim.x * blockDim.x)
        B[i] = b[(int)(i & (M - 1))];
}

// ---------- GCN edge aggregation: B[dst] += A[src]*norm ----------
template <int M, int LOGM>
__global__ void k_agg(const float* __restrict__ A, const int* __restrict__ es,
                      const int* __restrict__ ed, const float* __restrict__ dinv,
                      float* __restrict__ B, int E, int n) {
    long long total = (long long)(E + n) << LOGM;
    for (long long idx = blockIdx.x * (long long)blockDim.x + threadIdx.x; idx < total;
         idx += (long long)gridDim.x * blockDim.x) {
        int e = (int)(idx >> LOGM);
        int d = (int)(idx & (M - 1));
        int s, t;
        edge_st(es, ed, e, E, s, t);
        float norm = dinv[s] * dinv[t];
        atomicAdd(&B[t * M + d], A[s * M + d] * norm);
    }
}

// ---------- BN (inference) + ReLU in place ----------
template <int M>
__global__ void k_bnrelu(float* __restrict__ B, const float* __restrict__ g,
                         const float* __restrict__ be, const float* __restrict__ m,
                         const float* __restrict__ v, int n) {
    long long total = (long long)n * M;
    for (long long i = blockIdx.x * (long long)blockDim.x + threadIdx.x; i < total;
         i += (long long)gridDim.x * blockDim.x) {
        int d = (int)(i & (M - 1));
        float x = (B[i] - m[d]) * rsqrtf(v[d] + EPSN) * g[d] + be[d];
        B[i] = fmaxf(x, 0.f);
    }
}

// ---------- GAT attention coefficients a_s, a_d ----------
__global__ void k_att_sd(const float* __restrict__ hh, const float* __restrict__ ags,
                         const float* __restrict__ agd, float* __restrict__ a_s,
                         float* __restrict__ a_d, int n) {
    int total = n * NHEADS;
    for (int i = blockIdx.x * blockDim.x + threadIdx.x; i < total;
         i += gridDim.x * blockDim.x) {
        int ni = i >> 2, h = i & 3;
        const float* row = hh + ni * 128 + h * 32;
        float ss = 0.f, sd = 0.f;
#pragma unroll
        for (int d = 0; d < 32; ++d) {
            float x = row[d];
            ss += x * ags[h * 32 + d];
            sd += x * agd[h * 32 + d];
        }
        a_s[i] = ss;
        a_d[i] = sd;
    }
}

// ---------- segment max of leaky-relu scores ----------
__global__ void k_emax(const float* __restrict__ a_s, const float* __restrict__ a_d,
                       const int* __restrict__ es, const int* __restrict__ ed,
                       unsigned* __restrict__ emaxu, int E, int n) {
    long long total = (long long)(E + n) * 4;
    for (long long idx = blockIdx.x * (long long)blockDim.x + threadIdx.x; idx < total;
         idx += (long long)gridDim.x * blockDim.x) {
        int e = (int)(idx >> 2), h = (int)(idx & 3);
        int s, t;
        edge_st(es, ed, e, E, s, t);
        float ev = a_s[s * 4 + h] + a_d[t * 4 + h];
        ev = ev > 0.f ? ev : NEGS * ev;
        atomicMax(&emaxu[t * 4 + h], fenc(ev));
    }
}

// ---------- softmax denominator ----------
__global__ void k_den(const float* __restrict__ a_s, const float* __restrict__ a_d,
                      const int* __restrict__ es, const int* __restrict__ ed,
                      const unsigned* __restrict__ emaxu, float* __restrict__ den,
                      int E, int n) {
    long long total = (long long)(E + n) * 4;
    for (long long idx = blockIdx.x * (long long)blockDim.x + threadIdx.x; idx < total;
         idx += (long long)gridDim.x * blockDim.x) {
        int e = (int)(idx >> 2), h = (int)(idx & 3);
        int s, t;
        edge_st(es, ed, e, E, s, t);
        float ev = a_s[s * 4 + h] + a_d[t * 4 + h];
        ev = ev > 0.f ? ev : NEGS * ev;
        atomicAdd(&den[t * 4 + h], expf(ev - fdec(emaxu[t * 4 + h])));
    }
}

// ---------- attention-weighted aggregation ----------
__global__ void k_gat_agg(const float* __restrict__ hh, const float* __restrict__ a_s,
                          const float* __restrict__ a_d,
                          const unsigned* __restrict__ emaxu,
                          const float* __restrict__ den, const int* __restrict__ es,
                          const int* __restrict__ ed, float* __restrict__ B, int E,
                          int n) {
    long long total = (long long)(E + n) << 7;
    for (long long idx = blockIdx.x * (long long)blockDim.x + threadIdx.x; idx < total;
         idx += (long long)gridDim.x * blockDim.x) {
        int e = (int)(idx >> 7);
        int d = (int)(idx & 127);
        int h = d >> 5;
        int s, t;
        edge_st(es, ed, e, E, s, t);
        float ev = a_s[s * 4 + h] + a_d[t * 4 + h];
        ev = ev > 0.f ? ev : NEGS * ev;
        float att = expf(ev - fdec(emaxu[t * 4 + h])) / den[t * 4 + h];
        atomicAdd(&B[t * 128 + d], att * hh[s * 128 + d]);
    }
}

// ---------- head mean + bias + relu ----------
__global__ void k_gat_final(const float* __restrict__ Bagg, const float* __restrict__ bg,
                            float* __restrict__ out, int n) {
    long long total = (long long)n * 32;
    for (long long i = blockIdx.x * (long long)blockDim.x + threadIdx.x; i < total;
         i += (long long)gridDim.x * blockDim.x) {
        int ni = (int)(i >> 5), d = (int)(i & 31);
        const float* r = Bagg + ni * 128;
        float v = 0.25f * (r[d] + r[32 + d] + r[64 + d] + r[96 + d]) + bg[d];
        out[i] = fmaxf(v, 0.f);
    }
}

// ---------- graph mean pool ----------
__global__ void k_pool_init(float* __restrict__ pooled, float* __restrict__ cnt) {
    int i = blockIdx.x * blockDim.x + threadIdx.x;
    if (i < NGRAPH * 32) pooled[i] = 0.f;
    if (i < NGRAPH) cnt[i] = 0.f;
}
__global__ void k_pool(const float* __restrict__ h, const int* __restrict__ batch,
                       float* __restrict__ pooled, float* __restrict__ cnt, int n) {
    long long total = (long long)n * 32;
    for (long long i = blockIdx.x * (long long)blockDim.x + threadIdx.x; i < total;
         i += (long long)gridDim.x * blockDim.x) {
        int ni = (int)(i >> 5), d = (int)(i & 31);
        int b = batch[ni];
        atomicAdd(&pooled[b * 32 + d], h[i]);
        if (d == 0) atomicAdd(&cnt[b], 1.f);
    }
}

// ---------- classifier on one block ----------
__global__ void k_classifier(const float* __restrict__ pooled, const float* __restrict__ cnt,
                             const float* __restrict__ Wc1, const float* __restrict__ bc1,
                             const float* __restrict__ Wc2, const float* __restrict__ bc2,
                             float* __restrict__ out) {
    __shared__ float pl[NGRAPH * 32];
    __shared__ float t1[NGRAPH * 16];
    int tid = threadIdx.x;
    for (int i = tid; i < NGRAPH * 32; i += blockDim.x) {
        int g = i >> 5;
        pl[i] = pooled[i] / fmaxf(cnt[g], 1.f);
    }
    __syncthreads();
    for (int i = tid; i < NGRAPH * 16; i += blockDim.x) {
        int g = i >> 4, c = i & 15;
        float acc = bc1[c];
#pragma unroll
        for (int d = 0; d < 32; ++d) acc += pl[g * 32 + d] * Wc1[d * 16 + c];
        t1[i] = fmaxf(acc, 0.f);
    }
    __syncthreads();
    for (int i = tid; i < NGRAPH * 5; i += blockDim.x) {
        int g = i / 5, c = i % 5;
        float acc = bc2[c];
#pragma unroll
        for (int k = 0; k < 16; ++k) acc += t1[g * 16 + k] * Wc2[k * 5 + c];
        out[i] = acc;
    }
}

// ---------- launch ----------
static inline dim3 gsz(long long work, int block = 256) {
    long long g = (work + block - 1) / block;
    if (g > 262144) g = 262144;
    if (g < 1) g = 1;
    return dim3((unsigned)g);
}

extern "C" void kernel_launch(void* const* d_in, const int* in_sizes, int n_in,
                              void* d_out, int out_size, void* d_ws, size_t ws_size,
                              hipStream_t stream) {
    const float* x     = (const float*)d_in[0];
    const int*   ei    = (const int*)d_in[1];
    const int*   batch = (const int*)d_in[2];
    const float* W1 = (const float*)d_in[3];  const float* b1 = (const float*)d_in[4];
    const float* W2 = (const float*)d_in[5];  const float* b2 = (const float*)d_in[6];
    const float* W3 = (const float*)d_in[7];  const float* b3 = (const float*)d_in[8];
    const float* g1 = (const float*)d_in[9];  const float* be1 = (const float*)d_in[10];
    const float* m1 = (const float*)d_in[11]; const float* v1  = (const float*)d_in[12];
    const float* g2 = (const float*)d_in[13]; const float* be2 = (const float*)d_in[14];
    const float* m2 = (const float*)d_in[15]; const float* v2  = (const float*)d_in[16];
    const float* g3 = (const float*)d_in[17]; const float* be3 = (const float*)d_in[18];
    const float* m3 = (const float*)d_in[19]; const float* v3  = (const float*)d_in[20];
    const float* Wg  = (const float*)d_in[21];
    const float* ags = (const float*)d_in[22];
    const float* agd = (const float*)d_in[23];
    const float* bg  = (const float*)d_in[24];
    const float* Wc1 = (const float*)d_in[25]; const float* bc1 = (const float*)d_in[26];
    const float* Wc2 = (const float*)d_in[27]; const float* bc2 = (const float*)d_in[28];
    float* out = (float*)d_out;

    const int N = in_sizes[0] / 64;
    const int E = in_sizes[1] / 2;
    const int* esrc = ei;
    const int* edst = ei + E;

    // workspace carve-out (256B aligned)
    size_t off = 0;
    auto take = [&](size_t bytes) -> void* {
        void* p = (char*)d_ws + off;
        off += bytes;
        off = (off + 255) & ~(size_t)255;
        return p;
    };
    int*      deg    = (int*)take((size_t)N * 4);
    float*    dinv   = (float*)take((size_t)N * 4);
    float*    A      = (float*)take((size_t)N * 128 * 4);
    float*    B      = (float*)take((size_t)N * 128 * 4);
    float*    a_s    = (float*)take((size_t)N * 4 * 4);
    float*    a_d    = (float*)take((size_t)N * 4 * 4);
    unsigned* emaxu  = (unsigned*)take((size_t)N * 4 * 4);
    float*    den    = (float*)take((size_t)N * 4 * 4);
    float*    pooled = (float*)take((size_t)NGRAPH * 32 * 4);
    float*    cnt    = (float*)take((size_t)NGRAPH * 4);
    (void)ws_size; (void)n_in; (void)out_size;

    const int B256 = 256;
    // degrees / norm
    hipLaunchKernelGGL(k_init_deg, gsz(N), dim3(B256), 0, stream, deg, N);
    hipLaunchKernelGGL(k_deg, gsz(E), dim3(B256), 0, stream, edst, deg, E);
    hipLaunchKernelGGL(k_dinv, gsz(N), dim3(B256), 0, stream, deg, dinv, N);

    // GCN layer 1: 64 -> 128
    hipLaunchKernelGGL((k_matmul<64, 128, 16>), dim3((N + 15) / 16), dim3(B256), 0, stream, x, W1, A, N);
    hipLaunchKernelGGL((k_initB<128>), gsz((long long)N * 128), dim3(B256), 0, stream, B, b1, N);
    hipLaunchKernelGGL((k_agg<128, 7>), gsz((long long)(E + N) * 128), dim3(B256), 0, stream, A, esrc, edst, dinv, B, E, N);
    hipLaunchKernelGGL((k_bnrelu<128>), gsz((long long)N * 128), dim3(B256), 0, stream, B, g1, be1, m1, v1, N);

    // GCN layer 2: 128 -> 64
    hipLaunchKernelGGL((k_matmul<128, 64, 16>), dim3((N + 15) / 16), dim3(B256), 0, stream, B, W2, A, N);
    hipLaunchKernelGGL((k_initB<64>), gsz((long long)N * 64), dim3(B256), 0, stream, B, b2, N);
    hipLaunchKernelGGL((k_agg<64, 6>), gsz((long long)(E + N) * 64), dim3(B256), 0, stream, A, esrc, edst, dinv, B, E, N);
    hipLaunchKernelGGL((k_bnrelu<64>), gsz((long long)N * 64), dim3(B256), 0, stream, B, g2, be2, m2, v2, N);

    // GCN layer 3: 64 -> 32
    hipLaunchKernelGGL((k_matmul<64, 32, 16>), dim3((N + 15) / 16), dim3(B256), 0, stream, B, W3, A, N);
    hipLaunchKernelGGL((k_initB<32>), gsz((long long)N * 32), dim3(B256), 0, stream, B, b3, N);
    hipLaunchKernelGGL((k_agg<32, 5>), gsz((long long)(E + N) * 32), dim3(B256), 0, stream, A, esrc, edst, dinv, B, E, N);
    hipLaunchKernelGGL((k_bnrelu<32>), gsz((long long)N * 32), dim3(B256), 0, stream, B, g3, be3, m3, v3, N);

    // GAT: hh = h3 @ Wg  (N x 128), heads=4 x 32
    hipLaunchKernelGGL((k_matmul<32, 128, 16>), dim3((N + 15) / 16), dim3(B256), 0, stream, B, Wg, A, N);
    hipLaunchKernelGGL(k_att_sd, gsz((long long)N * 4), dim3(B256), 0, stream, A, ags, agd, a_s, a_d, N);
    hipLaunchKernelGGL(k_setu, gsz((long long)N * 4), dim3(B256), 0, stream, emaxu, 0u, (long long)N * 4);
    hipLaunchKernelGGL(k_emax, gsz((long long)(E + N) * 4), dim3(B256), 0, stream, a_s, a_d, esrc, edst, emaxu, E, N);
    hipLaunchKernelGGL(k_setf, gsz((long long)N * 4), dim3(B256), 0, stream, den, 0.f, (long long)N * 4);
    hipLaunchKernelGGL(k_den, gsz((long long)(E + N) * 4), dim3(B256), 0, stream, a_s, a_d, esrc, edst, emaxu, den, E, N);
    hipLaunchKernelGGL(k_setf, gsz((long long)N * 128), dim3(B256), 0, stream, B, 0.f, (long long)N * 128);
    hipLaunchKernelGGL(k_gat_agg, gsz((long long)(E + N) * 128), dim3(B256), 0, stream, A, a_s, a_d, emaxu, den, esrc, edst, B, E, N);
    hipLaunchKernelGGL(k_gat_final, gsz((long long)N * 32), dim3(B256), 0, stream, B, bg, A, N);

    // pool + classifier
    hipLaunchKernelGGL(k_pool_init, dim3(9), dim3(B256), 0, stream, pooled, cnt);
    hipLaunchKernelGGL(k_pool, gsz((long long)N * 32), dim3(B256), 0, stream, A, batch, pooled, cnt, N);
    hipLaunchKernelGGL(k_classifier, dim3(1), dim3(B256), 0, stream, pooled, cnt, Wc1, bc1, Wc2, bc2, out);
}

// Round 2
// 1348.266 us; speedup vs baseline: 2.6465x; 2.6465x over previous
//
#include <hip/hip_runtime.h>

#define EPSN   1e-5f
#define NEGS   0.2f
#define NGRAPH 64

// ================= degree / norm =================
__global__ void k_init_deg(int* __restrict__ deg, int n) {
    for (int i = blockIdx.x * blockDim.x + threadIdx.x; i < n;
         i += gridDim.x * blockDim.x)
        deg[i] = 1;  // self-loop
}
__global__ void k_deg(const int* __restrict__ dst, int* __restrict__ deg, int E) {
    for (int e = blockIdx.x * blockDim.x + threadIdx.x; e < E;
         e += gridDim.x * blockDim.x)
        atomicAdd(&deg[dst[e]], 1);
}
__global__ void k_dinv(const int* __restrict__ deg, float* __restrict__ dinv, int n) {
    for (int i = blockIdx.x * blockDim.x + threadIdx.x; i < n;
         i += gridDim.x * blockDim.x)
        dinv[i] = rsqrtf((float)deg[i]);
}

// ================= exclusive scan (3-phase) =================
__global__ void k_scan_block(const int* __restrict__ deg, int* __restrict__ part,
                             int* __restrict__ bsum, int n) {
    __shared__ int tmp[256];
    int gid = blockIdx.x * 256 + threadIdx.x;
    int v = (gid < n) ? deg[gid] : 0;
    tmp[threadIdx.x] = v;
    __syncthreads();
    for (int off = 1; off < 256; off <<= 1) {
        int t = (threadIdx.x >= off) ? tmp[threadIdx.x - off] : 0;
        __syncthreads();
        tmp[threadIdx.x] += t;
        __syncthreads();
    }
    if (gid < n) part[gid] = tmp[threadIdx.x] - v;  // exclusive
    if (threadIdx.x == 255) bsum[blockIdx.x] = tmp[255];
}
// single block, nb <= 512
__global__ void k_scan_bsum(int* __restrict__ bsum, int nb) {
    __shared__ int tmp[512];
    int tid = threadIdx.x;
    int v = (tid < nb) ? bsum[tid] : 0;
    tmp[tid] = v;
    __syncthreads();
    for (int off = 1; off < 512; off <<= 1) {
        int t = (tid >= off) ? tmp[tid - off] : 0;
        __syncthreads();
        tmp[tid] += t;
        __syncthreads();
    }
    if (tid < nb) bsum[tid] = tmp[tid] - v;  // exclusive
}
__global__ void k_scan_add(const int* __restrict__ part, const int* __restrict__ bsum,
                           int* __restrict__ rowptr, int* __restrict__ cursor, int n) {
    int gid = blockIdx.x * 256 + threadIdx.x;
    if (gid < n) {
        int v = part[gid] + bsum[blockIdx.x];
        rowptr[gid] = v;
        cursor[gid] = v;
    }
}
// scatter edges (+self-loops) into dst-sorted CSR
__global__ void k_scatter(const int* __restrict__ es, const int* __restrict__ ed,
                          int* __restrict__ cursor, int* __restrict__ csrc,
                          int E, int n) {
    int total = E + n;
    for (int e = blockIdx.x * blockDim.x + threadIdx.x; e < total;
         e += gridDim.x * blockDim.x) {
        int s, t;
        if (e < E) { s = es[e]; t = ed[e]; }
        else       { s = t = e - E; }
        int pos = atomicAdd(&cursor[t], 1);
        csrc[pos] = s;
    }
}

// ================= dense matmul Y[n,M] = X[n,K] @ W[K,M] =================
template <int K, int M, int ROWS>
__global__ void k_matmul(const float* __restrict__ X, const float* __restrict__ W,
                         float* __restrict__ Y, int n) {
    __shared__ float Wl[K * M];
    for (int i = threadIdx.x; i < K * M; i += blockDim.x) Wl[i] = W[i];
    __syncthreads();
    const int col = threadIdx.x & (M - 1);
    const int r0  = threadIdx.x / M;
    const int NR  = 256 / M;
    const int base = blockIdx.x * ROWS;
    for (int r = r0; r < ROWS; r += NR) {
        int row = base + r;
        if (row >= n) break;
        const float* xr = X + (long long)row * K;
        float acc = 0.f;
#pragma unroll
        for (int k = 0; k < K; ++k) acc += xr[k] * Wl[k * M + col];
        Y[(long long)row * M + col] = acc;
    }
}

// ================= CSR GCN aggregation + bias + BN + ReLU fused =================
// one node per LANES lanes; VPT values per lane
template <int M>
__global__ void k_agg_csr(const float* __restrict__ A, const int* __restrict__ rowptr,
                          const int* __restrict__ deg, const int* __restrict__ csrc,
                          const float* __restrict__ dinv,
                          const float* __restrict__ b, const float* __restrict__ g,
                          const float* __restrict__ be, const float* __restrict__ m,
                          const float* __restrict__ v,
                          float* __restrict__ B, int n) {
    const int LANES = (M < 64) ? M : 64;
    const int VPT   = (M + LANES - 1) / LANES;
    const int NPB   = 256 / LANES;
    int node = blockIdx.x * NPB + threadIdx.x / LANES;
    if (node >= n) return;
    int lane = threadIdx.x % LANES;
    float acc[VPT];
#pragma unroll
    for (int k = 0; k < VPT; ++k) acc[k] = 0.f;
    int start = rowptr[node];
    int cnt   = deg[node];
    float di_t = dinv[node];
    for (int i = 0; i < cnt; ++i) {
        int s = csrc[start + i];
        float w = di_t * dinv[s];
        const float* row = A + (long long)s * M;
#pragma unroll
        for (int k = 0; k < VPT; ++k) acc[k] += w * row[lane + LANES * k];
    }
#pragma unroll
    for (int k = 0; k < VPT; ++k) {
        int d = lane + LANES * k;
        float x = acc[k] + b[d];
        x = (x - m[d]) * rsqrtf(v[d] + EPSN) * g[d] + be[d];
        B[(long long)node * M + d] = fmaxf(x, 0.f);
    }
}

// ================= GAT attention coefficients =================
__global__ void k_att_sd(const float* __restrict__ hh, const float* __restrict__ ags,
                         const float* __restrict__ agd, float* __restrict__ a_s,
                         float* __restrict__ a_d, int n) {
    int total = n * 4;
    for (int i = blockIdx.x * blockDim.x + threadIdx.x; i < total;
         i += gridDim.x * blockDim.x) {
        int ni = i >> 2, h = i & 3;
        const float* row = hh + (long long)ni * 128 + h * 32;
        float ss = 0.f, sd = 0.f;
#pragma unroll
        for (int d = 0; d < 32; ++d) {
            float x = row[d];
            ss += x * ags[h * 32 + d];
            sd += x * agd[h * 32 + d];
        }
        a_s[i] = ss;
        a_d[i] = sd;
    }
}

// ================= GAT: online softmax + agg + head-mean + bias + ReLU =================
// one wave per node; lane -> (h0=lane>>5, d=lane&31) and (h1=h0+2, d)
__global__ void k_gat_csr(const float* __restrict__ hh, const float* __restrict__ a_s,
                          const float* __restrict__ a_d, const int* __restrict__ rowptr,
                          const int* __restrict__ deg, const int* __restrict__ csrc,
                          const float* __restrict__ bg, float* __restrict__ out, int n) {
    int node = blockIdx.x * 4 + (threadIdx.x >> 6);
    if (node >= n) return;
    int lane = threadIdx.x & 63;
    int d = lane & 31;
    int h0 = lane >> 5;      // 0 or 1
    int h1 = h0 + 2;         // 2 or 3
    float ad0 = a_d[node * 4 + h0];
    float ad1 = a_d[node * 4 + h1];
    int start = rowptr[node];
    int cnt   = deg[node];
    float m0 = -1e30f, l0 = 0.f, acc0 = 0.f;
    float m1 = -1e30f, l1 = 0.f, acc1 = 0.f;
    for (int i = 0; i < cnt; ++i) {
        int s = csrc[start + i];
        const float* row = hh + (long long)s * 128;
        float x0 = row[lane];        // h0*32+d == lane
        float x1 = row[64 + lane];   // h1*32+d == 64+lane
        float e0 = a_s[s * 4 + h0] + ad0; e0 = e0 > 0.f ? e0 : NEGS * e0;
        float e1 = a_s[s * 4 + h1] + ad1; e1 = e1 > 0.f ? e1 : NEGS * e1;
        float nm0 = fmaxf(m0, e0);
        float sc0 = __expf(m0 - nm0);
        float p0  = __expf(e0 - nm0);
        l0 = l0 * sc0 + p0; acc0 = acc0 * sc0 + p0 * x0; m0 = nm0;
        float nm1 = fmaxf(m1, e1);
        float sc1 = __expf(m1 - nm1);
        float p1  = __expf(e1 - nm1);
        l1 = l1 * sc1 + p1; acc1 = acc1 * sc1 + p1 * x1; m1 = nm1;
    }
    float val = acc0 / l0 + acc1 / l1;       // heads {0,2} (lane<32) or {1,3}
    val += __shfl_xor(val, 32);              // combine other half's heads
    if (lane < 32) out[(long long)node * 32 + d] = fmaxf(0.25f * val + bg[d], 0.f);
}

// ================= pool =================
__global__ void k_pool_init(float* __restrict__ pooled, float* __restrict__ cnt) {
    int i = blockIdx.x * blockDim.x + threadIdx.x;
    if (i < NGRAPH * 32) pooled[i] = 0.f;
    if (i < NGRAPH) cnt[i] = 0.f;
}
__global__ void k_pool2(const float* __restrict__ h, const int* __restrict__ batch,
                        float* __restrict__ pooled, float* __restrict__ cnt, int n) {
    __shared__ float lp[NGRAPH * 32];
    __shared__ float lc[NGRAPH];
    int tid = threadIdx.x;
    for (int i = tid; i < NGRAPH * 32; i += 256) lp[i] = 0.f;
    for (int i = tid; i < NGRAPH; i += 256) lc[i] = 0.f;
    __syncthreads();
    int per = (n + gridDim.x - 1) / gridDim.x;
    int lo = blockIdx.x * per;
    int hi = min(n, lo + per);
    for (long long i = (long long)lo * 32 + tid; i < (long long)hi * 32; i += 256) {
        int ni = (int)(i >> 5), d = (int)(i & 31);
        int b = batch[ni];
        atomicAdd(&lp[b * 32 + d], h[i]);
        if (d == 0) atomicAdd(&lc[b], 1.f);
    }
    __syncthreads();
    for (int i = tid; i < NGRAPH * 32; i += 256)
        if (lp[i] != 0.f) atomicAdd(&pooled[i], lp[i]);
    for (int i = tid; i < NGRAPH; i += 256)
        if (lc[i] != 0.f) atomicAdd(&cnt[i], lc[i]);
}

// ================= classifier =================
__global__ void k_classifier(const float* __restrict__ pooled, const float* __restrict__ cnt,
                             const float* __restrict__ Wc1, const float* __restrict__ bc1,
                             const float* __restrict__ Wc2, const float* __restrict__ bc2,
                             float* __restrict__ out) {
    __shared__ float pl[NGRAPH * 32];
    __shared__ float t1[NGRAPH * 16];
    int tid = threadIdx.x;
    for (int i = tid; i < NGRAPH * 32; i += blockDim.x) {
        int g = i >> 5;
        pl[i] = pooled[i] / fmaxf(cnt[g], 1.f);
    }
    __syncthreads();
    for (int i = tid; i < NGRAPH * 16; i += blockDim.x) {
        int g = i >> 4, c = i & 15;
        float acc = bc1[c];
#pragma unroll
        for (int d = 0; d < 32; ++d) acc += pl[g * 32 + d] * Wc1[d * 16 + c];
        t1[i] = fmaxf(acc, 0.f);
    }
    __syncthreads();
    for (int i = tid; i < NGRAPH * 5; i += blockDim.x) {
        int g = i / 5, c = i % 5;
        float acc = bc2[c];
#pragma unroll
        for (int k = 0; k < 16; ++k) acc += t1[g * 16 + k] * Wc2[k * 5 + c];
        out[i] = acc;
    }
}

// ================= launch =================
static inline dim3 gsz(long long work, int block = 256) {
    long long g = (work + block - 1) / block;
    if (g > 262144) g = 262144;
    if (g < 1) g = 1;
    return dim3((unsigned)g);
}

extern "C" void kernel_launch(void* const* d_in, const int* in_sizes, int n_in,
                              void* d_out, int out_size, void* d_ws, size_t ws_size,
                              hipStream_t stream) {
    const float* x     = (const float*)d_in[0];
    const int*   ei    = (const int*)d_in[1];
    const int*   batch = (const int*)d_in[2];
    const float* W1 = (const float*)d_in[3];  const float* b1 = (const float*)d_in[4];
    const float* W2 = (const float*)d_in[5];  const float* b2 = (const float*)d_in[6];
    const float* W3 = (const float*)d_in[7];  const float* b3 = (const float*)d_in[8];
    const float* g1 = (const float*)d_in[9];  const float* be1 = (const float*)d_in[10];
    const float* m1 = (const float*)d_in[11]; const float* v1  = (const float*)d_in[12];
    const float* g2 = (const float*)d_in[13]; const float* be2 = (const float*)d_in[14];
    const float* m2 = (const float*)d_in[15]; const float* v2  = (const float*)d_in[16];
    const float* g3 = (const float*)d_in[17]; const float* be3 = (const float*)d_in[18];
    const float* m3 = (const float*)d_in[19]; const float* v3  = (const float*)d_in[20];
    const float* Wg  = (const float*)d_in[21];
    const float* ags = (const float*)d_in[22];
    const float* agd = (const float*)d_in[23];
    const float* bg  = (const float*)d_in[24];
    const float* Wc1 = (const float*)d_in[25]; const float* bc1 = (const float*)d_in[26];
    const float* Wc2 = (const float*)d_in[27]; const float* bc2 = (const float*)d_in[28];
    float* out = (float*)d_out;

    const int N = in_sizes[0] / 64;
    const int E = in_sizes[1] / 2;
    const int* esrc = ei;
    const int* edst = ei + E;
    const int nb = (N + 255) / 256;   // scan blocks (<=512 assumed)

    size_t off = 0;
    auto take = [&](size_t bytes) -> void* {
        void* p = (char*)d_ws + off;
        off += bytes;
        off = (off + 255) & ~(size_t)255;
        return p;
    };
    int*   deg    = (int*)take((size_t)N * 4);
    float* dinv   = (float*)take((size_t)N * 4);
    int*   rowptr = (int*)take((size_t)N * 4);
    int*   cursor = (int*)take((size_t)N * 4);
    int*   part   = (int*)take((size_t)N * 4);
    int*   bsum   = (int*)take((size_t)512 * 4);
    int*   csrc   = (int*)take((size_t)(E + N) * 4);
    float* A      = (float*)take((size_t)N * 128 * 4);
    float* B      = (float*)take((size_t)N * 128 * 4);
    float* a_s    = (float*)take((size_t)N * 4 * 4);
    float* a_d    = (float*)take((size_t)N * 4 * 4);
    float* pooled = (float*)take((size_t)NGRAPH * 32 * 4);
    float* cnt    = (float*)take((size_t)NGRAPH * 4);
    (void)ws_size; (void)n_in; (void)out_size;

    const dim3 B256(256);
    // degree + norm
    hipLaunchKernelGGL(k_init_deg, gsz(N), B256, 0, stream, deg, N);
    hipLaunchKernelGGL(k_deg, gsz(E), B256, 0, stream, edst, deg, E);
    hipLaunchKernelGGL(k_dinv, gsz(N), B256, 0, stream, deg, dinv, N);
    // CSR build
    hipLaunchKernelGGL(k_scan_block, dim3(nb), B256, 0, stream, deg, part, bsum, N);
    hipLaunchKernelGGL(k_scan_bsum, dim3(1), dim3(512), 0, stream, bsum, nb);
    hipLaunchKernelGGL(k_scan_add, dim3(nb), B256, 0, stream, part, bsum, rowptr, cursor, N);
    hipLaunchKernelGGL(k_scatter, gsz(E + N), B256, 0, stream, esrc, edst, cursor, csrc, E, N);

    // GCN layer 1: 64 -> 128
    hipLaunchKernelGGL((k_matmul<64, 128, 16>), dim3((N + 15) / 16), B256, 0, stream, x, W1, A, N);
    hipLaunchKernelGGL((k_agg_csr<128>), dim3((N + 3) / 4), B256, 0, stream,
                       A, rowptr, deg, csrc, dinv, b1, g1, be1, m1, v1, B, N);
    // GCN layer 2: 128 -> 64
    hipLaunchKernelGGL((k_matmul<128, 64, 16>), dim3((N + 15) / 16), B256, 0, stream, B, W2, A, N);
    hipLaunchKernelGGL((k_agg_csr<64>), dim3((N + 3) / 4), B256, 0, stream,
                       A, rowptr, deg, csrc, dinv, b2, g2, be2, m2, v2, B, N);
    // GCN layer 3: 64 -> 32
    hipLaunchKernelGGL((k_matmul<64, 32, 16>), dim3((N + 15) / 16), B256, 0, stream, B, W3, A, N);
    hipLaunchKernelGGL((k_agg_csr<32>), dim3((N + 7) / 8), B256, 0, stream,
                       A, rowptr, deg, csrc, dinv, b3, g3, be3, m3, v3, B, N);

    // GAT
    hipLaunchKernelGGL((k_matmul<32, 128, 16>), dim3((N + 15) / 16), B256, 0, stream, B, Wg, A, N);
    hipLaunchKernelGGL(k_att_sd, gsz((long long)N * 4), B256, 0, stream, A, ags, agd, a_s, a_d, N);
    hipLaunchKernelGGL(k_gat_csr, dim3((N + 3) / 4), B256, 0, stream,
                       A, a_s, a_d, rowptr, deg, csrc, bg, B, N);

    // pool + classifier
    hipLaunchKernelGGL(k_pool_init, dim3(9), B256, 0, stream, pooled, cnt);
    hipLaunchKernelGGL(k_pool2, dim3(128), B256, 0, stream, B, batch, pooled, cnt, N);
    hipLaunchKernelGGL(k_classifier, dim3(1), B256, 0, stream, pooled, cnt, Wc1, bc1, Wc2, bc2, out);
}

// Round 3
// 1067.800 us; speedup vs baseline: 3.3416x; 1.2627x over previous
//
#include <hip/hip_runtime.h>

#define EPSN   1e-5f
#define NEGS   0.2f
#define NGRAPH 64

__device__ __forceinline__ float lrelu(float e) { return e > 0.f ? e : NEGS * e; }

// ================= degree / norm =================
__global__ void k_init_deg(int* __restrict__ deg, int n) {
    for (int i = blockIdx.x * blockDim.x + threadIdx.x; i < n;
         i += gridDim.x * blockDim.x)
        deg[i] = 1;  // self-loop
}
__global__ void k_deg(const int* __restrict__ dst, int* __restrict__ deg, int E) {
    for (int e = blockIdx.x * blockDim.x + threadIdx.x; e < E;
         e += gridDim.x * blockDim.x)
        atomicAdd(&deg[dst[e]], 1);
}
__global__ void k_dinv(const int* __restrict__ deg, float* __restrict__ dinv, int n) {
    for (int i = blockIdx.x * blockDim.x + threadIdx.x; i < n;
         i += gridDim.x * blockDim.x)
        dinv[i] = rsqrtf((float)deg[i]);
}
// Xs = x * dinv[row]  (pre-scale for layer-1 aggregate-first)
__global__ void k_scale_x(const float* __restrict__ x, const float* __restrict__ dinv,
                          float* __restrict__ Xs, int n) {
    long long total = (long long)n * 64;
    for (long long i = blockIdx.x * (long long)blockDim.x + threadIdx.x; i < total;
         i += (long long)gridDim.x * blockDim.x)
        Xs[i] = x[i] * dinv[(int)(i >> 6)];
}

// ================= exclusive scan (3-phase) =================
__global__ void k_scan_block(const int* __restrict__ deg, int* __restrict__ part,
                             int* __restrict__ bsum, int n) {
    __shared__ int tmp[256];
    int gid = blockIdx.x * 256 + threadIdx.x;
    int v = (gid < n) ? deg[gid] : 0;
    tmp[threadIdx.x] = v;
    __syncthreads();
    for (int off = 1; off < 256; off <<= 1) {
        int t = (threadIdx.x >= off) ? tmp[threadIdx.x - off] : 0;
        __syncthreads();
        tmp[threadIdx.x] += t;
        __syncthreads();
    }
    if (gid < n) part[gid] = tmp[threadIdx.x] - v;  // exclusive
    if (threadIdx.x == 255) bsum[blockIdx.x] = tmp[255];
}
__global__ void k_scan_bsum(int* __restrict__ bsum, int nb) {
    __shared__ int tmp[512];
    int tid = threadIdx.x;
    int v = (tid < nb) ? bsum[tid] : 0;
    tmp[tid] = v;
    __syncthreads();
    for (int off = 1; off < 512; off <<= 1) {
        int t = (tid >= off) ? tmp[tid - off] : 0;
        __syncthreads();
        tmp[tid] += t;
        __syncthreads();
    }
    if (tid < nb) bsum[tid] = tmp[tid] - v;  // exclusive
}
__global__ void k_scan_add(const int* __restrict__ part, const int* __restrict__ bsum,
                           int* __restrict__ rowptr, int* __restrict__ cursor, int n) {
    int gid = blockIdx.x * 256 + threadIdx.x;
    if (gid < n) {
        int v = part[gid] + bsum[blockIdx.x];
        rowptr[gid] = v;
        cursor[gid] = v;
    }
}
__global__ void k_scatter(const int* __restrict__ es, const int* __restrict__ ed,
                          int* __restrict__ cursor, int* __restrict__ csrc,
                          int E, int n) {
    int total = E + n;
    for (int e = blockIdx.x * blockDim.x + threadIdx.x; e < total;
         e += gridDim.x * blockDim.x) {
        int s, t;
        if (e < E) { s = es[e]; t = ed[e]; }
        else       { s = t = e - E; }
        int pos = atomicAdd(&cursor[t], 1);
        csrc[pos] = s;
    }
}

// ================= dense matmul Y[n,M] = X[n,K] @ W[K,M] + epilogue =========
// EPI 0: plain; 1: +bias, BN, ReLU; 2: * dinv[row]
template <int K, int M, int ROWS, int EPI>
__global__ void k_matmul(const float* __restrict__ X, const float* __restrict__ W,
                         float* __restrict__ Y, int n,
                         const float* __restrict__ b, const float* __restrict__ g,
                         const float* __restrict__ be, const float* __restrict__ m,
                         const float* __restrict__ v, const float* __restrict__ dinv) {
    __shared__ float Wl[K * M];
    for (int i = threadIdx.x; i < K * M; i += blockDim.x) Wl[i] = W[i];
    __syncthreads();
    const int col = threadIdx.x & (M - 1);
    const int r0  = threadIdx.x / M;
    const int NR  = 256 / M;
    const int base = blockIdx.x * ROWS;
    for (int r = r0; r < ROWS; r += NR) {
        int row = base + r;
        if (row >= n) break;
        const float* xr = X + (long long)row * K;
        float acc = 0.f;
#pragma unroll
        for (int k = 0; k < K; ++k) acc += xr[k] * Wl[k * M + col];
        if (EPI == 1) {
            acc += b[col];
            acc = (acc - m[col]) * rsqrtf(v[col] + EPSN) * g[col] + be[col];
            acc = fmaxf(acc, 0.f);
        } else if (EPI == 2) {
            acc *= dinv[row];
        }
        Y[(long long)row * M + col] = acc;
    }
}

// ================= CSR sum-aggregation (rows pre-scaled by dinv[s]) =========
// EPI 0: out = acc*dinv[node]; EPI 1: + bias, BN, ReLU
template <int M, int EPI>
__global__ void k_agg_csr(const float* __restrict__ A, const int* __restrict__ rowptr,
                          const int* __restrict__ deg, const int* __restrict__ csrc,
                          const float* __restrict__ dinv,
                          const float* __restrict__ b, const float* __restrict__ g,
                          const float* __restrict__ be, const float* __restrict__ m,
                          const float* __restrict__ v,
                          float* __restrict__ B, int n) {
    const int NPB = 256 / M;
    int node = blockIdx.x * NPB + threadIdx.x / M;
    if (node >= n) return;
    int lane = threadIdx.x % M;
    int i = rowptr[node];
    int end = i + deg[node];
    float acc = 0.f;
    for (; i + 4 <= end; i += 4) {
        int s0 = csrc[i], s1 = csrc[i + 1], s2 = csrc[i + 2], s3 = csrc[i + 3];
        float x0 = A[(long long)s0 * M + lane];
        float x1 = A[(long long)s1 * M + lane];
        float x2 = A[(long long)s2 * M + lane];
        float x3 = A[(long long)s3 * M + lane];
        acc += (x0 + x1) + (x2 + x3);
    }
    for (; i < end; ++i) acc += A[(long long)csrc[i] * M + lane];
    float o = acc * dinv[node];
    if (EPI == 1) {
        o += b[lane];
        o = (o - m[lane]) * rsqrtf(v[lane] + EPSN) * g[lane] + be[lane];
        o = fmaxf(o, 0.f);
    }
    B[(long long)node * M + lane] = o;
}

// ================= GAT attention coefs from H3 (32-dim) =====================
// a_s[n,h] = sum_k H3[n,k] * Ws[k,h],  Ws[k,h] = sum_d Wg[k,h*32+d]*ags[h,d]
__global__ void k_att2(const float* __restrict__ H3, const float* __restrict__ Wg,
                       const float* __restrict__ ags, const float* __restrict__ agd,
                       float* __restrict__ a_s, float* __restrict__ a_d, int n) {
    __shared__ float Ws[32 * 4], Wd[32 * 4];
    for (int j = threadIdx.x; j < 128; j += 256) {
        int k = j >> 2, h = j & 3;
        float ss = 0.f, dd = 0.f;
        for (int d2 = 0; d2 < 32; ++d2) {
            float w = Wg[k * 128 + h * 32 + d2];
            ss += w * ags[h * 32 + d2];
            dd += w * agd[h * 32 + d2];
        }
        Ws[j] = ss; Wd[j] = dd;
    }
    __syncthreads();
    int total = n * 4;
    for (int i = blockIdx.x * blockDim.x + threadIdx.x; i < total;
         i += gridDim.x * blockDim.x) {
        int ni = i >> 2, h = i & 3;
        const float* hr = H3 + (long long)ni * 32;
        float xs = 0.f, xd = 0.f;
#pragma unroll
        for (int k = 0; k < 32; ++k) {
            float x = hr[k];
            xs += x * Ws[k * 4 + h];
            xd += x * Wd[k * 4 + h];
        }
        a_s[i] = xs;
        a_d[i] = xd;
    }
}

// ================= GAT: 2-phase softmax + 32-dim gather + fused Wg matmul ===
// one wave per node; lane -> d=lane&31, heads h0=lane>>5 (0/1), h1=h0+2 (2/3)
__global__ void k_gat2(const float* __restrict__ H3, const float* __restrict__ a_s,
                       const float* __restrict__ a_d, const int* __restrict__ rowptr,
                       const int* __restrict__ deg, const int* __restrict__ csrc,
                       const float* __restrict__ Wg, const float* __restrict__ bg,
                       float* __restrict__ H4, int n) {
    __shared__ float wbAll[4][128];
    int wid  = threadIdx.x >> 6;
    int node = blockIdx.x * 4 + wid;
    int lane = threadIdx.x & 63;
    int d  = lane & 31;
    int h0 = lane >> 5;
    int h1 = h0 + 2;
    float r0 = 0.f, r1 = 0.f;
    if (node < n) {
        float ad0 = a_d[node * 4 + h0];
        float ad1 = a_d[node * 4 + h1];
        int beg = rowptr[node];
        int end = beg + deg[node];
        // phase A: per-head max
        float m0 = -1e30f, m1 = -1e30f;
        int i = beg;
        for (; i + 4 <= end; i += 4) {
            int s0 = csrc[i], s1 = csrc[i + 1], s2 = csrc[i + 2], s3 = csrc[i + 3];
            float e;
            e = lrelu(a_s[s0 * 4 + h0] + ad0); m0 = fmaxf(m0, e);
            e = lrelu(a_s[s1 * 4 + h0] + ad0); m0 = fmaxf(m0, e);
            e = lrelu(a_s[s2 * 4 + h0] + ad0); m0 = fmaxf(m0, e);
            e = lrelu(a_s[s3 * 4 + h0] + ad0); m0 = fmaxf(m0, e);
            e = lrelu(a_s[s0 * 4 + h1] + ad1); m1 = fmaxf(m1, e);
            e = lrelu(a_s[s1 * 4 + h1] + ad1); m1 = fmaxf(m1, e);
            e = lrelu(a_s[s2 * 4 + h1] + ad1); m1 = fmaxf(m1, e);
            e = lrelu(a_s[s3 * 4 + h1] + ad1); m1 = fmaxf(m1, e);
        }
        for (; i < end; ++i) {
            int s = csrc[i];
            m0 = fmaxf(m0, lrelu(a_s[s * 4 + h0] + ad0));
            m1 = fmaxf(m1, lrelu(a_s[s * 4 + h1] + ad1));
        }
        // phase B: exp-sum + weighted gather (independent per edge -> unroll)
        float l0 = 0.f, a0 = 0.f, l1 = 0.f, a1 = 0.f;
        i = beg;
        for (; i + 2 <= end; i += 2) {
            int s0 = csrc[i], s1 = csrc[i + 1];
            float x0 = H3[(long long)s0 * 32 + d];
            float x1 = H3[(long long)s1 * 32 + d];
            float p;
            p = __expf(lrelu(a_s[s0 * 4 + h0] + ad0) - m0); l0 += p; a0 += p * x0;
            p = __expf(lrelu(a_s[s0 * 4 + h1] + ad1) - m1); l1 += p; a1 += p * x0;
            p = __expf(lrelu(a_s[s1 * 4 + h0] + ad0) - m0); l0 += p; a0 += p * x1;
            p = __expf(lrelu(a_s[s1 * 4 + h1] + ad1) - m1); l1 += p; a1 += p * x1;
        }
        for (; i < end; ++i) {
            int s = csrc[i];
            float x = H3[(long long)s * 32 + d];
            float p;
            p = __expf(lrelu(a_s[s * 4 + h0] + ad0) - m0); l0 += p; a0 += p * x;
            p = __expf(lrelu(a_s[s * 4 + h1] + ad1) - m1); l1 += p; a1 += p * x;
        }
        r0 = a0 / l0;   // deg>=1 (self-loop) so l>0
        r1 = a1 / l1;
    }
    // stage per-head agg into LDS: wb[j] = agg[h=j>>5][k=j&31]
    float* wb = wbAll[wid];
    wb[lane]      = r0;   // j = h0*32+d = lane
    wb[64 + lane] = r1;   // j = h1*32+d = 64+lane
    __syncthreads();
    if (node < n) {
        // out[d] = relu(0.25 * sum_j wb[j]*Wg[(j&31)*128+(j>>5)*32+d] + bg[d])
        int half = (lane >> 5) * 64;   // lanes split the 128-sum
        float o = 0.f;
#pragma unroll
        for (int j = 0; j < 64; ++j) {
            int jj = half + j;
            o += wb[jj] * Wg[(jj & 31) * 128 + (jj >> 5) * 32 + d];
        }
        o += __shfl_xor(o, 32);
        if (lane < 32)
            H4[(long long)node * 32 + d] = fmaxf(0.25f * o + bg[d], 0.f);
    }
}

// ================= pool =================
__global__ void k_pool_init(float* __restrict__ pooled, float* __restrict__ cnt) {
    int i = blockIdx.x * blockDim.x + threadIdx.x;
    if (i < NGRAPH * 32) pooled[i] = 0.f;
    if (i < NGRAPH) cnt[i] = 0.f;
}
__global__ void k_pool2(const float* __restrict__ h, const int* __restrict__ batch,
                        float* __restrict__ pooled, float* __restrict__ cnt, int n) {
    __shared__ float lp[NGRAPH * 32];
    __shared__ float lc[NGRAPH];
    int tid = threadIdx.x;
    for (int i = tid; i < NGRAPH * 32; i += 256) lp[i] = 0.f;
    for (int i = tid; i < NGRAPH; i += 256) lc[i] = 0.f;
    __syncthreads();
    int per = (n + gridDim.x - 1) / gridDim.x;
    int lo = blockIdx.x * per;
    int hi = min(n, lo + per);
    for (long long i = (long long)lo * 32 + tid; i < (long long)hi * 32; i += 256) {
        int ni = (int)(i >> 5), d = (int)(i & 31);
        int b = batch[ni];
        atomicAdd(&lp[b * 32 + d], h[i]);
        if (d == 0) atomicAdd(&lc[b], 1.f);
    }
    __syncthreads();
    for (int i = tid; i < NGRAPH * 32; i += 256)
        if (lp[i] != 0.f) atomicAdd(&pooled[i], lp[i]);
    for (int i = tid; i < NGRAPH; i += 256)
        if (lc[i] != 0.f) atomicAdd(&cnt[i], lc[i]);
}

// ================= classifier =================
__global__ void k_classifier(const float* __restrict__ pooled, const float* __restrict__ cnt,
                             const float* __restrict__ Wc1, const float* __restrict__ bc1,
                             const float* __restrict__ Wc2, const float* __restrict__ bc2,
                             float* __restrict__ out) {
    __shared__ float pl[NGRAPH * 32];
    __shared__ float t1[NGRAPH * 16];
    int tid = threadIdx.x;
    for (int i = tid; i < NGRAPH * 32; i += blockDim.x) {
        int g = i >> 5;
        pl[i] = pooled[i] / fmaxf(cnt[g], 1.f);
    }
    __syncthreads();
    for (int i = tid; i < NGRAPH * 16; i += blockDim.x) {
        int g = i >> 4, c = i & 15;
        float acc = bc1[c];
#pragma unroll
        for (int d = 0; d < 32; ++d) acc += pl[g * 32 + d] * Wc1[d * 16 + c];
        t1[i] = fmaxf(acc, 0.f);
    }
    __syncthreads();
    for (int i = tid; i < NGRAPH * 5; i += blockDim.x) {
        int g = i / 5, c = i % 5;
        float acc = bc2[c];
#pragma unroll
        for (int k = 0; k < 16; ++k) acc += t1[g * 16 + k] * Wc2[k * 5 + c];
        out[i] = acc;
    }
}

// ================= launch =================
static inline dim3 gsz(long long work, int block = 256) {
    long long g = (work + block - 1) / block;
    if (g > 262144) g = 262144;
    if (g < 1) g = 1;
    return dim3((unsigned)g);
}

extern "C" void kernel_launch(void* const* d_in, const int* in_sizes, int n_in,
                              void* d_out, int out_size, void* d_ws, size_t ws_size,
                              hipStream_t stream) {
    const float* x     = (const float*)d_in[0];
    const int*   ei    = (const int*)d_in[1];
    const int*   batch = (const int*)d_in[2];
    const float* W1 = (const float*)d_in[3];  const float* b1 = (const float*)d_in[4];
    const float* W2 = (const float*)d_in[5];  const float* b2 = (const float*)d_in[6];
    const float* W3 = (const float*)d_in[7];  const float* b3 = (const float*)d_in[8];
    const float* g1 = (const float*)d_in[9];  const float* be1 = (const float*)d_in[10];
    const float* m1 = (const float*)d_in[11]; const float* v1  = (const float*)d_in[12];
    const float* g2 = (const float*)d_in[13]; const float* be2 = (const float*)d_in[14];
    const float* m2 = (const float*)d_in[15]; const float* v2  = (const float*)d_in[16];
    const float* g3 = (const float*)d_in[17]; const float* be3 = (const float*)d_in[18];
    const float* m3 = (const float*)d_in[19]; const float* v3  = (const float*)d_in[20];
    const float* Wg  = (const float*)d_in[21];
    const float* ags = (const float*)d_in[22];
    const float* agd = (const float*)d_in[23];
    const float* bg  = (const float*)d_in[24];
    const float* Wc1 = (const float*)d_in[25]; const float* bc1 = (const float*)d_in[26];
    const float* Wc2 = (const float*)d_in[27]; const float* bc2 = (const float*)d_in[28];
    float* out = (float*)d_out;

    const int N = in_sizes[0] / 64;
    const int E = in_sizes[1] / 2;
    const int* esrc = ei;
    const int* edst = ei + E;
    const int nb = (N + 255) / 256;

    size_t off = 0;
    auto take = [&](size_t bytes) -> void* {
        void* p = (char*)d_ws + off;
        off += bytes;
        off = (off + 255) & ~(size_t)255;
        return p;
    };
    int*   deg    = (int*)take((size_t)N * 4);
    float* dinv   = (float*)take((size_t)N * 4);
    int*   rowptr = (int*)take((size_t)N * 4);
    int*   cursor = (int*)take((size_t)N * 4);
    int*   part   = (int*)take((size_t)N * 4);
    int*   bsum   = (int*)take((size_t)512 * 4);
    int*   csrc   = (int*)take((size_t)(E + N) * 4);
    float* bufA   = (float*)take((size_t)N * 64 * 4);   // Xs -> A2 -> A3
    float* bufB   = (float*)take((size_t)N * 64 * 4);   // Xa -> H2 -> H3
    float* bufC   = (float*)take((size_t)N * 128 * 4);  // H1 -> H4
    float* a_s    = (float*)take((size_t)N * 4 * 4);
    float* a_d    = (float*)take((size_t)N * 4 * 4);
    float* pooled = (float*)take((size_t)NGRAPH * 32 * 4);
    float* cnt    = (float*)take((size_t)NGRAPH * 4);
    (void)ws_size; (void)n_in; (void)out_size;

    const dim3 B256(256);
    const float* nil = nullptr;

    // degree + norm + CSR
    hipLaunchKernelGGL(k_init_deg, gsz(N), B256, 0, stream, deg, N);
    hipLaunchKernelGGL(k_deg, gsz(E), B256, 0, stream, edst, deg, E);
    hipLaunchKernelGGL(k_dinv, gsz(N), B256, 0, stream, deg, dinv, N);
    hipLaunchKernelGGL(k_scan_block, dim3(nb), B256, 0, stream, deg, part, bsum, N);
    hipLaunchKernelGGL(k_scan_bsum, dim3(1), dim3(512), 0, stream, bsum, nb);
    hipLaunchKernelGGL(k_scan_add, dim3(nb), B256, 0, stream, part, bsum, rowptr, cursor, N);
    hipLaunchKernelGGL(k_scatter, gsz(E + N), B256, 0, stream, esrc, edst, cursor, csrc, E, N);

    // layer 1 (aggregate-first): Xs = x*dinv ; Xa = dinv*sum(Xs) ; H1 = relu(BN(Xa@W1+b1))
    hipLaunchKernelGGL(k_scale_x, gsz((long long)N * 64), B256, 0, stream, x, dinv, bufA, N);
    hipLaunchKernelGGL((k_agg_csr<64, 0>), dim3((N + 3) / 4), B256, 0, stream,
                       bufA, rowptr, deg, csrc, dinv, nil, nil, nil, nil, nil, bufB, N);
    hipLaunchKernelGGL((k_matmul<64, 128, 16, 1>), dim3((N + 15) / 16), B256, 0, stream,
                       bufB, W1, bufC, N, b1, g1, be1, m1, v1, nil);
    // layer 2: A2 = (H1@W2)*dinv ; H2 = relu(BN(dinv*sum(A2)+b2))
    hipLaunchKernelGGL((k_matmul<128, 64, 16, 2>), dim3((N + 15) / 16), B256, 0, stream,
                       bufC, W2, bufA, N, nil, nil, nil, nil, nil, dinv);
    hipLaunchKernelGGL((k_agg_csr<64, 1>), dim3((N + 3) / 4), B256, 0, stream,
                       bufA, rowptr, deg, csrc, dinv, b2, g2, be2, m2, v2, bufB, N);
    // layer 3: A3 = (H2@W3)*dinv ; H3 = relu(BN(dinv*sum(A3)+b3))
    hipLaunchKernelGGL((k_matmul<64, 32, 16, 2>), dim3((N + 15) / 16), B256, 0, stream,
                       bufB, W3, bufA, N, nil, nil, nil, nil, nil, dinv);
    hipLaunchKernelGGL((k_agg_csr<32, 1>), dim3((N + 7) / 8), B256, 0, stream,
                       bufA, rowptr, deg, csrc, dinv, b3, g3, be3, m3, v3, bufB, N);

    // GAT on H3 (bufB): coefs, gather+softmax, fused Wg epilogue -> H4 (bufC)
    hipLaunchKernelGGL(k_att2, gsz((long long)N * 4), B256, 0, stream,
                       bufB, Wg, ags, agd, a_s, a_d, N);
    hipLaunchKernelGGL(k_gat2, dim3((N + 3) / 4), B256, 0, stream,
                       bufB, a_s, a_d, rowptr, deg, csrc, Wg, bg, bufC, N);

    // pool + classifier
    hipLaunchKernelGGL(k_pool_init, dim3(9), B256, 0, stream, pooled, cnt);
    hipLaunchKernelGGL(k_pool2, dim3(128), B256, 0, stream, bufC, batch, pooled, cnt, N);
    hipLaunchKernelGGL(k_classifier, dim3(1), B256, 0, stream, pooled, cnt, Wc1, bc1, Wc2, bc2, out);
}

// Round 4
// 850.172 us; speedup vs baseline: 4.1970x; 1.2560x over previous
//
#include <hip/hip_runtime.h>

#define EPSN   1e-5f
#define NEGS   0.2f
#define NGRAPH 64

__device__ __forceinline__ float lrelu(float e) { return e > 0.f ? e : NEGS * e; }

// ================= degree / norm =================
__global__ void k_init_deg(int* __restrict__ deg, int n) {
    for (int i = blockIdx.x * blockDim.x + threadIdx.x; i < n;
         i += gridDim.x * blockDim.x)
        deg[i] = 1;  // self-loop
}
__global__ void k_deg(const int* __restrict__ dst, int* __restrict__ deg, int E) {
    for (int e = blockIdx.x * blockDim.x + threadIdx.x; e < E;
         e += gridDim.x * blockDim.x)
        atomicAdd(&deg[dst[e]], 1);
}
__global__ void k_dinv(const int* __restrict__ deg, float* __restrict__ dinv, int n) {
    for (int i = blockIdx.x * blockDim.x + threadIdx.x; i < n;
         i += gridDim.x * blockDim.x)
        dinv[i] = rsqrtf((float)deg[i]);
}
// Xs = x * dinv[row], float4
__global__ void k_scale_x4(const float* __restrict__ x, const float* __restrict__ dinv,
                           float* __restrict__ Xs, int n) {
    int total = n * 16;  // 64 dims / 4
    for (int q = blockIdx.x * blockDim.x + threadIdx.x; q < total;
         q += gridDim.x * blockDim.x) {
        float din = dinv[q >> 4];
        float4 xv = ((const float4*)x)[q];
        xv.x *= din; xv.y *= din; xv.z *= din; xv.w *= din;
        ((float4*)Xs)[q] = xv;
    }
}

// ================= exclusive scan (3-phase) =================
__global__ void k_scan_block(const int* __restrict__ deg, int* __restrict__ part,
                             int* __restrict__ bsum, int n) {
    __shared__ int tmp[256];
    int gid = blockIdx.x * 256 + threadIdx.x;
    int v = (gid < n) ? deg[gid] : 0;
    tmp[threadIdx.x] = v;
    __syncthreads();
    for (int off = 1; off < 256; off <<= 1) {
        int t = (threadIdx.x >= off) ? tmp[threadIdx.x - off] : 0;
        __syncthreads();
        tmp[threadIdx.x] += t;
        __syncthreads();
    }
    if (gid < n) part[gid] = tmp[threadIdx.x] - v;  // exclusive
    if (threadIdx.x == 255) bsum[blockIdx.x] = tmp[255];
}
__global__ void k_scan_bsum(int* __restrict__ bsum, int nb) {
    __shared__ int tmp[512];
    int tid = threadIdx.x;
    int v = (tid < nb) ? bsum[tid] : 0;
    tmp[tid] = v;
    __syncthreads();
    for (int off = 1; off < 512; off <<= 1) {
        int t = (tid >= off) ? tmp[tid - off] : 0;
        __syncthreads();
        tmp[tid] += t;
        __syncthreads();
    }
    if (tid < nb) bsum[tid] = tmp[tid] - v;  // exclusive
}
__global__ void k_scan_add(const int* __restrict__ part, const int* __restrict__ bsum,
                           int* __restrict__ rowptr, int* __restrict__ cursor, int n) {
    int gid = blockIdx.x * 256 + threadIdx.x;
    if (gid < n) {
        int v = part[gid] + bsum[blockIdx.x];
        rowptr[gid] = v;
        cursor[gid] = v;
    }
}
__global__ void k_scatter(const int* __restrict__ es, const int* __restrict__ ed,
                          int* __restrict__ cursor, int* __restrict__ csrc,
                          int E, int n) {
    int total = E + n;
    for (int e = blockIdx.x * blockDim.x + threadIdx.x; e < total;
         e += gridDim.x * blockDim.x) {
        int s, t;
        if (e < E) { s = es[e]; t = ed[e]; }
        else       { s = t = e - E; }
        int pos = atomicAdd(&cursor[t], 1);
        csrc[pos] = s;
    }
}

// ===== dense matmul Y[n,M] = X[n,K] @ W[K,M], 4-col blocking, float4 =====
// EPI 0: plain; 1: +bias, BN, ReLU; 2: * dinv[row]
template <int K, int M, int EPI>
__global__ void k_matmul4(const float* __restrict__ X, const float* __restrict__ W,
                          float* __restrict__ Y, int n,
                          const float* __restrict__ b, const float* __restrict__ g,
                          const float* __restrict__ be, const float* __restrict__ m,
                          const float* __restrict__ v, const float* __restrict__ dinv) {
    __shared__ float Wl[K * M];
    for (int i = threadIdx.x; i < K * M / 4; i += 256)
        ((float4*)Wl)[i] = ((const float4*)W)[i];
    __syncthreads();
    const int TPR = M / 4;          // threads per row
    const int RPB = 256 / TPR;      // rows per block
    const int c4  = (threadIdx.x % TPR) * 4;
    int row = blockIdx.x * RPB + threadIdx.x / TPR;
    if (row >= n) return;
    const float4* xr = (const float4*)(X + (long long)row * K);
    float4 acc = make_float4(0.f, 0.f, 0.f, 0.f);
#pragma unroll
    for (int k4 = 0; k4 < K / 4; ++k4) {
        float4 xv = xr[k4];
        const float* wp = &Wl[(k4 * 4) * M + c4];
        float4 w0 = *(const float4*)(wp);
        float4 w1 = *(const float4*)(wp + M);
        float4 w2 = *(const float4*)(wp + 2 * M);
        float4 w3 = *(const float4*)(wp + 3 * M);
        acc.x += xv.x * w0.x + xv.y * w1.x + xv.z * w2.x + xv.w * w3.x;
        acc.y += xv.x * w0.y + xv.y * w1.y + xv.z * w2.y + xv.w * w3.y;
        acc.z += xv.x * w0.z + xv.y * w1.z + xv.z * w2.z + xv.w * w3.z;
        acc.w += xv.x * w0.w + xv.y * w1.w + xv.z * w2.w + xv.w * w3.w;
    }
    if (EPI == 1) {
        float4 bb = *(const float4*)(b + c4);
        float4 mm = *(const float4*)(m + c4);
        float4 vv = *(const float4*)(v + c4);
        float4 gg = *(const float4*)(g + c4);
        float4 ee = *(const float4*)(be + c4);
        acc.x = fmaxf((acc.x + bb.x - mm.x) * rsqrtf(vv.x + EPSN) * gg.x + ee.x, 0.f);
        acc.y = fmaxf((acc.y + bb.y - mm.y) * rsqrtf(vv.y + EPSN) * gg.y + ee.y, 0.f);
        acc.z = fmaxf((acc.z + bb.z - mm.z) * rsqrtf(vv.z + EPSN) * gg.z + ee.z, 0.f);
        acc.w = fmaxf((acc.w + bb.w - mm.w) * rsqrtf(vv.w + EPSN) * gg.w + ee.w, 0.f);
    } else if (EPI == 2) {
        float din = dinv[row];
        acc.x *= din; acc.y *= din; acc.z *= din; acc.w *= din;
    }
    *(float4*)(Y + (long long)row * M + c4) = acc;
}

// ===== CSR sum-aggregation, float4, multi-edge per wave (rows pre-scaled) =====
// one wave per node; LPE = M/4 lanes per edge; EPW = 64/LPE edges in flight
template <int M, int EPI>
__global__ void k_agg4(const float* __restrict__ A, const int* __restrict__ rowptr,
                       const int* __restrict__ deg, const int* __restrict__ csrc,
                       const float* __restrict__ dinv,
                       const float* __restrict__ b, const float* __restrict__ g,
                       const float* __restrict__ be, const float* __restrict__ m,
                       const float* __restrict__ v,
                       float* __restrict__ B, int n) {
    const int LPE = M / 4;
    const int EPW = 64 / LPE;
    int node = blockIdx.x * 4 + (threadIdx.x >> 6);
    if (node >= n) return;
    int lane = threadIdx.x & 63;
    int eg = lane / LPE;
    int dl = lane % LPE;
    int beg = rowptr[node];
    int end = beg + deg[node];
    float4 acc = make_float4(0.f, 0.f, 0.f, 0.f);
    for (int base = beg; base < end; base += EPW) {
        int i = base + eg;
        if (i < end) {
            int s = csrc[i];
            float4 xv = *(const float4*)(A + (long long)s * M + dl * 4);
            acc.x += xv.x; acc.y += xv.y; acc.z += xv.z; acc.w += xv.w;
        }
    }
#pragma unroll
    for (int off = LPE; off < 64; off <<= 1) {
        acc.x += __shfl_xor(acc.x, off);
        acc.y += __shfl_xor(acc.y, off);
        acc.z += __shfl_xor(acc.z, off);
        acc.w += __shfl_xor(acc.w, off);
    }
    if (eg == 0) {
        float din = dinv[node];
        acc.x *= din; acc.y *= din; acc.z *= din; acc.w *= din;
        if (EPI == 1) {
            int d0 = dl * 4;
            float4 bb = *(const float4*)(b + d0);
            float4 mm = *(const float4*)(m + d0);
            float4 vv = *(const float4*)(v + d0);
            float4 gg = *(const float4*)(g + d0);
            float4 ee = *(const float4*)(be + d0);
            acc.x = fmaxf((acc.x + bb.x - mm.x) * rsqrtf(vv.x + EPSN) * gg.x + ee.x, 0.f);
            acc.y = fmaxf((acc.y + bb.y - mm.y) * rsqrtf(vv.y + EPSN) * gg.y + ee.y, 0.f);
            acc.z = fmaxf((acc.z + bb.z - mm.z) * rsqrtf(vv.z + EPSN) * gg.z + ee.z, 0.f);
            acc.w = fmaxf((acc.w + bb.w - mm.w) * rsqrtf(vv.w + EPSN) * gg.w + ee.w, 0.f);
        }
        *(float4*)(B + (long long)node * M + dl * 4) = acc;
    }
}

// ================= GAT attention coefs from H3 (32-dim) =====================
__global__ void k_att2(const float* __restrict__ H3, const float* __restrict__ Wg,
                       const float* __restrict__ ags, const float* __restrict__ agd,
                       float* __restrict__ a_s, float* __restrict__ a_d, int n) {
    __shared__ float Ws[32 * 4], Wd[32 * 4];
    for (int j = threadIdx.x; j < 128; j += 256) {
        int k = j >> 2, h = j & 3;
        float ss = 0.f, dd = 0.f;
        for (int d2 = 0; d2 < 32; ++d2) {
            float w = Wg[k * 128 + h * 32 + d2];
            ss += w * ags[h * 32 + d2];
            dd += w * agd[h * 32 + d2];
        }
        Ws[j] = ss; Wd[j] = dd;
    }
    __syncthreads();
    int total = n * 4;
    for (int i = blockIdx.x * blockDim.x + threadIdx.x; i < total;
         i += gridDim.x * blockDim.x) {
        int ni = i >> 2, h = i & 3;
        const float* hr = H3 + (long long)ni * 32;
        float xs = 0.f, xd = 0.f;
#pragma unroll
        for (int k = 0; k < 32; ++k) {
            float x = hr[k];
            xs += x * Ws[k * 4 + h];
            xd += x * Wd[k * 4 + h];
        }
        a_s[i] = xs;
        a_d[i] = xd;
    }
}

// ===== GAT softmax weights per (edge, head): one wave per node =====
// lane -> slot = lane>>2 (16 slots), head = lane&3; 0.25 head-mean folded in
__global__ void k_attw(const float* __restrict__ a_s, const float* __restrict__ a_d,
                       const int* __restrict__ rowptr, const int* __restrict__ deg,
                       const int* __restrict__ csrc, float* __restrict__ att, int n) {
    int node = blockIdx.x * 4 + (threadIdx.x >> 6);
    if (node >= n) return;
    int lane = threadIdx.x & 63;
    int hh = lane & 3;
    int slot = lane >> 2;
    int beg = rowptr[node];
    int cnt = deg[node];
    float ad = a_d[node * 4 + hh];
    float mx = -1e30f;
    for (int i = slot; i < cnt; i += 16)
        mx = fmaxf(mx, lrelu(a_s[csrc[beg + i] * 4 + hh] + ad));
    mx = fmaxf(mx, __shfl_xor(mx, 4));
    mx = fmaxf(mx, __shfl_xor(mx, 8));
    mx = fmaxf(mx, __shfl_xor(mx, 16));
    mx = fmaxf(mx, __shfl_xor(mx, 32));
    float sum = 0.f;
    for (int i = slot; i < cnt; i += 16)
        sum += __expf(lrelu(a_s[csrc[beg + i] * 4 + hh] + ad) - mx);
    sum += __shfl_xor(sum, 4);
    sum += __shfl_xor(sum, 8);
    sum += __shfl_xor(sum, 16);
    sum += __shfl_xor(sum, 32);
    float inv = 0.25f / sum;
    for (int i = slot; i < cnt; i += 16)
        att[(beg + i) * 4 + hh] =
            __expf(lrelu(a_s[csrc[beg + i] * 4 + hh] + ad) - mx) * inv;
}

// ===== GAT gather with precomputed weights + fused Wg epilogue =====
// one wave per node; lane -> d=lane&31, h0=lane>>5 (heads h0 / h0+2)
__global__ void k_gatg(const float* __restrict__ H3, const float* __restrict__ att,
                       const int* __restrict__ rowptr, const int* __restrict__ deg,
                       const int* __restrict__ csrc, const float* __restrict__ Wg,
                       const float* __restrict__ bg, float* __restrict__ H4, int n) {
    __shared__ float wbAll[4][128];
    int wid = threadIdx.x >> 6;
    int node = blockIdx.x * 4 + wid;
    int lane = threadIdx.x & 63;
    int d = lane & 31;
    int h0 = lane >> 5;
    float a0 = 0.f, a1 = 0.f;
    if (node < n) {
        int i = rowptr[node];
        int end = i + deg[node];
        for (; i + 4 <= end; i += 4) {
            int s0 = csrc[i], s1 = csrc[i + 1], s2 = csrc[i + 2], s3 = csrc[i + 3];
            float x0 = H3[(long long)s0 * 32 + d];
            float x1 = H3[(long long)s1 * 32 + d];
            float x2 = H3[(long long)s2 * 32 + d];
            float x3 = H3[(long long)s3 * 32 + d];
            float w00 = att[i * 4 + h0],       w01 = att[i * 4 + h0 + 2];
            float w10 = att[(i + 1) * 4 + h0], w11 = att[(i + 1) * 4 + h0 + 2];
            float w20 = att[(i + 2) * 4 + h0], w21 = att[(i + 2) * 4 + h0 + 2];
            float w30 = att[(i + 3) * 4 + h0], w31 = att[(i + 3) * 4 + h0 + 2];
            a0 += w00 * x0 + w10 * x1 + w20 * x2 + w30 * x3;
            a1 += w01 * x0 + w11 * x1 + w21 * x2 + w31 * x3;
        }
        for (; i < end; ++i) {
            int s = csrc[i];
            float x = H3[(long long)s * 32 + d];
            a0 += att[i * 4 + h0] * x;
            a1 += att[i * 4 + h0 + 2] * x;
        }
    }
    float* wb = wbAll[wid];
    wb[lane] = a0;        // j = h0*32+d
    wb[64 + lane] = a1;   // j = (h0+2)*32+d
    __syncthreads();
    if (node < n) {
        int half = (lane >> 5) * 64;
        float o = 0.f;
#pragma unroll
        for (int j = 0; j < 64; ++j) {
            int jj = half + j;
            o += wb[jj] * Wg[(jj & 31) * 128 + (jj >> 5) * 32 + d];
        }
        o += __shfl_xor(o, 32);
        if (lane < 32)
            H4[(long long)node * 32 + d] = fmaxf(o + bg[d], 0.f);
    }
}

// ================= pool =================
__global__ void k_pool_init(float* __restrict__ pooled, float* __restrict__ cnt) {
    int i = blockIdx.x * blockDim.x + threadIdx.x;
    if (i < NGRAPH * 32) pooled[i] = 0.f;
    if (i < NGRAPH) cnt[i] = 0.f;
}
__global__ void k_pool2(const float* __restrict__ h, const int* __restrict__ batch,
                        float* __restrict__ pooled, float* __restrict__ cnt, int n) {
    __shared__ float lp[NGRAPH * 32];
    __shared__ float lc[NGRAPH];
    int tid = threadIdx.x;
    for (int i = tid; i < NGRAPH * 32; i += 256) lp[i] = 0.f;
    for (int i = tid; i < NGRAPH; i += 256) lc[i] = 0.f;
    __syncthreads();
    int per = (n + gridDim.x - 1) / gridDim.x;
    int lo = blockIdx.x * per;
    int hi = min(n, lo + per);
    for (long long i = (long long)lo * 32 + tid; i < (long long)hi * 32; i += 256) {
        int ni = (int)(i >> 5), d = (int)(i & 31);
        int b = batch[ni];
        atomicAdd(&lp[b * 32 + d], h[i]);
        if (d == 0) atomicAdd(&lc[b], 1.f);
    }
    __syncthreads();
    for (int i = tid; i < NGRAPH * 32; i += 256)
        if (lp[i] != 0.f) atomicAdd(&pooled[i], lp[i]);
    for (int i = tid; i < NGRAPH; i += 256)
        if (lc[i] != 0.f) atomicAdd(&cnt[i], lc[i]);
}

// ================= classifier =================
__global__ void k_classifier(const float* __restrict__ pooled, const float* __restrict__ cnt,
                             const float* __restrict__ Wc1, const float* __restrict__ bc1,
                             const float* __restrict__ Wc2, const float* __restrict__ bc2,
                             float* __restrict__ out) {
    __shared__ float pl[NGRAPH * 32];
    __shared__ float t1[NGRAPH * 16];
    int tid = threadIdx.x;
    for (int i = tid; i < NGRAPH * 32; i += blockDim.x) {
        int g = i >> 5;
        pl[i] = pooled[i] / fmaxf(cnt[g], 1.f);
    }
    __syncthreads();
    for (int i = tid; i < NGRAPH * 16; i += blockDim.x) {
        int g = i >> 4, c = i & 15;
        float acc = bc1[c];
#pragma unroll
        for (int d = 0; d < 32; ++d) acc += pl[g * 32 + d] * Wc1[d * 16 + c];
        t1[i] = fmaxf(acc, 0.f);
    }
    __syncthreads();
    for (int i = tid; i < NGRAPH * 5; i += blockDim.x) {
        int g = i / 5, c = i % 5;
        float acc = bc2[c];
#pragma unroll
        for (int k = 0; k < 16; ++k) acc += t1[g * 16 + k] * Wc2[k * 5 + c];
        out[i] = acc;
    }
}

// ================= launch =================
static inline dim3 gsz(long long work, int block = 256) {
    long long g = (work + block - 1) / block;
    if (g > 262144) g = 262144;
    if (g < 1) g = 1;
    return dim3((unsigned)g);
}

extern "C" void kernel_launch(void* const* d_in, const int* in_sizes, int n_in,
                              void* d_out, int out_size, void* d_ws, size_t ws_size,
                              hipStream_t stream) {
    const float* x     = (const float*)d_in[0];
    const int*   ei    = (const int*)d_in[1];
    const int*   batch = (const int*)d_in[2];
    const float* W1 = (const float*)d_in[3];  const float* b1 = (const float*)d_in[4];
    const float* W2 = (const float*)d_in[5];  const float* b2 = (const float*)d_in[6];
    const float* W3 = (const float*)d_in[7];  const float* b3 = (const float*)d_in[8];
    const float* g1 = (const float*)d_in[9];  const float* be1 = (const float*)d_in[10];
    const float* m1 = (const float*)d_in[11]; const float* v1  = (const float*)d_in[12];
    const float* g2 = (const float*)d_in[13]; const float* be2 = (const float*)d_in[14];
    const float* m2 = (const float*)d_in[15]; const float* v2  = (const float*)d_in[16];
    const float* g3 = (const float*)d_in[17]; const float* be3 = (const float*)d_in[18];
    const float* m3 = (const float*)d_in[19]; const float* v3  = (const float*)d_in[20];
    const float* Wg  = (const float*)d_in[21];
    const float* ags = (const float*)d_in[22];
    const float* agd = (const float*)d_in[23];
    const float* bg  = (const float*)d_in[24];
    const float* Wc1 = (const float*)d_in[25]; const float* bc1 = (const float*)d_in[26];
    const float* Wc2 = (const float*)d_in[27]; const float* bc2 = (const float*)d_in[28];
    float* out = (float*)d_out;

    const int N = in_sizes[0] / 64;
    const int E = in_sizes[1] / 2;
    const int* esrc = ei;
    const int* edst = ei + E;
    const int nb = (N + 255) / 256;

    size_t off = 0;
    auto take = [&](size_t bytes) -> void* {
        void* p = (char*)d_ws + off;
        off += bytes;
        off = (off + 255) & ~(size_t)255;
        return p;
    };
    int*   deg    = (int*)take((size_t)N * 4);
    float* dinv   = (float*)take((size_t)N * 4);
    int*   rowptr = (int*)take((size_t)N * 4);
    int*   cursor = (int*)take((size_t)N * 4);
    int*   part   = (int*)take((size_t)N * 4);
    int*   bsum   = (int*)take((size_t)512 * 4);
    int*   csrc   = (int*)take((size_t)(E + N) * 4);
    float* bufA   = (float*)take((size_t)N * 64 * 4);   // Xs -> A2 -> A3 -> H4
    float* bufB   = (float*)take((size_t)N * 64 * 4);   // Xa -> H2 -> H3
    float* bufC   = (float*)take((size_t)N * 128 * 4);  // H1 ; then att (E+N)*4 floats
    float* a_s    = (float*)take((size_t)N * 4 * 4);
    float* a_d    = (float*)take((size_t)N * 4 * 4);
    float* pooled = (float*)take((size_t)NGRAPH * 32 * 4);
    float* cnt    = (float*)take((size_t)NGRAPH * 4);
    float* att    = bufC;  // alias: bufC free after matmul2 consumes H1
    (void)ws_size; (void)n_in; (void)out_size;

    const dim3 B256(256);
    const float* nil = nullptr;

    // degree + norm + CSR
    hipLaunchKernelGGL(k_init_deg, gsz(N), B256, 0, stream, deg, N);
    hipLaunchKernelGGL(k_deg, gsz(E), B256, 0, stream, edst, deg, E);
    hipLaunchKernelGGL(k_dinv, gsz(N), B256, 0, stream, deg, dinv, N);
    hipLaunchKernelGGL(k_scan_block, dim3(nb), B256, 0, stream, deg, part, bsum, N);
    hipLaunchKernelGGL(k_scan_bsum, dim3(1), dim3(512), 0, stream, bsum, nb);
    hipLaunchKernelGGL(k_scan_add, dim3(nb), B256, 0, stream, part, bsum, rowptr, cursor, N);
    hipLaunchKernelGGL(k_scatter, gsz(E + N), B256, 0, stream, esrc, edst, cursor, csrc, E, N);

    // layer 1 (aggregate-first): Xs = x*dinv ; Xa = dinv*sum(Xs) ; H1 = relu(BN(Xa@W1+b1))
    hipLaunchKernelGGL(k_scale_x4, gsz((long long)N * 16), B256, 0, stream, x, dinv, bufA, N);
    hipLaunchKernelGGL((k_agg4<64, 0>), dim3((N + 3) / 4), B256, 0, stream,
                       bufA, rowptr, deg, csrc, dinv, nil, nil, nil, nil, nil, bufB, N);
    hipLaunchKernelGGL((k_matmul4<64, 128, 1>), dim3((N + 7) / 8), B256, 0, stream,
                       bufB, W1, bufC, N, b1, g1, be1, m1, v1, nil);
    // layer 2: A2 = (H1@W2)*dinv ; H2 = relu(BN(dinv*sum(A2)+b2))
    hipLaunchKernelGGL((k_matmul4<128, 64, 2>), dim3((N + 15) / 16), B256, 0, stream,
                       bufC, W2, bufA, N, nil, nil, nil, nil, nil, dinv);
    hipLaunchKernelGGL((k_agg4<64, 1>), dim3((N + 3) / 4), B256, 0, stream,
                       bufA, rowptr, deg, csrc, dinv, b2, g2, be2, m2, v2, bufB, N);
    // layer 3: A3 = (H2@W3)*dinv ; H3 = relu(BN(dinv*sum(A3)+b3))
    hipLaunchKernelGGL((k_matmul4<64, 32, 2>), dim3((N + 31) / 32), B256, 0, stream,
                       bufB, W3, bufA, N, nil, nil, nil, nil, nil, dinv);
    hipLaunchKernelGGL((k_agg4<32, 1>), dim3((N + 3) / 4), B256, 0, stream,
                       bufA, rowptr, deg, csrc, dinv, b3, g3, be3, m3, v3, bufB, N);

    // GAT on H3 (bufB): coefs -> per-edge softmax weights -> gather + Wg epilogue
    hipLaunchKernelGGL(k_att2, gsz((long long)N * 4), B256, 0, stream,
                       bufB, Wg, ags, agd, a_s, a_d, N);
    hipLaunchKernelGGL(k_attw, dim3((N + 3) / 4), B256, 0, stream,
                       a_s, a_d, rowptr, deg, csrc, att, N);
    hipLaunchKernelGGL(k_gatg, dim3((N + 3) / 4), B256, 0, stream,
                       bufB, att, rowptr, deg, csrc, Wg, bg, bufA, N);

    // pool + classifier
    hipLaunchKernelGGL(k_pool_init, dim3(9), B256, 0, stream, pooled, cnt);
    hipLaunchKernelGGL(k_pool2, dim3(128), B256, 0, stream, bufA, batch, pooled, cnt, N);
    hipLaunchKernelGGL(k_classifier, dim3(1), B256, 0, stream, pooled, cnt, Wc1, bc1, Wc2, bc2, out);
}

// Round 5
// 694.397 us; speedup vs baseline: 5.1386x; 1.2243x over previous
//
#include <hip/hip_runtime.h>

#define EPSN   1e-5f
#define NEGS   0.2f
#define NGRAPH 64
#define BSHIFT 9
#define NPBK   512            // nodes per bucket = 1<<BSHIFT
#define GCAP   96             // GAT LDS edge cap per node

__device__ __forceinline__ float lrelu(float e) { return e > 0.f ? e : NEGS * e; }

// ===================== binned CSR build =====================
// pass 1: per-block LDS histogram of dst buckets -> global bucket_size
__global__ void k_bin_count(const int* __restrict__ ed, int* __restrict__ bsize,
                            int E, int NB) {
    __shared__ int lcnt[1024];
    for (int i = threadIdx.x; i < NB; i += 256) lcnt[i] = 0;
    __syncthreads();
    int chunk = (E + gridDim.x - 1) / gridDim.x;
    int lo = blockIdx.x * chunk;
    int hi = min(E, lo + chunk);
    for (int e = lo + threadIdx.x; e < hi; e += 256)
        atomicAdd(&lcnt[ed[e] >> BSHIFT], 1);
    __syncthreads();
    for (int b = threadIdx.x; b < NB; b += 256)
        if (lcnt[b]) atomicAdd(&bsize[b], lcnt[b]);
}
// pass 2: single-wave exclusive scan of bucket sizes -> bbase, gcur
__global__ void k_bucket_scan(const int* __restrict__ bsize, int* __restrict__ bbase,
                              int* __restrict__ gcur, int NB) {
    int lane = threadIdx.x;
    if (lane >= 64) return;
    int carry = 0;
    int rounds = (NB + 63) / 64;
    for (int r = 0; r < rounds; ++r) {
        int idx = r * 64 + lane;
        int orig = (idx < NB) ? bsize[idx] : 0;
        int v = orig;
#pragma unroll
        for (int o = 1; o < 64; o <<= 1) {
            int t = __shfl_up(v, o, 64);
            if (lane >= o) v += t;
        }
        if (idx < NB) {
            int excl = carry + v - orig;
            bbase[idx] = excl;
            gcur[idx] = excl;
        }
        carry += __shfl(v, 63, 64);
    }
}
// pass 3: write (s,t) into bucket regions (block-contiguous runs)
__global__ void k_bin_write(const int* __restrict__ es, const int* __restrict__ ed,
                            int* __restrict__ gcur, int2* __restrict__ binned,
                            int E, int NB) {
    __shared__ int lcnt[1024];
    __shared__ int lofs[1024];
    int chunk = (E + gridDim.x - 1) / gridDim.x;
    int lo = blockIdx.x * chunk;
    int hi = min(E, lo + chunk);
    for (int i = threadIdx.x; i < NB; i += 256) lcnt[i] = 0;
    __syncthreads();
    for (int e = lo + threadIdx.x; e < hi; e += 256)
        atomicAdd(&lcnt[ed[e] >> BSHIFT], 1);
    __syncthreads();
    for (int b = threadIdx.x; b < NB; b += 256) {
        int c = lcnt[b];
        lofs[b] = c ? atomicAdd(&gcur[b], c) : 0;
    }
    __syncthreads();
    for (int i = threadIdx.x; i < NB; i += 256) lcnt[i] = 0;
    __syncthreads();
    for (int e = lo + threadIdx.x; e < hi; e += 256) {
        int s = es[e], t = ed[e];
        int b = t >> BSHIFT;
        int pos = lofs[b] + atomicAdd(&lcnt[b], 1);
        binned[pos] = make_int2(s, t);
    }
}
// pass 4: one block per bucket -> local CSR in LDS, emit rowptr/deg/dinv/csrc
__global__ void k_csr_build(const int2* __restrict__ binned, const int* __restrict__ bbase,
                            const int* __restrict__ bsize, int* __restrict__ rowptr,
                            int* __restrict__ deg, float* __restrict__ dinv,
                            int* __restrict__ csrc, int N) {
    __shared__ int cnt_l[NPBK];
    __shared__ int ofs_l[NPBK];
    int b = blockIdx.x;
    int base = bbase[b];
    int cnt = bsize[b];
    int nlo = b << BSHIFT;
    int nhi = min(N, nlo + NPBK);
    int nv = nhi - nlo;
    int csrbase = base + nlo;       // self-loops of preceding buckets
    int tid = threadIdx.x;
    for (int i = tid; i < NPBK; i += 256) cnt_l[i] = (i < nv) ? 1 : 0;  // self-loop
    __syncthreads();
    for (int e = tid; e < cnt; e += 256) {
        int2 st = binned[base + e];
        atomicAdd(&cnt_l[st.y - nlo], 1);
    }
    __syncthreads();
    if (tid < 64) {                  // wave-0 exclusive scan over NPBK
        int carry = 0;
#pragma unroll
        for (int r = 0; r < NPBK / 64; ++r) {
            int idx = r * 64 + tid;
            int orig = cnt_l[idx];
            int v = orig;
#pragma unroll
            for (int o = 1; o < 64; o <<= 1) {
                int t = __shfl_up(v, o, 64);
                if (tid >= o) v += t;
            }
            ofs_l[idx] = carry + v - orig;
            carry += __shfl(v, 63, 64);
        }
    }
    __syncthreads();
    for (int i = tid; i < nv; i += 256) {
        int node = nlo + i;
        int d = cnt_l[i];
        rowptr[node] = csrbase + ofs_l[i];
        deg[node] = d;
        dinv[node] = rsqrtf((float)d);
    }
    __syncthreads();
    for (int i = tid; i < NPBK; i += 256) cnt_l[i] = ofs_l[i];  // cursors
    __syncthreads();
    for (int e = tid; e < cnt; e += 256) {
        int2 st = binned[base + e];
        int p = atomicAdd(&cnt_l[st.y - nlo], 1);
        csrc[csrbase + p] = st.x;
    }
    for (int i = tid; i < nv; i += 256) {   // self-loop entries
        int p = atomicAdd(&cnt_l[i], 1);
        csrc[csrbase + p] = nlo + i;
    }
}

// ===================== Xs = x * dinv[row] =====================
__global__ void k_scale_x4(const float* __restrict__ x, const float* __restrict__ dinv,
                           float* __restrict__ Xs, int n) {
    int total = n * 16;
    for (int q = blockIdx.x * blockDim.x + threadIdx.x; q < total;
         q += gridDim.x * blockDim.x) {
        float din = dinv[q >> 4];
        float4 xv = ((const float4*)x)[q];
        xv.x *= din; xv.y *= din; xv.z *= din; xv.w *= din;
        ((float4*)Xs)[q] = xv;
    }
}

// ===== dense matmul Y[n,M] = X[n,K] @ W[K,M], 4-col blocking, float4 =====
template <int K, int M, int EPI>
__global__ void k_matmul4(const float* __restrict__ X, const float* __restrict__ W,
                          float* __restrict__ Y, int n,
                          const float* __restrict__ b, const float* __restrict__ g,
                          const float* __restrict__ be, const float* __restrict__ m,
                          const float* __restrict__ v, const float* __restrict__ dinv) {
    __shared__ float Wl[K * M];
    for (int i = threadIdx.x; i < K * M / 4; i += 256)
        ((float4*)Wl)[i] = ((const float4*)W)[i];
    __syncthreads();
    const int TPR = M / 4;
    const int RPB = 256 / TPR;
    const int c4  = (threadIdx.x % TPR) * 4;
    int row = blockIdx.x * RPB + threadIdx.x / TPR;
    if (row >= n) return;
    const float4* xr = (const float4*)(X + (long long)row * K);
    float4 acc = make_float4(0.f, 0.f, 0.f, 0.f);
#pragma unroll
    for (int k4 = 0; k4 < K / 4; ++k4) {
        float4 xv = xr[k4];
        const float* wp = &Wl[(k4 * 4) * M + c4];
        float4 w0 = *(const float4*)(wp);
        float4 w1 = *(const float4*)(wp + M);
        float4 w2 = *(const float4*)(wp + 2 * M);
        float4 w3 = *(const float4*)(wp + 3 * M);
        acc.x += xv.x * w0.x + xv.y * w1.x + xv.z * w2.x + xv.w * w3.x;
        acc.y += xv.x * w0.y + xv.y * w1.y + xv.z * w2.y + xv.w * w3.y;
        acc.z += xv.x * w0.z + xv.y * w1.z + xv.z * w2.z + xv.w * w3.z;
        acc.w += xv.x * w0.w + xv.y * w1.w + xv.z * w2.w + xv.w * w3.w;
    }
    if (EPI == 1) {
        float4 bb = *(const float4*)(b + c4);
        float4 mm = *(const float4*)(m + c4);
        float4 vv = *(const float4*)(v + c4);
        float4 gg = *(const float4*)(g + c4);
        float4 ee = *(const float4*)(be + c4);
        acc.x = fmaxf((acc.x + bb.x - mm.x) * rsqrtf(vv.x + EPSN) * gg.x + ee.x, 0.f);
        acc.y = fmaxf((acc.y + bb.y - mm.y) * rsqrtf(vv.y + EPSN) * gg.y + ee.y, 0.f);
        acc.z = fmaxf((acc.z + bb.z - mm.z) * rsqrtf(vv.z + EPSN) * gg.z + ee.z, 0.f);
        acc.w = fmaxf((acc.w + bb.w - mm.w) * rsqrtf(vv.w + EPSN) * gg.w + ee.w, 0.f);
    } else if (EPI == 2) {
        float din = dinv[row];
        acc.x *= din; acc.y *= din; acc.z *= din; acc.w *= din;
    }
    *(float4*)(Y + (long long)row * M + c4) = acc;
}

// ===== CSR sum-aggregation, float4, multi-edge per wave =====
template <int M, int EPI>
__global__ void k_agg4(const float* __restrict__ A, const int* __restrict__ rowptr,
                       const int* __restrict__ deg, const int* __restrict__ csrc,
                       const float* __restrict__ dinv,
                       const float* __restrict__ b, const float* __restrict__ g,
                       const float* __restrict__ be, const float* __restrict__ m,
                       const float* __restrict__ v,
                       float* __restrict__ B, int n) {
    const int LPE = M / 4;
    const int EPW = 64 / LPE;
    int node = blockIdx.x * 4 + (threadIdx.x >> 6);
    if (node >= n) return;
    int lane = threadIdx.x & 63;
    int eg = lane / LPE;
    int dl = lane % LPE;
    int beg = rowptr[node];
    int end = beg + deg[node];
    float4 acc = make_float4(0.f, 0.f, 0.f, 0.f);
    for (int base = beg; base < end; base += EPW) {
        int i = base + eg;
        if (i < end) {
            int s = csrc[i];
            float4 xv = *(const float4*)(A + (long long)s * M + dl * 4);
            acc.x += xv.x; acc.y += xv.y; acc.z += xv.z; acc.w += xv.w;
        }
    }
#pragma unroll
    for (int off = LPE; off < 64; off <<= 1) {
        acc.x += __shfl_xor(acc.x, off);
        acc.y += __shfl_xor(acc.y, off);
        acc.z += __shfl_xor(acc.z, off);
        acc.w += __shfl_xor(acc.w, off);
    }
    if (eg == 0) {
        float din = dinv[node];
        acc.x *= din; acc.y *= din; acc.z *= din; acc.w *= din;
        if (EPI == 1) {
            int d0 = dl * 4;
            float4 bb = *(const float4*)(b + d0);
            float4 mm = *(const float4*)(m + d0);
            float4 vv = *(const float4*)(v + d0);
            float4 gg = *(const float4*)(g + d0);
            float4 ee = *(const float4*)(be + d0);
            acc.x = fmaxf((acc.x + bb.x - mm.x) * rsqrtf(vv.x + EPSN) * gg.x + ee.x, 0.f);
            acc.y = fmaxf((acc.y + bb.y - mm.y) * rsqrtf(vv.y + EPSN) * gg.y + ee.y, 0.f);
            acc.z = fmaxf((acc.z + bb.z - mm.z) * rsqrtf(vv.z + EPSN) * gg.z + ee.z, 0.f);
            acc.w = fmaxf((acc.w + bb.w - mm.w) * rsqrtf(vv.w + EPSN) * gg.w + ee.w, 0.f);
        }
        *(float4*)(B + (long long)node * M + dl * 4) = acc;
    }
}

// ===================== GAT attention coefs from H3 =====================
__global__ void k_att2(const float* __restrict__ H3, const float* __restrict__ Wg,
                       const float* __restrict__ ags, const float* __restrict__ agd,
                       float* __restrict__ a_s, float* __restrict__ a_d, int n) {
    __shared__ float Ws[32 * 4], Wd[32 * 4];
    for (int j = threadIdx.x; j < 128; j += 256) {
        int k = j >> 2, h = j & 3;
        float ss = 0.f, dd = 0.f;
        for (int d2 = 0; d2 < 32; ++d2) {
            float w = Wg[k * 128 + h * 32 + d2];
            ss += w * ags[h * 32 + d2];
            dd += w * agd[h * 32 + d2];
        }
        Ws[j] = ss; Wd[j] = dd;
    }
    __syncthreads();
    int total = n * 4;
    for (int i = blockIdx.x * blockDim.x + threadIdx.x; i < total;
         i += gridDim.x * blockDim.x) {
        int ni = i >> 2, h = i & 3;
        const float* hr = H3 + (long long)ni * 32;
        float xs = 0.f, xd = 0.f;
#pragma unroll
        for (int k = 0; k < 32; ++k) {
            float x = hr[k];
            xs += x * Ws[k * 4 + h];
            xd += x * Wd[k * 4 + h];
        }
        a_s[i] = xs;
        a_d[i] = xd;
    }
}

// ===== fused GAT: softmax (LDS-cached) + gather + Wg epilogue =====
// one wave per node; phase1 lanes: slot=lane>>2 (16), h=lane&3
// phase2 lanes: d=lane&31, h0=lane>>5 (heads h0, h0+2)
__global__ void k_gat3(const float* __restrict__ H3, const float* __restrict__ a_s,
                       const float* __restrict__ a_d, const int* __restrict__ rowptr,
                       const int* __restrict__ deg, const int* __restrict__ csrc,
                       const float* __restrict__ Wg, const float* __restrict__ bg,
                       float* __restrict__ H4, int n) {
    __shared__ float sc[4][4][GCAP];
    __shared__ int   srcb[4][GCAP];
    __shared__ float2 mi[4][4];      // {max, 0.25/sum} per head
    __shared__ float wb[4][128];
    int w = threadIdx.x >> 6;
    int node = blockIdx.x * 4 + w;
    int lane = threadIdx.x & 63;
    int beg = 0, cnt = 0;
    bool fits = false;
    if (node < n) {
        beg = rowptr[node];
        cnt = deg[node];
        fits = (cnt <= GCAP);
        int hh = lane & 3;
        int slot = lane >> 2;
        float ad = a_d[node * 4 + hh];
        float mx = -1e30f;
        if (fits) {
            for (int i = slot; i < cnt; i += 16) {
                int s = csrc[beg + i];
                if (hh == 0) srcb[w][i] = s;
                float e = lrelu(a_s[s * 4 + hh] + ad);
                sc[w][hh][i] = e;
                mx = fmaxf(mx, e);
            }
        } else {
            for (int i = slot; i < cnt; i += 16)
                mx = fmaxf(mx, lrelu(a_s[csrc[beg + i] * 4 + hh] + ad));
        }
        mx = fmaxf(mx, __shfl_xor(mx, 4));
        mx = fmaxf(mx, __shfl_xor(mx, 8));
        mx = fmaxf(mx, __shfl_xor(mx, 16));
        mx = fmaxf(mx, __shfl_xor(mx, 32));
        float sum = 0.f;
        if (fits) {
            for (int i = slot; i < cnt; i += 16) {
                float p = __expf(sc[w][hh][i] - mx);
                sc[w][hh][i] = p;
                sum += p;
            }
        } else {
            for (int i = slot; i < cnt; i += 16)
                sum += __expf(lrelu(a_s[csrc[beg + i] * 4 + hh] + ad) - mx);
        }
        sum += __shfl_xor(sum, 4);
        sum += __shfl_xor(sum, 8);
        sum += __shfl_xor(sum, 16);
        sum += __shfl_xor(sum, 32);
        if (slot == 0) mi[w][hh] = make_float2(mx, 0.25f / sum);
    }
    __syncthreads();
    int d = lane & 31;
    int h0 = lane >> 5;
    int h2 = h0 + 2;
    float a0 = 0.f, a1 = 0.f;
    if (node < n) {
        float inv0 = mi[w][h0].y;
        float inv2 = mi[w][h2].y;
        if (fits) {
            int i = 0;
            for (; i + 2 <= cnt; i += 2) {
                int s0 = srcb[w][i], s1 = srcb[w][i + 1];
                float x0 = H3[(long long)s0 * 32 + d];
                float x1 = H3[(long long)s1 * 32 + d];
                float w00 = sc[w][h0][i] * inv0,     w01 = sc[w][h2][i] * inv2;
                float w10 = sc[w][h0][i + 1] * inv0, w11 = sc[w][h2][i + 1] * inv2;
                a0 += w00 * x0 + w10 * x1;
                a1 += w01 * x0 + w11 * x1;
            }
            for (; i < cnt; ++i) {
                int s = srcb[w][i];
                float x = H3[(long long)s * 32 + d];
                a0 += sc[w][h0][i] * inv0 * x;
                a1 += sc[w][h2][i] * inv2 * x;
            }
        } else {
            float mx0 = mi[w][h0].x, mx2 = mi[w][h2].x;
            float ad0 = a_d[node * 4 + h0];
            float ad2 = a_d[node * 4 + h2];
            for (int i = 0; i < cnt; ++i) {
                int s = csrc[beg + i];
                float x = H3[(long long)s * 32 + d];
                float w0 = __expf(lrelu(a_s[s * 4 + h0] + ad0) - mx0) * inv0;
                float w1 = __expf(lrelu(a_s[s * 4 + h2] + ad2) - mx2) * inv2;
                a0 += w0 * x;
                a1 += w1 * x;
            }
        }
    }
    wb[w][lane] = a0;        // j = h0*32+d
    wb[w][64 + lane] = a1;   // j = (h0+2)*32+d
    __syncthreads();
    if (node < n) {
        int half = (lane >> 5) * 64;
        float o = 0.f;
#pragma unroll
        for (int j = 0; j < 64; ++j) {
            int jj = half + j;
            o += wb[w][jj] * Wg[(jj & 31) * 128 + (jj >> 5) * 32 + d];
        }
        o += __shfl_xor(o, 32);
        if (lane < 32)
            H4[(long long)node * 32 + d] = fmaxf(o + bg[d], 0.f);
    }
}

// ===================== pool =====================
__global__ void k_pool_init(float* __restrict__ pooled, float* __restrict__ cnt) {
    int i = blockIdx.x * blockDim.x + threadIdx.x;
    if (i < NGRAPH * 32) pooled[i] = 0.f;
    if (i < NGRAPH) cnt[i] = 0.f;
}
__global__ void k_pool2(const float* __restrict__ h, const int* __restrict__ batch,
                        float* __restrict__ pooled, float* __restrict__ cnt, int n) {
    __shared__ float lp[NGRAPH * 32];
    __shared__ float lc[NGRAPH];
    int tid = threadIdx.x;
    for (int i = tid; i < NGRAPH * 32; i += 256) lp[i] = 0.f;
    for (int i = tid; i < NGRAPH; i += 256) lc[i] = 0.f;
    __syncthreads();
    int per = (n + gridDim.x - 1) / gridDim.x;
    int lo = blockIdx.x * per;
    int hi = min(n, lo + per);
    for (long long i = (long long)lo * 32 + tid; i < (long long)hi * 32; i += 256) {
        int ni = (int)(i >> 5), dd = (int)(i & 31);
        int b = batch[ni];
        atomicAdd(&lp[b * 32 + dd], h[i]);
        if (dd == 0) atomicAdd(&lc[b], 1.f);
    }
    __syncthreads();
    for (int i = tid; i < NGRAPH * 32; i += 256)
        if (lp[i] != 0.f) atomicAdd(&pooled[i], lp[i]);
    for (int i = tid; i < NGRAPH; i += 256)
        if (lc[i] != 0.f) atomicAdd(&cnt[i], lc[i]);
}

// ===================== classifier =====================
__global__ void k_classifier(const float* __restrict__ pooled, const float* __restrict__ cnt,
                             const float* __restrict__ Wc1, const float* __restrict__ bc1,
                             const float* __restrict__ Wc2, const float* __restrict__ bc2,
                             float* __restrict__ out) {
    __shared__ float pl[NGRAPH * 32];
    __shared__ float t1[NGRAPH * 16];
    int tid = threadIdx.x;
    for (int i = tid; i < NGRAPH * 32; i += blockDim.x) {
        int g = i >> 5;
        pl[i] = pooled[i] / fmaxf(cnt[g], 1.f);
    }
    __syncthreads();
    for (int i = tid; i < NGRAPH * 16; i += blockDim.x) {
        int g = i >> 4, c = i & 15;
        float acc = bc1[c];
#pragma unroll
        for (int d = 0; d < 32; ++d) acc += pl[g * 32 + d] * Wc1[d * 16 + c];
        t1[i] = fmaxf(acc, 0.f);
    }
    __syncthreads();
    for (int i = tid; i < NGRAPH * 5; i += blockDim.x) {
        int g = i / 5, c = i % 5;
        float acc = bc2[c];
#pragma unroll
        for (int k = 0; k < 16; ++k) acc += t1[g * 16 + k] * Wc2[k * 5 + c];
        out[i] = acc;
    }
}

// ===================== launch =====================
static inline dim3 gsz(long long work, int block = 256) {
    long long g = (work + block - 1) / block;
    if (g > 262144) g = 262144;
    if (g < 1) g = 1;
    return dim3((unsigned)g);
}

extern "C" void kernel_launch(void* const* d_in, const int* in_sizes, int n_in,
                              void* d_out, int out_size, void* d_ws, size_t ws_size,
                              hipStream_t stream) {
    const float* x     = (const float*)d_in[0];
    const int*   ei    = (const int*)d_in[1];
    const int*   batch = (const int*)d_in[2];
    const float* W1 = (const float*)d_in[3];  const float* b1 = (const float*)d_in[4];
    const float* W2 = (const float*)d_in[5];  const float* b2 = (const float*)d_in[6];
    const float* W3 = (const float*)d_in[7];  const float* b3 = (const float*)d_in[8];
    const float* g1 = (const float*)d_in[9];  const float* be1 = (const float*)d_in[10];
    const float* m1 = (const float*)d_in[11]; const float* v1  = (const float*)d_in[12];
    const float* g2 = (const float*)d_in[13]; const float* be2 = (const float*)d_in[14];
    const float* m2 = (const float*)d_in[15]; const float* v2  = (const float*)d_in[16];
    const float* g3 = (const float*)d_in[17]; const float* be3 = (const float*)d_in[18];
    const float* m3 = (const float*)d_in[19]; const float* v3  = (const float*)d_in[20];
    const float* Wg  = (const float*)d_in[21];
    const float* ags = (const float*)d_in[22];
    const float* agd = (const float*)d_in[23];
    const float* bg  = (const float*)d_in[24];
    const float* Wc1 = (const float*)d_in[25]; const float* bc1 = (const float*)d_in[26];
    const float* Wc2 = (const float*)d_in[27]; const float* bc2 = (const float*)d_in[28];
    float* out = (float*)d_out;

    const int N = in_sizes[0] / 64;
    const int E = in_sizes[1] / 2;
    const int* esrc = ei;
    const int* edst = ei + E;
    const int NB = (N + NPBK - 1) >> BSHIFT;   // buckets (<=1024 assumed)

    size_t off = 0;
    auto take = [&](size_t bytes) -> void* {
        void* p = (char*)d_ws + off;
        off += bytes;
        off = (off + 255) & ~(size_t)255;
        return p;
    };
    int*   deg    = (int*)take((size_t)N * 4);
    float* dinv   = (float*)take((size_t)N * 4);
    int*   rowptr = (int*)take((size_t)N * 4);
    int*   bsize  = (int*)take((size_t)1024 * 4);
    int*   bbase  = (int*)take((size_t)1024 * 4);
    int*   gcur   = (int*)take((size_t)1024 * 4);
    int*   csrc   = (int*)take((size_t)(E + N) * 4);
    float* bufA   = (float*)take((size_t)N * 64 * 4);   // Xs -> A2 -> A3 -> H4
    float* bufB   = (float*)take((size_t)N * 64 * 4);   // Xa -> H2 -> H3
    float* bufC   = (float*)take((size_t)N * 128 * 4);  // binned (early) ; H1 (later)
    float* a_s    = (float*)take((size_t)N * 4 * 4);
    float* a_d    = (float*)take((size_t)N * 4 * 4);
    float* pooled = (float*)take((size_t)NGRAPH * 32 * 4);
    float* cnt    = (float*)take((size_t)NGRAPH * 4);
    int2*  binned = (int2*)bufC;   // E*8B <= N*128*4B; dead before H1 written
    (void)ws_size; (void)n_in; (void)out_size;

    const dim3 B256(256);
    const float* nil = nullptr;

    // ---- binned CSR build ----
    hipMemsetAsync(bsize, 0, (size_t)NB * 4, stream);
    hipLaunchKernelGGL(k_bin_count, dim3(512), B256, 0, stream, edst, bsize, E, NB);
    hipLaunchKernelGGL(k_bucket_scan, dim3(1), dim3(64), 0, stream, bsize, bbase, gcur, NB);
    hipLaunchKernelGGL(k_bin_write, dim3(512), B256, 0, stream, esrc, edst, gcur, binned, E, NB);
    hipLaunchKernelGGL(k_csr_build, dim3(NB), B256, 0, stream,
                       binned, bbase, bsize, rowptr, deg, dinv, csrc, N);

    // ---- layer 1 (aggregate-first): Xs = x*dinv ; Xa = dinv*sum ; H1 = relu(BN(Xa@W1+b1))
    hipLaunchKernelGGL(k_scale_x4, gsz((long long)N * 16), B256, 0, stream, x, dinv, bufA, N);
    hipLaunchKernelGGL((k_agg4<64, 0>), dim3((N + 3) / 4), B256, 0, stream,
                       bufA, rowptr, deg, csrc, dinv, nil, nil, nil, nil, nil, bufB, N);
    hipLaunchKernelGGL((k_matmul4<64, 128, 1>), dim3((N + 7) / 8), B256, 0, stream,
                       bufB, W1, bufC, N, b1, g1, be1, m1, v1, nil);
    // ---- layer 2
    hipLaunchKernelGGL((k_matmul4<128, 64, 2>), dim3((N + 15) / 16), B256, 0, stream,
                       bufC, W2, bufA, N, nil, nil, nil, nil, nil, dinv);
    hipLaunchKernelGGL((k_agg4<64, 1>), dim3((N + 3) / 4), B256, 0, stream,
                       bufA, rowptr, deg, csrc, dinv, b2, g2, be2, m2, v2, bufB, N);
    // ---- layer 3
    hipLaunchKernelGGL((k_matmul4<64, 32, 2>), dim3((N + 31) / 32), B256, 0, stream,
                       bufB, W3, bufA, N, nil, nil, nil, nil, nil, dinv);
    hipLaunchKernelGGL((k_agg4<32, 1>), dim3((N + 3) / 4), B256, 0, stream,
                       bufA, rowptr, deg, csrc, dinv, b3, g3, be3, m3, v3, bufB, N);

    // ---- GAT
    hipLaunchKernelGGL(k_att2, gsz((long long)N * 4), B256, 0, stream,
                       bufB, Wg, ags, agd, a_s, a_d, N);
    hipLaunchKernelGGL(k_gat3, dim3((N + 3) / 4), B256, 0, stream,
                       bufB, a_s, a_d, rowptr, deg, csrc, Wg, bg, bufA, N);

    // ---- pool + classifier
    hipLaunchKernelGGL(k_pool_init, dim3(9), B256, 0, stream, pooled, cnt);
    hipLaunchKernelGGL(k_pool2, dim3(128), B256, 0, stream, bufA, batch, pooled, cnt, N);
    hipLaunchKernelGGL(k_classifier, dim3(1), B256, 0, stream, pooled, cnt, Wc1, bc1, Wc2, bc2, out);
}

// Round 6
// 655.083 us; speedup vs baseline: 5.4470x; 1.0600x over previous
//
#include <hip/hip_runtime.h>

#define EPSN   1e-5f
#define NEGS   0.2f
#define NGRAPH 64
#define BSHIFT 9
#define NPBK   512            // nodes per bucket = 1<<BSHIFT
#define GCAP   96             // GAT LDS edge cap per node

__device__ __forceinline__ float lrelu(float e) { return e > 0.f ? e : NEGS * e; }

// ===================== binned CSR build =====================
__global__ void k_bin_count(const int* __restrict__ ed, int* __restrict__ bsize,
                            int E, int NB) {
    __shared__ int lcnt[1024];
    for (int i = threadIdx.x; i < NB; i += 256) lcnt[i] = 0;
    __syncthreads();
    int chunk = (E + gridDim.x - 1) / gridDim.x;
    int lo = blockIdx.x * chunk;
    int hi = min(E, lo + chunk);
    for (int e = lo + threadIdx.x; e < hi; e += 256)
        atomicAdd(&lcnt[ed[e] >> BSHIFT], 1);
    __syncthreads();
    for (int b = threadIdx.x; b < NB; b += 256)
        if (lcnt[b]) atomicAdd(&bsize[b], lcnt[b]);
}
__global__ void k_bucket_scan(const int* __restrict__ bsize, int* __restrict__ bbase,
                              int* __restrict__ gcur, int NB) {
    int lane = threadIdx.x;
    if (lane >= 64) return;
    int carry = 0;
    int rounds = (NB + 63) / 64;
    for (int r = 0; r < rounds; ++r) {
        int idx = r * 64 + lane;
        int orig = (idx < NB) ? bsize[idx] : 0;
        int v = orig;
#pragma unroll
        for (int o = 1; o < 64; o <<= 1) {
            int t = __shfl_up(v, o, 64);
            if (lane >= o) v += t;
        }
        if (idx < NB) {
            int excl = carry + v - orig;
            bbase[idx] = excl;
            gcur[idx] = excl;
        }
        carry += __shfl(v, 63, 64);
    }
}
__global__ void k_bin_write(const int* __restrict__ es, const int* __restrict__ ed,
                            int* __restrict__ gcur, int2* __restrict__ binned,
                            int E, int NB) {
    __shared__ int lcnt[1024];
    __shared__ int lofs[1024];
    int chunk = (E + gridDim.x - 1) / gridDim.x;
    int lo = blockIdx.x * chunk;
    int hi = min(E, lo + chunk);
    for (int i = threadIdx.x; i < NB; i += 256) lcnt[i] = 0;
    __syncthreads();
    for (int e = lo + threadIdx.x; e < hi; e += 256)
        atomicAdd(&lcnt[ed[e] >> BSHIFT], 1);
    __syncthreads();
    for (int b = threadIdx.x; b < NB; b += 256) {
        int c = lcnt[b];
        lofs[b] = c ? atomicAdd(&gcur[b], c) : 0;
    }
    __syncthreads();
    for (int i = threadIdx.x; i < NB; i += 256) lcnt[i] = 0;
    __syncthreads();
    for (int e = lo + threadIdx.x; e < hi; e += 256) {
        int s = es[e], t = ed[e];
        int b = t >> BSHIFT;
        int pos = lofs[b] + atomicAdd(&lcnt[b], 1);
        binned[pos] = make_int2(s, t);
    }
}
__global__ void k_csr_build(const int2* __restrict__ binned, const int* __restrict__ bbase,
                            const int* __restrict__ bsize, int* __restrict__ rowptr,
                            int* __restrict__ deg, float* __restrict__ dinv,
                            int* __restrict__ csrc, int N) {
    __shared__ int cnt_l[NPBK];
    __shared__ int ofs_l[NPBK];
    int b = blockIdx.x;
    int base = bbase[b];
    int cnt = bsize[b];
    int nlo = b << BSHIFT;
    int nhi = min(N, nlo + NPBK);
    int nv = nhi - nlo;
    int csrbase = base + nlo;
    int tid = threadIdx.x;
    for (int i = tid; i < NPBK; i += 256) cnt_l[i] = (i < nv) ? 1 : 0;
    __syncthreads();
    for (int e = tid; e < cnt; e += 256) {
        int2 st = binned[base + e];
        atomicAdd(&cnt_l[st.y - nlo], 1);
    }
    __syncthreads();
    if (tid < 64) {
        int carry = 0;
#pragma unroll
        for (int r = 0; r < NPBK / 64; ++r) {
            int idx = r * 64 + tid;
            int orig = cnt_l[idx];
            int v = orig;
#pragma unroll
            for (int o = 1; o < 64; o <<= 1) {
                int t = __shfl_up(v, o, 64);
                if (tid >= o) v += t;
            }
            ofs_l[idx] = carry + v - orig;
            carry += __shfl(v, 63, 64);
        }
    }
    __syncthreads();
    for (int i = tid; i < nv; i += 256) {
        int node = nlo + i;
        int d = cnt_l[i];
        rowptr[node] = csrbase + ofs_l[i];
        deg[node] = d;
        dinv[node] = rsqrtf((float)d);
    }
    __syncthreads();
    for (int i = tid; i < NPBK; i += 256) cnt_l[i] = ofs_l[i];
    __syncthreads();
    for (int e = tid; e < cnt; e += 256) {
        int2 st = binned[base + e];
        int p = atomicAdd(&cnt_l[st.y - nlo], 1);
        csrc[csrbase + p] = st.x;
    }
    for (int i = tid; i < nv; i += 256) {
        int p = atomicAdd(&cnt_l[i], 1);
        csrc[csrbase + p] = nlo + i;
    }
}

// ===== dense matmul Y[n,M] = X[n,K] @ W[K,M], 4-col blocking, float4 =====
template <int K, int M, int EPI>
__global__ void k_matmul4(const float* __restrict__ X, const float* __restrict__ W,
                          float* __restrict__ Y, int n,
                          const float* __restrict__ b, const float* __restrict__ g,
                          const float* __restrict__ be, const float* __restrict__ m,
                          const float* __restrict__ v, const float* __restrict__ dinv) {
    __shared__ float Wl[K * M];
    for (int i = threadIdx.x; i < K * M / 4; i += 256)
        ((float4*)Wl)[i] = ((const float4*)W)[i];
    __syncthreads();
    const int TPR = M / 4;
    const int RPB = 256 / TPR;
    const int c4  = (threadIdx.x % TPR) * 4;
    int row = blockIdx.x * RPB + threadIdx.x / TPR;
    if (row >= n) return;
    const float4* xr = (const float4*)(X + (long long)row * K);
    float4 acc = make_float4(0.f, 0.f, 0.f, 0.f);
#pragma unroll
    for (int k4 = 0; k4 < K / 4; ++k4) {
        float4 xv = xr[k4];
        const float* wp = &Wl[(k4 * 4) * M + c4];
        float4 w0 = *(const float4*)(wp);
        float4 w1 = *(const float4*)(wp + M);
        float4 w2 = *(const float4*)(wp + 2 * M);
        float4 w3 = *(const float4*)(wp + 3 * M);
        acc.x += xv.x * w0.x + xv.y * w1.x + xv.z * w2.x + xv.w * w3.x;
        acc.y += xv.x * w0.y + xv.y * w1.y + xv.z * w2.y + xv.w * w3.y;
        acc.z += xv.x * w0.z + xv.y * w1.z + xv.z * w2.z + xv.w * w3.z;
        acc.w += xv.x * w0.w + xv.y * w1.w + xv.z * w2.w + xv.w * w3.w;
    }
    if (EPI == 1) {
        float4 bb = *(const float4*)(b + c4);
        float4 mm = *(const float4*)(m + c4);
        float4 vv = *(const float4*)(v + c4);
        float4 gg = *(const float4*)(g + c4);
        float4 ee = *(const float4*)(be + c4);
        acc.x = fmaxf((acc.x + bb.x - mm.x) * rsqrtf(vv.x + EPSN) * gg.x + ee.x, 0.f);
        acc.y = fmaxf((acc.y + bb.y - mm.y) * rsqrtf(vv.y + EPSN) * gg.y + ee.y, 0.f);
        acc.z = fmaxf((acc.z + bb.z - mm.z) * rsqrtf(vv.z + EPSN) * gg.z + ee.z, 0.f);
        acc.w = fmaxf((acc.w + bb.w - mm.w) * rsqrtf(vv.w + EPSN) * gg.w + ee.w, 0.f);
    } else if (EPI == 2) {
        float din = dinv[row];
        acc.x *= din; acc.y *= din; acc.z *= din; acc.w *= din;
    }
    *(float4*)(Y + (long long)row * M + c4) = acc;
}

// ===== CSR sum-aggregation, float4, multi-edge per wave, unroll-2 =====
// PRE=1: scale each gathered row by dinv[s] (for layer-1 reading raw x)
template <int M, int EPI, int PRE>
__global__ void k_agg4(const float* __restrict__ A, const int* __restrict__ rowptr,
                       const int* __restrict__ deg, const int* __restrict__ csrc,
                       const float* __restrict__ dinv,
                       const float* __restrict__ b, const float* __restrict__ g,
                       const float* __restrict__ be, const float* __restrict__ m,
                       const float* __restrict__ v,
                       float* __restrict__ B, int n) {
    const int LPE = M / 4;
    const int EPW = 64 / LPE;
    int node = blockIdx.x * 4 + (threadIdx.x >> 6);
    if (node >= n) return;
    int lane = threadIdx.x & 63;
    int eg = lane / LPE;
    int dl = lane % LPE;
    int beg = rowptr[node];
    int end = beg + deg[node];
    float4 acc = make_float4(0.f, 0.f, 0.f, 0.f);
    int i = beg + eg;
    for (; i + EPW < end; i += 2 * EPW) {
        int s0 = csrc[i];
        int s1 = csrc[i + EPW];
        float4 x0 = *(const float4*)(A + (long long)s0 * M + dl * 4);
        float4 x1 = *(const float4*)(A + (long long)s1 * M + dl * 4);
        if (PRE) {
            float w0 = dinv[s0], w1 = dinv[s1];
            x0.x *= w0; x0.y *= w0; x0.z *= w0; x0.w *= w0;
            x1.x *= w1; x1.y *= w1; x1.z *= w1; x1.w *= w1;
        }
        acc.x += x0.x + x1.x; acc.y += x0.y + x1.y;
        acc.z += x0.z + x1.z; acc.w += x0.w + x1.w;
    }
    if (i < end) {
        int s = csrc[i];
        float4 xv = *(const float4*)(A + (long long)s * M + dl * 4);
        if (PRE) {
            float w0 = dinv[s];
            xv.x *= w0; xv.y *= w0; xv.z *= w0; xv.w *= w0;
        }
        acc.x += xv.x; acc.y += xv.y; acc.z += xv.z; acc.w += xv.w;
    }
#pragma unroll
    for (int off = LPE; off < 64; off <<= 1) {
        acc.x += __shfl_xor(acc.x, off);
        acc.y += __shfl_xor(acc.y, off);
        acc.z += __shfl_xor(acc.z, off);
        acc.w += __shfl_xor(acc.w, off);
    }
    if (eg == 0) {
        float din = dinv[node];
        acc.x *= din; acc.y *= din; acc.z *= din; acc.w *= din;
        if (EPI == 1) {
            int d0 = dl * 4;
            float4 bb = *(const float4*)(b + d0);
            float4 mm = *(const float4*)(m + d0);
            float4 vv = *(const float4*)(v + d0);
            float4 gg = *(const float4*)(g + d0);
            float4 ee = *(const float4*)(be + d0);
            acc.x = fmaxf((acc.x + bb.x - mm.x) * rsqrtf(vv.x + EPSN) * gg.x + ee.x, 0.f);
            acc.y = fmaxf((acc.y + bb.y - mm.y) * rsqrtf(vv.y + EPSN) * gg.y + ee.y, 0.f);
            acc.z = fmaxf((acc.z + bb.z - mm.z) * rsqrtf(vv.z + EPSN) * gg.z + ee.z, 0.f);
            acc.w = fmaxf((acc.w + bb.w - mm.w) * rsqrtf(vv.w + EPSN) * gg.w + ee.w, 0.f);
        }
        *(float4*)(B + (long long)node * M + dl * 4) = acc;
    }
}

// ===== tiny: Ws/Wd = Wg folded with ags/agd -> wsd[2][32][4] =====
__global__ void k_wsd(const float* __restrict__ Wg, const float* __restrict__ ags,
                      const float* __restrict__ agd, float* __restrict__ wsd) {
    int j = threadIdx.x;
    if (j < 128) {
        int k = j >> 2, h = j & 3;
        float ss = 0.f, dd = 0.f;
        for (int d2 = 0; d2 < 32; ++d2) {
            float wv = Wg[k * 128 + h * 32 + d2];
            ss += wv * ags[h * 32 + d2];
            dd += wv * agd[h * 32 + d2];
        }
        wsd[j] = ss;         // Ws[k][h]
        wsd[128 + j] = dd;   // Wd[k][h]
    }
}

// ===== layer-3 agg (M=32) + BN/ReLU + fused attention-coef epilogue =====
__global__ void k_agg_att(const float* __restrict__ A, const int* __restrict__ rowptr,
                          const int* __restrict__ deg, const int* __restrict__ csrc,
                          const float* __restrict__ dinv,
                          const float* __restrict__ b, const float* __restrict__ g,
                          const float* __restrict__ be, const float* __restrict__ m,
                          const float* __restrict__ v, const float* __restrict__ wsd,
                          float* __restrict__ H3, float* __restrict__ a_s,
                          float* __restrict__ a_d, int n) {
    __shared__ float Wl[256];
    for (int i = threadIdx.x; i < 256; i += 256) Wl[i] = wsd[i];
    __syncthreads();
    const int M = 32, LPE = 8, EPW = 8;
    int node = blockIdx.x * 4 + (threadIdx.x >> 6);
    if (node >= n) return;
    int lane = threadIdx.x & 63;
    int eg = lane >> 3;
    int dl = lane & 7;
    int beg = rowptr[node];
    int end = beg + deg[node];
    float4 acc = make_float4(0.f, 0.f, 0.f, 0.f);
    int i = beg + eg;
    for (; i + EPW < end; i += 2 * EPW) {
        int s0 = csrc[i];
        int s1 = csrc[i + EPW];
        float4 x0 = *(const float4*)(A + (long long)s0 * M + dl * 4);
        float4 x1 = *(const float4*)(A + (long long)s1 * M + dl * 4);
        acc.x += x0.x + x1.x; acc.y += x0.y + x1.y;
        acc.z += x0.z + x1.z; acc.w += x0.w + x1.w;
    }
    if (i < end) {
        int s = csrc[i];
        float4 xv = *(const float4*)(A + (long long)s * M + dl * 4);
        acc.x += xv.x; acc.y += xv.y; acc.z += xv.z; acc.w += xv.w;
    }
#pragma unroll
    for (int off = 8; off < 64; off <<= 1) {
        acc.x += __shfl_xor(acc.x, off);
        acc.y += __shfl_xor(acc.y, off);
        acc.z += __shfl_xor(acc.z, off);
        acc.w += __shfl_xor(acc.w, off);
    }
    // all lanes now hold the full sum for their dl chunk; finish BN+ReLU
    float din = dinv[node];
    int d0 = dl * 4;
    float4 bb = *(const float4*)(b + d0);
    float4 mm = *(const float4*)(m + d0);
    float4 vv = *(const float4*)(v + d0);
    float4 gg = *(const float4*)(g + d0);
    float4 ee = *(const float4*)(be + d0);
    float4 hv;
    hv.x = fmaxf((acc.x * din + bb.x - mm.x) * rsqrtf(vv.x + EPSN) * gg.x + ee.x, 0.f);
    hv.y = fmaxf((acc.y * din + bb.y - mm.y) * rsqrtf(vv.y + EPSN) * gg.y + ee.y, 0.f);
    hv.z = fmaxf((acc.z * din + bb.z - mm.z) * rsqrtf(vv.z + EPSN) * gg.z + ee.z, 0.f);
    hv.w = fmaxf((acc.w * din + bb.w - mm.w) * rsqrtf(vv.w + EPSN) * gg.w + ee.w, 0.f);
    if (eg == 0)
        *(float4*)(H3 + (long long)node * M + d0) = hv;
    // attention coefs: lane l<8 computes (sel=l>>2, h=l&3); all lanes help via shfl
    int h = lane & 3, sel = (lane >> 2) & 1;
    const float* wp = &Wl[sel * 128];
    float o = 0.f;
#pragma unroll
    for (int src = 0; src < 8; ++src) {
        float bx = __shfl(hv.x, src);
        float by = __shfl(hv.y, src);
        float bz = __shfl(hv.z, src);
        float bw = __shfl(hv.w, src);
        int k0 = src * 4;
        o += bx * wp[k0 * 4 + h] + by * wp[(k0 + 1) * 4 + h] +
             bz * wp[(k0 + 2) * 4 + h] + bw * wp[(k0 + 3) * 4 + h];
    }
    if (lane < 4) a_s[node * 4 + h] = o;
    else if (lane < 8) a_d[node * 4 + h] = o;
}

// ===== fused GAT v2: edge-per-lane softmax + unrolled gather + Wg epilogue =====
// no __syncthreads: each wave owns its LDS slice
__global__ void k_gat4(const float* __restrict__ H3, const float* __restrict__ a_s,
                       const float* __restrict__ a_d, const int* __restrict__ rowptr,
                       const int* __restrict__ deg, const int* __restrict__ csrc,
                       const float* __restrict__ Wg, const float* __restrict__ bg,
                       float* __restrict__ H4, int n) {
    __shared__ float sc[4][GCAP * 4];   // [w][e*4+h]
    __shared__ int   srcb[4][GCAP];
    __shared__ float wb[4][128];
    int w = threadIdx.x >> 6;
    int node = blockIdx.x * 4 + w;
    if (node >= n) return;
    int lane = threadIdx.x & 63;
    int beg = rowptr[node];
    int cnt = deg[node];
    bool fits = (cnt <= GCAP);
    float4 ad4 = ((const float4*)a_d)[node];
    float m0 = -1e30f, m1 = -1e30f, m2 = -1e30f, m3 = -1e30f;
    if (fits) {
        for (int e = lane; e < cnt; e += 64) {
            int s = csrc[beg + e];
            srcb[w][e] = s;
            float4 as = ((const float4*)a_s)[s];
            float e0 = lrelu(as.x + ad4.x);
            float e1 = lrelu(as.y + ad4.y);
            float e2 = lrelu(as.z + ad4.z);
            float e3 = lrelu(as.w + ad4.w);
            *(float4*)&sc[w][e * 4] = make_float4(e0, e1, e2, e3);
            m0 = fmaxf(m0, e0); m1 = fmaxf(m1, e1);
            m2 = fmaxf(m2, e2); m3 = fmaxf(m3, e3);
        }
    } else {
        for (int e = lane; e < cnt; e += 64) {
            int s = csrc[beg + e];
            float4 as = ((const float4*)a_s)[s];
            m0 = fmaxf(m0, lrelu(as.x + ad4.x));
            m1 = fmaxf(m1, lrelu(as.y + ad4.y));
            m2 = fmaxf(m2, lrelu(as.z + ad4.z));
            m3 = fmaxf(m3, lrelu(as.w + ad4.w));
        }
    }
#pragma unroll
    for (int o = 1; o < 64; o <<= 1) {
        m0 = fmaxf(m0, __shfl_xor(m0, o));
        m1 = fmaxf(m1, __shfl_xor(m1, o));
        m2 = fmaxf(m2, __shfl_xor(m2, o));
        m3 = fmaxf(m3, __shfl_xor(m3, o));
    }
    float s0 = 0.f, s1 = 0.f, s2 = 0.f, s3 = 0.f;
    if (fits) {
        for (int e = lane; e < cnt; e += 64) {
            float4 sv = *(float4*)&sc[w][e * 4];
            float p0 = __expf(sv.x - m0);
            float p1 = __expf(sv.y - m1);
            float p2 = __expf(sv.z - m2);
            float p3 = __expf(sv.w - m3);
            *(float4*)&sc[w][e * 4] = make_float4(p0, p1, p2, p3);
            s0 += p0; s1 += p1; s2 += p2; s3 += p3;
        }
    } else {
        for (int e = lane; e < cnt; e += 64) {
            int s = csrc[beg + e];
            float4 as = ((const float4*)a_s)[s];
            s0 += __expf(lrelu(as.x + ad4.x) - m0);
            s1 += __expf(lrelu(as.y + ad4.y) - m1);
            s2 += __expf(lrelu(as.z + ad4.z) - m2);
            s3 += __expf(lrelu(as.w + ad4.w) - m3);
        }
    }
#pragma unroll
    for (int o = 1; o < 64; o <<= 1) {
        s0 += __shfl_xor(s0, o);
        s1 += __shfl_xor(s1, o);
        s2 += __shfl_xor(s2, o);
        s3 += __shfl_xor(s3, o);
    }
    float inv0 = 0.25f / s0, inv1 = 0.25f / s1, inv2 = 0.25f / s2, inv3 = 0.25f / s3;
    // phase 2
    int d = lane & 31;
    int h0 = lane >> 5;           // heads h0 and h0+2
    float invA = (h0 == 0) ? inv0 : inv1;
    float invB = (h0 == 0) ? inv2 : inv3;
    float a0 = 0.f, a1 = 0.f;
    if (fits) {
        int i = 0;
        for (; i + 4 <= cnt; i += 4) {
            int sA = srcb[w][i],     sB = srcb[w][i + 1];
            int sC = srcb[w][i + 2], sD = srcb[w][i + 3];
            float x0 = H3[(long long)sA * 32 + d];
            float x1 = H3[(long long)sB * 32 + d];
            float x2 = H3[(long long)sC * 32 + d];
            float x3 = H3[(long long)sD * 32 + d];
            float wA0 = sc[w][i * 4 + h0],       wA1 = sc[w][i * 4 + h0 + 2];
            float wB0 = sc[w][(i + 1) * 4 + h0], wB1 = sc[w][(i + 1) * 4 + h0 + 2];
            float wC0 = sc[w][(i + 2) * 4 + h0], wC1 = sc[w][(i + 2) * 4 + h0 + 2];
            float wD0 = sc[w][(i + 3) * 4 + h0], wD1 = sc[w][(i + 3) * 4 + h0 + 2];
            a0 += wA0 * x0 + wB0 * x1 + wC0 * x2 + wD0 * x3;
            a1 += wA1 * x0 + wB1 * x1 + wC1 * x2 + wD1 * x3;
        }
        for (; i < cnt; ++i) {
            int s = srcb[w][i];
            float x = H3[(long long)s * 32 + d];
            a0 += sc[w][i * 4 + h0] * x;
            a1 += sc[w][i * 4 + h0 + 2] * x;
        }
        a0 *= invA; a1 *= invB;
    } else {
        float mA = (h0 == 0) ? m0 : m1;
        float mB = (h0 == 0) ? m2 : m3;
        float adA = (h0 == 0) ? ad4.x : ad4.y;
        float adB = (h0 == 0) ? ad4.z : ad4.w;
        for (int i = 0; i < cnt; ++i) {
            int s = csrc[beg + i];
            float4 as = ((const float4*)a_s)[s];
            float eA = (h0 == 0) ? (as.x + adA) : (as.y + adA);
            float eB = (h0 == 0) ? (as.z + adB) : (as.w + adB);
            float x = H3[(long long)s * 32 + d];
            a0 += __expf(lrelu(eA) - mA) * x;
            a1 += __expf(lrelu(eB) - mB) * x;
        }
        a0 *= invA; a1 *= invB;
    }
    wb[w][lane] = a0;        // j = h0*32+d
    wb[w][64 + lane] = a1;   // j = (h0+2)*32+d
    int half = h0 * 64;
    float o = 0.f;
#pragma unroll
    for (int j = 0; j < 64; ++j) {
        int jj = half + j;
        o += wb[w][jj] * Wg[(jj & 31) * 128 + (jj >> 5) * 32 + d];
    }
    o += __shfl_xor(o, 32);
    if (lane < 32)
        H4[(long long)node * 32 + d] = fmaxf(o + bg[d], 0.f);
}

// ===================== pool =====================
__global__ void k_pool_init(float* __restrict__ pooled, float* __restrict__ cnt) {
    int i = blockIdx.x * blockDim.x + threadIdx.x;
    if (i < NGRAPH * 32) pooled[i] = 0.f;
    if (i < NGRAPH) cnt[i] = 0.f;
}
__global__ void k_pool2(const float* __restrict__ h, const int* __restrict__ batch,
                        float* __restrict__ pooled, float* __restrict__ cnt, int n) {
    __shared__ float lp[NGRAPH * 32];
    __shared__ float lc[NGRAPH];
    int tid = threadIdx.x;
    for (int i = tid; i < NGRAPH * 32; i += 256) lp[i] = 0.f;
    for (int i = tid; i < NGRAPH; i += 256) lc[i] = 0.f;
    __syncthreads();
    int per = (n + gridDim.x - 1) / gridDim.x;
    int lo = blockIdx.x * per;
    int hi = min(n, lo + per);
    for (long long i = (long long)lo * 32 + tid; i < (long long)hi * 32; i += 256) {
        int ni = (int)(i >> 5), dd = (int)(i & 31);
        int b = batch[ni];
        atomicAdd(&lp[b * 32 + dd], h[i]);
        if (dd == 0) atomicAdd(&lc[b], 1.f);
    }
    __syncthreads();
    for (int i = tid; i < NGRAPH * 32; i += 256)
        if (lp[i] != 0.f) atomicAdd(&pooled[i], lp[i]);
    for (int i = tid; i < NGRAPH; i += 256)
        if (lc[i] != 0.f) atomicAdd(&cnt[i], lc[i]);
}

// ===================== classifier =====================
__global__ void k_classifier(const float* __restrict__ pooled, const float* __restrict__ cnt,
                             const float* __restrict__ Wc1, const float* __restrict__ bc1,
                             const float* __restrict__ Wc2, const float* __restrict__ bc2,
                             float* __restrict__ out) {
    __shared__ float pl[NGRAPH * 32];
    __shared__ float t1[NGRAPH * 16];
    int tid = threadIdx.x;
    for (int i = tid; i < NGRAPH * 32; i += blockDim.x) {
        int g = i >> 5;
        pl[i] = pooled[i] / fmaxf(cnt[g], 1.f);
    }
    __syncthreads();
    for (int i = tid; i < NGRAPH * 16; i += blockDim.x) {
        int g = i >> 4, c = i & 15;
        float acc = bc1[c];
#pragma unroll
        for (int d = 0; d < 32; ++d) acc += pl[g * 32 + d] * Wc1[d * 16 + c];
        t1[i] = fmaxf(acc, 0.f);
    }
    __syncthreads();
    for (int i = tid; i < NGRAPH * 5; i += blockDim.x) {
        int g = i / 5, c = i % 5;
        float acc = bc2[c];
#pragma unroll
        for (int k = 0; k < 16; ++k) acc += t1[g * 16 + k] * Wc2[k * 5 + c];
        out[i] = acc;
    }
}

// ===================== launch =====================
static inline dim3 gsz(long long work, int block = 256) {
    long long g = (work + block - 1) / block;
    if (g > 262144) g = 262144;
    if (g < 1) g = 1;
    return dim3((unsigned)g);
}

extern "C" void kernel_launch(void* const* d_in, const int* in_sizes, int n_in,
                              void* d_out, int out_size, void* d_ws, size_t ws_size,
                              hipStream_t stream) {
    const float* x     = (const float*)d_in[0];
    const int*   ei    = (const int*)d_in[1];
    const int*   batch = (const int*)d_in[2];
    const float* W1 = (const float*)d_in[3];  const float* b1 = (const float*)d_in[4];
    const float* W2 = (const float*)d_in[5];  const float* b2 = (const float*)d_in[6];
    const float* W3 = (const float*)d_in[7];  const float* b3 = (const float*)d_in[8];
    const float* g1 = (const float*)d_in[9];  const float* be1 = (const float*)d_in[10];
    const float* m1 = (const float*)d_in[11]; const float* v1  = (const float*)d_in[12];
    const float* g2 = (const float*)d_in[13]; const float* be2 = (const float*)d_in[14];
    const float* m2 = (const float*)d_in[15]; const float* v2  = (const float*)d_in[16];
    const float* g3 = (const float*)d_in[17]; const float* be3 = (const float*)d_in[18];
    const float* m3 = (const float*)d_in[19]; const float* v3  = (const float*)d_in[20];
    const float* Wg  = (const float*)d_in[21];
    const float* ags = (const float*)d_in[22];
    const float* agd = (const float*)d_in[23];
    const float* bg  = (const float*)d_in[24];
    const float* Wc1 = (const float*)d_in[25]; const float* bc1 = (const float*)d_in[26];
    const float* Wc2 = (const float*)d_in[27]; const float* bc2 = (const float*)d_in[28];
    float* out = (float*)d_out;

    const int N = in_sizes[0] / 64;
    const int E = in_sizes[1] / 2;
    const int* esrc = ei;
    const int* edst = ei + E;
    const int NB = (N + NPBK - 1) >> BSHIFT;

    size_t off = 0;
    auto take = [&](size_t bytes) -> void* {
        void* p = (char*)d_ws + off;
        off += bytes;
        off = (off + 255) & ~(size_t)255;
        return p;
    };
    int*   deg    = (int*)take((size_t)N * 4);
    float* dinv   = (float*)take((size_t)N * 4);
    int*   rowptr = (int*)take((size_t)N * 4);
    int*   bsize  = (int*)take((size_t)1024 * 4);
    int*   bbase  = (int*)take((size_t)1024 * 4);
    int*   gcur   = (int*)take((size_t)1024 * 4);
    float* wsd    = (float*)take((size_t)256 * 4);
    int*   csrc   = (int*)take((size_t)(E + N) * 4);
    float* bufA   = (float*)take((size_t)N * 64 * 4);   // A2 -> A3 -> H4
    float* bufB   = (float*)take((size_t)N * 64 * 4);   // Xa -> H2 -> H3
    float* bufC   = (float*)take((size_t)N * 128 * 4);  // binned (early) ; H1 (later)
    float* a_s    = (float*)take((size_t)N * 4 * 4);
    float* a_d    = (float*)take((size_t)N * 4 * 4);
    float* pooled = (float*)take((size_t)NGRAPH * 32 * 4);
    float* cnt    = (float*)take((size_t)NGRAPH * 4);
    int2*  binned = (int2*)bufC;
    (void)ws_size; (void)n_in; (void)out_size;

    const dim3 B256(256);
    const float* nil = nullptr;

    // ---- binned CSR build ----
    hipMemsetAsync(bsize, 0, (size_t)NB * 4, stream);
    hipLaunchKernelGGL(k_bin_count, dim3(512), B256, 0, stream, edst, bsize, E, NB);
    hipLaunchKernelGGL(k_bucket_scan, dim3(1), dim3(64), 0, stream, bsize, bbase, gcur, NB);
    hipLaunchKernelGGL(k_bin_write, dim3(512), B256, 0, stream, esrc, edst, gcur, binned, E, NB);
    hipLaunchKernelGGL(k_csr_build, dim3(NB), B256, 0, stream,
                       binned, bbase, bsize, rowptr, deg, dinv, csrc, N);
    hipLaunchKernelGGL(k_wsd, dim3(1), dim3(128), 0, stream, Wg, ags, agd, wsd);

    // ---- layer 1 (aggregate-first, dinv[s] fused into gather)
    hipLaunchKernelGGL((k_agg4<64, 0, 1>), dim3((N + 3) / 4), B256, 0, stream,
                       x, rowptr, deg, csrc, dinv, nil, nil, nil, nil, nil, bufB, N);
    hipLaunchKernelGGL((k_matmul4<64, 128, 1>), dim3((N + 7) / 8), B256, 0, stream,
                       bufB, W1, bufC, N, b1, g1, be1, m1, v1, nil);
    // ---- layer 2
    hipLaunchKernelGGL((k_matmul4<128, 64, 2>), dim3((N + 15) / 16), B256, 0, stream,
                       bufC, W2, bufA, N, nil, nil, nil, nil, nil, dinv);
    hipLaunchKernelGGL((k_agg4<64, 1, 0>), dim3((N + 3) / 4), B256, 0, stream,
                       bufA, rowptr, deg, csrc, dinv, b2, g2, be2, m2, v2, bufB, N);
    // ---- layer 3 (+ fused attention coefs)
    hipLaunchKernelGGL((k_matmul4<64, 32, 2>), dim3((N + 31) / 32), B256, 0, stream,
                       bufB, W3, bufA, N, nil, nil, nil, nil, nil, dinv);
    hipLaunchKernelGGL(k_agg_att, dim3((N + 3) / 4), B256, 0, stream,
                       bufA, rowptr, deg, csrc, dinv, b3, g3, be3, m3, v3,
                       wsd, bufB, a_s, a_d, N);

    // ---- GAT
    hipLaunchKernelGGL(k_gat4, dim3((N + 3) / 4), B256, 0, stream,
                       bufB, a_s, a_d, rowptr, deg, csrc, Wg, bg, bufA, N);

    // ---- pool + classifier
    hipLaunchKernelGGL(k_pool_init, dim3(9), B256, 0, stream, pooled, cnt);
    hipLaunchKernelGGL(k_pool2, dim3(128), B256, 0, stream, bufA, batch, pooled, cnt, N);
    hipLaunchKernelGGL(k_classifier, dim3(1), B256, 0, stream, pooled, cnt, Wc1, bc1, Wc2, bc2, out);
}

// Round 7
// 633.099 us; speedup vs baseline: 5.6361x; 1.0347x over previous
//
#include <hip/hip_runtime.h>

#define EPSN   1e-5f
#define NEGS   0.2f
#define NGRAPH 64
#define BSHIFT 9
#define NPBK   512            // nodes per bucket = 1<<BSHIFT
#define GCAP   96             // GAT LDS edge cap per node

typedef _Float16 half_t;
typedef _Float16 halfv8 __attribute__((ext_vector_type(8)));
typedef _Float16 halfv4 __attribute__((ext_vector_type(4)));
typedef _Float16 halfv2 __attribute__((ext_vector_type(2)));

__device__ __forceinline__ float lrelu(float e) { return e > 0.f ? e : NEGS * e; }

// ===================== binned CSR build =====================
__global__ void k_bin_count(const int* __restrict__ ed, int* __restrict__ bsize,
                            int E, int NB) {
    __shared__ int lcnt[1024];
    for (int i = threadIdx.x; i < NB; i += 256) lcnt[i] = 0;
    __syncthreads();
    int chunk = (E + gridDim.x - 1) / gridDim.x;
    int lo = blockIdx.x * chunk;
    int hi = min(E, lo + chunk);
    for (int e = lo + threadIdx.x; e < hi; e += 256)
        atomicAdd(&lcnt[ed[e] >> BSHIFT], 1);
    __syncthreads();
    for (int b = threadIdx.x; b < NB; b += 256)
        if (lcnt[b]) atomicAdd(&bsize[b], lcnt[b]);
}
__global__ void k_bucket_scan(const int* __restrict__ bsize, int* __restrict__ bbase,
                              int* __restrict__ gcur, int NB) {
    int lane = threadIdx.x;
    if (lane >= 64) return;
    int carry = 0;
    int rounds = (NB + 63) / 64;
    for (int r = 0; r < rounds; ++r) {
        int idx = r * 64 + lane;
        int orig = (idx < NB) ? bsize[idx] : 0;
        int v = orig;
#pragma unroll
        for (int o = 1; o < 64; o <<= 1) {
            int t = __shfl_up(v, o, 64);
            if (lane >= o) v += t;
        }
        if (idx < NB) {
            int excl = carry + v - orig;
            bbase[idx] = excl;
            gcur[idx] = excl;
        }
        carry += __shfl(v, 63, 64);
    }
}
__global__ void k_bin_write(const int* __restrict__ es, const int* __restrict__ ed,
                            int* __restrict__ gcur, int2* __restrict__ binned,
                            int E, int NB) {
    __shared__ int lcnt[1024];
    __shared__ int lofs[1024];
    int chunk = (E + gridDim.x - 1) / gridDim.x;
    int lo = blockIdx.x * chunk;
    int hi = min(E, lo + chunk);
    for (int i = threadIdx.x; i < NB; i += 256) lcnt[i] = 0;
    __syncthreads();
    for (int e = lo + threadIdx.x; e < hi; e += 256)
        atomicAdd(&lcnt[ed[e] >> BSHIFT], 1);
    __syncthreads();
    for (int b = threadIdx.x; b < NB; b += 256) {
        int c = lcnt[b];
        lofs[b] = c ? atomicAdd(&gcur[b], c) : 0;
    }
    __syncthreads();
    for (int i = threadIdx.x; i < NB; i += 256) lcnt[i] = 0;
    __syncthreads();
    for (int e = lo + threadIdx.x; e < hi; e += 256) {
        int s = es[e], t = ed[e];
        int b = t >> BSHIFT;
        int pos = lofs[b] + atomicAdd(&lcnt[b], 1);
        binned[pos] = make_int2(s, t);
    }
}
__global__ void k_csr_build(const int2* __restrict__ binned, const int* __restrict__ bbase,
                            const int* __restrict__ bsize, int* __restrict__ rowptr,
                            int* __restrict__ deg, float* __restrict__ dinv,
                            int* __restrict__ csrc, int N) {
    __shared__ int cnt_l[NPBK];
    __shared__ int ofs_l[NPBK];
    int b = blockIdx.x;
    int base = bbase[b];
    int cnt = bsize[b];
    int nlo = b << BSHIFT;
    int nhi = min(N, nlo + NPBK);
    int nv = nhi - nlo;
    int csrbase = base + nlo;
    int tid = threadIdx.x;
    for (int i = tid; i < NPBK; i += 256) cnt_l[i] = (i < nv) ? 1 : 0;
    __syncthreads();
    for (int e = tid; e < cnt; e += 256) {
        int2 st = binned[base + e];
        atomicAdd(&cnt_l[st.y - nlo], 1);
    }
    __syncthreads();
    if (tid < 64) {
        int carry = 0;
#pragma unroll
        for (int r = 0; r < NPBK / 64; ++r) {
            int idx = r * 64 + tid;
            int orig = cnt_l[idx];
            int v = orig;
#pragma unroll
            for (int o = 1; o < 64; o <<= 1) {
                int t = __shfl_up(v, o, 64);
                if (tid >= o) v += t;
            }
            ofs_l[idx] = carry + v - orig;
            carry += __shfl(v, 63, 64);
        }
    }
    __syncthreads();
    for (int i = tid; i < nv; i += 256) {
        int node = nlo + i;
        int d = cnt_l[i];
        rowptr[node] = csrbase + ofs_l[i];
        deg[node] = d;
        dinv[node] = rsqrtf((float)d);
    }
    __syncthreads();
    for (int i = tid; i < NPBK; i += 256) cnt_l[i] = ofs_l[i];
    __syncthreads();
    for (int e = tid; e < cnt; e += 256) {
        int2 st = binned[base + e];
        int p = atomicAdd(&cnt_l[st.y - nlo], 1);
        csrc[csrbase + p] = st.x;
    }
    for (int i = tid; i < nv; i += 256) {
        int p = atomicAdd(&cnt_l[i], 1);
        csrc[csrbase + p] = nlo + i;
    }
}

// ===================== xh = half(x * dinv[row]) =====================
__global__ void k_cvt_xh(const float* __restrict__ x, const float* __restrict__ dinv,
                         half_t* __restrict__ xh, int n) {
    int total = n * 8;   // 64 dims / 8
    for (int q = blockIdx.x * blockDim.x + threadIdx.x; q < total;
         q += gridDim.x * blockDim.x) {
        float din = dinv[q >> 3];
        float4 a = ((const float4*)x)[q * 2];
        float4 b = ((const float4*)x)[q * 2 + 1];
        halfv8 h;
        h[0] = (half_t)(a.x * din); h[1] = (half_t)(a.y * din);
        h[2] = (half_t)(a.z * din); h[3] = (half_t)(a.w * din);
        h[4] = (half_t)(b.x * din); h[5] = (half_t)(b.y * din);
        h[6] = (half_t)(b.z * din); h[7] = (half_t)(b.w * din);
        ((halfv8*)xh)[q] = h;
    }
}

// ===== dense matmul Y[n,M] = X[n,K] @ W[K,M], f32 out; EPI 1: bias+BN+ReLU =====
template <int K, int M>
__global__ void k_matmul4(const float* __restrict__ X, const float* __restrict__ W,
                          float* __restrict__ Y, int n,
                          const float* __restrict__ b, const float* __restrict__ g,
                          const float* __restrict__ be, const float* __restrict__ m,
                          const float* __restrict__ v) {
    __shared__ float Wl[K * M];
    for (int i = threadIdx.x; i < K * M / 4; i += 256)
        ((float4*)Wl)[i] = ((const float4*)W)[i];
    __syncthreads();
    const int TPR = M / 4;
    const int RPB = 256 / TPR;
    const int c4  = (threadIdx.x % TPR) * 4;
    int row = blockIdx.x * RPB + threadIdx.x / TPR;
    if (row >= n) return;
    const float4* xr = (const float4*)(X + (long long)row * K);
    float4 acc = make_float4(0.f, 0.f, 0.f, 0.f);
#pragma unroll
    for (int k4 = 0; k4 < K / 4; ++k4) {
        float4 xv = xr[k4];
        const float* wp = &Wl[(k4 * 4) * M + c4];
        float4 w0 = *(const float4*)(wp);
        float4 w1 = *(const float4*)(wp + M);
        float4 w2 = *(const float4*)(wp + 2 * M);
        float4 w3 = *(const float4*)(wp + 3 * M);
        acc.x += xv.x * w0.x + xv.y * w1.x + xv.z * w2.x + xv.w * w3.x;
        acc.y += xv.x * w0.y + xv.y * w1.y + xv.z * w2.y + xv.w * w3.y;
        acc.z += xv.x * w0.z + xv.y * w1.z + xv.z * w2.z + xv.w * w3.z;
        acc.w += xv.x * w0.w + xv.y * w1.w + xv.z * w2.w + xv.w * w3.w;
    }
    float4 bb = *(const float4*)(b + c4);
    float4 mm = *(const float4*)(m + c4);
    float4 vv = *(const float4*)(v + c4);
    float4 gg = *(const float4*)(g + c4);
    float4 ee = *(const float4*)(be + c4);
    acc.x = fmaxf((acc.x + bb.x - mm.x) * rsqrtf(vv.x + EPSN) * gg.x + ee.x, 0.f);
    acc.y = fmaxf((acc.y + bb.y - mm.y) * rsqrtf(vv.y + EPSN) * gg.y + ee.y, 0.f);
    acc.z = fmaxf((acc.z + bb.z - mm.z) * rsqrtf(vv.z + EPSN) * gg.z + ee.z, 0.f);
    acc.w = fmaxf((acc.w + bb.w - mm.w) * rsqrtf(vv.w + EPSN) * gg.w + ee.w, 0.f);
    *(float4*)(Y + (long long)row * M + c4) = acc;
}

// ===== dense matmul, half output, scaled by dinv[row] =====
template <int K, int M>
__global__ void k_matmul4h(const float* __restrict__ X, const float* __restrict__ W,
                           half_t* __restrict__ Y, int n, const float* __restrict__ dinv) {
    __shared__ float Wl[K * M];
    for (int i = threadIdx.x; i < K * M / 4; i += 256)
        ((float4*)Wl)[i] = ((const float4*)W)[i];
    __syncthreads();
    const int TPR = M / 4;
    const int RPB = 256 / TPR;
    const int c4  = (threadIdx.x % TPR) * 4;
    int row = blockIdx.x * RPB + threadIdx.x / TPR;
    if (row >= n) return;
    const float4* xr = (const float4*)(X + (long long)row * K);
    float4 acc = make_float4(0.f, 0.f, 0.f, 0.f);
#pragma unroll
    for (int k4 = 0; k4 < K / 4; ++k4) {
        float4 xv = xr[k4];
        const float* wp = &Wl[(k4 * 4) * M + c4];
        float4 w0 = *(const float4*)(wp);
        float4 w1 = *(const float4*)(wp + M);
        float4 w2 = *(const float4*)(wp + 2 * M);
        float4 w3 = *(const float4*)(wp + 3 * M);
        acc.x += xv.x * w0.x + xv.y * w1.x + xv.z * w2.x + xv.w * w3.x;
        acc.y += xv.x * w0.y + xv.y * w1.y + xv.z * w2.y + xv.w * w3.y;
        acc.z += xv.x * w0.z + xv.y * w1.z + xv.z * w2.z + xv.w * w3.z;
        acc.w += xv.x * w0.w + xv.y * w1.w + xv.z * w2.w + xv.w * w3.w;
    }
    float din = dinv[row];
    halfv4 hv;
    hv[0] = (half_t)(acc.x * din); hv[1] = (half_t)(acc.y * din);
    hv[2] = (half_t)(acc.z * din); hv[3] = (half_t)(acc.w * din);
    *(halfv4*)(Y + (long long)row * M + c4) = hv;
}

// ===== CSR sum-aggregation over half rows, 8 dims/lane, unroll-2 =====
// EPI 0: out = acc*dinv[node]; 1: + bias, BN, ReLU. Output f32.
template <int M, int EPI>
__global__ void k_agg4h(const half_t* __restrict__ A, const int* __restrict__ rowptr,
                        const int* __restrict__ deg, const int* __restrict__ csrc,
                        const float* __restrict__ dinv,
                        const float* __restrict__ b, const float* __restrict__ g,
                        const float* __restrict__ be, const float* __restrict__ m,
                        const float* __restrict__ v,
                        float* __restrict__ B, int n) {
    const int LPE = M / 8;
    const int EPW = 64 / LPE;
    int node = blockIdx.x * 4 + (threadIdx.x >> 6);
    if (node >= n) return;
    int lane = threadIdx.x & 63;
    int eg = lane / LPE;
    int dl = lane % LPE;
    int beg = rowptr[node];
    int end = beg + deg[node];
    float acc[8];
#pragma unroll
    for (int j = 0; j < 8; ++j) acc[j] = 0.f;
    int i = beg + eg;
    for (; i + EPW < end; i += 2 * EPW) {
        int s0 = csrc[i];
        int s1 = csrc[i + EPW];
        halfv8 x0 = *(const halfv8*)(A + (long long)s0 * M + dl * 8);
        halfv8 x1 = *(const halfv8*)(A + (long long)s1 * M + dl * 8);
#pragma unroll
        for (int j = 0; j < 8; ++j) acc[j] += (float)x0[j] + (float)x1[j];
    }
    if (i < end) {
        int s = csrc[i];
        halfv8 xv = *(const halfv8*)(A + (long long)s * M + dl * 8);
#pragma unroll
        for (int j = 0; j < 8; ++j) acc[j] += (float)xv[j];
    }
#pragma unroll
    for (int off = LPE; off < 64; off <<= 1) {
#pragma unroll
        for (int j = 0; j < 8; ++j) acc[j] += __shfl_xor(acc[j], off);
    }
    if (eg == 0) {
        float din = dinv[node];
        int d0 = dl * 8;
        float o[8];
#pragma unroll
        for (int j = 0; j < 8; ++j) o[j] = acc[j] * din;
        if (EPI == 1) {
#pragma unroll
            for (int j = 0; j < 8; ++j) {
                int d = d0 + j;
                o[j] = fmaxf((o[j] + b[d] - m[d]) * rsqrtf(v[d] + EPSN) * g[d] + be[d], 0.f);
            }
        }
        float4 lo = make_float4(o[0], o[1], o[2], o[3]);
        float4 hi = make_float4(o[4], o[5], o[6], o[7]);
        *(float4*)(B + (long long)node * M + d0) = lo;
        *(float4*)(B + (long long)node * M + d0 + 4) = hi;
    }
}

// ===== tiny: Ws/Wd = Wg folded with ags/agd -> wsd[2][32][4] =====
__global__ void k_wsd(const float* __restrict__ Wg, const float* __restrict__ ags,
                      const float* __restrict__ agd, float* __restrict__ wsd) {
    int j = threadIdx.x;
    if (j < 128) {
        int k = j >> 2, h = j & 3;
        float ss = 0.f, dd = 0.f;
        for (int d2 = 0; d2 < 32; ++d2) {
            float wv = Wg[k * 128 + h * 32 + d2];
            ss += wv * ags[h * 32 + d2];
            dd += wv * agd[h * 32 + d2];
        }
        wsd[j] = ss;         // Ws[k][h]
        wsd[128 + j] = dd;   // Wd[k][h]
    }
}

// ===== layer-3 agg (M=32, half in) + BN/ReLU + fused attention coefs; H3 half out =====
__global__ void k_agg_att(const half_t* __restrict__ A, const int* __restrict__ rowptr,
                          const int* __restrict__ deg, const int* __restrict__ csrc,
                          const float* __restrict__ dinv,
                          const float* __restrict__ b, const float* __restrict__ g,
                          const float* __restrict__ be, const float* __restrict__ m,
                          const float* __restrict__ v, const float* __restrict__ wsd,
                          half_t* __restrict__ H3h, float* __restrict__ a_s,
                          float* __restrict__ a_d, int n) {
    __shared__ float Wl[256];
    for (int i = threadIdx.x; i < 256; i += 256) Wl[i] = wsd[i];
    __syncthreads();
    const int M = 32, LPE = 4, EPW = 16;
    int node = blockIdx.x * 4 + (threadIdx.x >> 6);
    if (node >= n) return;
    int lane = threadIdx.x & 63;
    int eg = lane >> 2;      // 16 edge slots
    int dl = lane & 3;       // 4 lanes/row, 8 dims each
    int beg = rowptr[node];
    int end = beg + deg[node];
    float acc[8];
#pragma unroll
    for (int j = 0; j < 8; ++j) acc[j] = 0.f;
    int i = beg + eg;
    for (; i + EPW < end; i += 2 * EPW) {
        int s0 = csrc[i];
        int s1 = csrc[i + EPW];
        halfv8 x0 = *(const halfv8*)(A + (long long)s0 * M + dl * 8);
        halfv8 x1 = *(const halfv8*)(A + (long long)s1 * M + dl * 8);
#pragma unroll
        for (int j = 0; j < 8; ++j) acc[j] += (float)x0[j] + (float)x1[j];
    }
    if (i < end) {
        int s = csrc[i];
        halfv8 xv = *(const halfv8*)(A + (long long)s * M + dl * 8);
#pragma unroll
        for (int j = 0; j < 8; ++j) acc[j] += (float)xv[j];
    }
#pragma unroll
    for (int off = 4; off < 64; off <<= 1) {
#pragma unroll
        for (int j = 0; j < 8; ++j) acc[j] += __shfl_xor(acc[j], off);
    }
    float din = dinv[node];
    int d0 = dl * 8;
    float hv[8];
#pragma unroll
    for (int j = 0; j < 8; ++j) {
        int d = d0 + j;
        hv[j] = fmaxf((acc[j] * din + b[d] - m[d]) * rsqrtf(v[d] + EPSN) * g[d] + be[d], 0.f);
    }
    if (eg == 0) {
        halfv8 hw;
#pragma unroll
        for (int j = 0; j < 8; ++j) hw[j] = (half_t)hv[j];
        *(halfv8*)(H3h + (long long)node * M + d0) = hw;
    }
    // attention coefs via shfl from lanes 0..3 (dl=0..3, eg=0)
    int h = lane & 3, sel = (lane >> 2) & 1;
    const float* wp = &Wl[sel * 128];
    float o = 0.f;
#pragma unroll
    for (int src = 0; src < 4; ++src) {
#pragma unroll
        for (int j = 0; j < 8; ++j) {
            float xv = __shfl(hv[j], src);
            o += xv * wp[(src * 8 + j) * 4 + h];
        }
    }
    if (lane < 4) a_s[node * 4 + h] = o;
    else if (lane < 8) a_d[node * 4 + h] = o;
}

// ===== fused GAT v3: edge-per-lane softmax + quarter-wave half2 gather + Wg epilogue =====
__global__ void k_gat4(const half_t* __restrict__ H3h, const float* __restrict__ a_s,
                       const float* __restrict__ a_d, const int* __restrict__ rowptr,
                       const int* __restrict__ deg, const int* __restrict__ csrc,
                       const float* __restrict__ Wg, const float* __restrict__ bg,
                       float* __restrict__ H4, int n) {
    __shared__ float sc[4][GCAP * 4];   // [w][e*4+h]
    __shared__ int   srcb[4][GCAP];
    __shared__ float wb[4][128];
    int w = threadIdx.x >> 6;
    int node = blockIdx.x * 4 + w;
    if (node >= n) return;
    int lane = threadIdx.x & 63;
    int beg = rowptr[node];
    int cnt = deg[node];
    bool fits = (cnt <= GCAP);
    float4 ad4 = ((const float4*)a_d)[node];
    float m0 = -1e30f, m1 = -1e30f, m2 = -1e30f, m3 = -1e30f;
    if (fits) {
        for (int e = lane; e < cnt; e += 64) {
            int s = csrc[beg + e];
            srcb[w][e] = s;
            float4 as = ((const float4*)a_s)[s];
            float e0 = lrelu(as.x + ad4.x);
            float e1 = lrelu(as.y + ad4.y);
            float e2 = lrelu(as.z + ad4.z);
            float e3 = lrelu(as.w + ad4.w);
            *(float4*)&sc[w][e * 4] = make_float4(e0, e1, e2, e3);
            m0 = fmaxf(m0, e0); m1 = fmaxf(m1, e1);
            m2 = fmaxf(m2, e2); m3 = fmaxf(m3, e3);
        }
    } else {
        for (int e = lane; e < cnt; e += 64) {
            int s = csrc[beg + e];
            float4 as = ((const float4*)a_s)[s];
            m0 = fmaxf(m0, lrelu(as.x + ad4.x));
            m1 = fmaxf(m1, lrelu(as.y + ad4.y));
            m2 = fmaxf(m2, lrelu(as.z + ad4.z));
            m3 = fmaxf(m3, lrelu(as.w + ad4.w));
        }
    }
#pragma unroll
    for (int o = 1; o < 64; o <<= 1) {
        m0 = fmaxf(m0, __shfl_xor(m0, o));
        m1 = fmaxf(m1, __shfl_xor(m1, o));
        m2 = fmaxf(m2, __shfl_xor(m2, o));
        m3 = fmaxf(m3, __shfl_xor(m3, o));
    }
    float s0 = 0.f, s1 = 0.f, s2 = 0.f, s3 = 0.f;
    if (fits) {
        for (int e = lane; e < cnt; e += 64) {
            float4 sv = *(float4*)&sc[w][e * 4];
            float p0 = __expf(sv.x - m0);
            float p1 = __expf(sv.y - m1);
            float p2 = __expf(sv.z - m2);
            float p3 = __expf(sv.w - m3);
            *(float4*)&sc[w][e * 4] = make_float4(p0, p1, p2, p3);
            s0 += p0; s1 += p1; s2 += p2; s3 += p3;
        }
    } else {
        for (int e = lane; e < cnt; e += 64) {
            int s = csrc[beg + e];
            float4 as = ((const float4*)a_s)[s];
            s0 += __expf(lrelu(as.x + ad4.x) - m0);
            s1 += __expf(lrelu(as.y + ad4.y) - m1);
            s2 += __expf(lrelu(as.z + ad4.z) - m2);
            s3 += __expf(lrelu(as.w + ad4.w) - m3);
        }
    }
#pragma unroll
    for (int o = 1; o < 64; o <<= 1) {
        s0 += __shfl_xor(s0, o);
        s1 += __shfl_xor(s1, o);
        s2 += __shfl_xor(s2, o);
        s3 += __shfl_xor(s3, o);
    }
    float inv0 = 0.25f / s0, inv1 = 0.25f / s1, inv2 = 0.25f / s2, inv3 = 0.25f / s3;
    // phase 2: quarter-wave per edge; lane -> q=lane>>4 (edge offset), k=lane&15 (dims 2k,2k+1)
    int q = lane >> 4;
    int k = lane & 15;
    float acc[8];
#pragma unroll
    for (int j = 0; j < 8; ++j) acc[j] = 0.f;
    if (fits) {
        int i = q;
        for (; i + 4 < cnt; i += 8) {
            int sA = srcb[w][i];
            int sB = srcb[w][i + 4];
            halfv2 xA = *(const halfv2*)(H3h + (long long)sA * 32 + 2 * k);
            halfv2 xB = *(const halfv2*)(H3h + (long long)sB * 32 + 2 * k);
            float4 wA = *(float4*)&sc[w][i * 4];
            float4 wB = *(float4*)&sc[w][(i + 4) * 4];
            float a0 = (float)xA[0], a1 = (float)xA[1];
            float b0 = (float)xB[0], b1 = (float)xB[1];
            acc[0] += wA.x * a0 + wB.x * b0; acc[1] += wA.x * a1 + wB.x * b1;
            acc[2] += wA.y * a0 + wB.y * b0; acc[3] += wA.y * a1 + wB.y * b1;
            acc[4] += wA.z * a0 + wB.z * b0; acc[5] += wA.z * a1 + wB.z * b1;
            acc[6] += wA.w * a0 + wB.w * b0; acc[7] += wA.w * a1 + wB.w * b1;
        }
        if (i < cnt) {
            int s = srcb[w][i];
            halfv2 xv = *(const halfv2*)(H3h + (long long)s * 32 + 2 * k);
            float4 wv = *(float4*)&sc[w][i * 4];
            float x0 = (float)xv[0], x1 = (float)xv[1];
            acc[0] += wv.x * x0; acc[1] += wv.x * x1;
            acc[2] += wv.y * x0; acc[3] += wv.y * x1;
            acc[4] += wv.z * x0; acc[5] += wv.z * x1;
            acc[6] += wv.w * x0; acc[7] += wv.w * x1;
        }
    } else {
        for (int i = q; i < cnt; i += 4) {
            int s = csrc[beg + i];
            float4 as = ((const float4*)a_s)[s];
            float p0 = __expf(lrelu(as.x + ad4.x) - m0);
            float p1 = __expf(lrelu(as.y + ad4.y) - m1);
            float p2 = __expf(lrelu(as.z + ad4.z) - m2);
            float p3 = __expf(lrelu(as.w + ad4.w) - m3);
            halfv2 xv = *(const halfv2*)(H3h + (long long)s * 32 + 2 * k);
            float x0 = (float)xv[0], x1 = (float)xv[1];
            acc[0] += p0 * x0; acc[1] += p0 * x1;
            acc[2] += p1 * x0; acc[3] += p1 * x1;
            acc[4] += p2 * x0; acc[5] += p2 * x1;
            acc[6] += p3 * x0; acc[7] += p3 * x1;
        }
    }
#pragma unroll
    for (int o = 16; o < 64; o <<= 1) {
#pragma unroll
        for (int j = 0; j < 8; ++j) acc[j] += __shfl_xor(acc[j], o);
    }
    if (q == 0) {
        float invh[4] = {inv0, inv1, inv2, inv3};
#pragma unroll
        for (int h = 0; h < 4; ++h) {
            wb[w][h * 32 + 2 * k]     = acc[h * 2]     * invh[h];
            wb[w][h * 32 + 2 * k + 1] = acc[h * 2 + 1] * invh[h];
        }
    }
    // epilogue: out[d] = relu(sum_j wb[j]*Wg[(j&31)*128+(j>>5)*32+d] + bg[d])
    int d = lane & 31;
    int h0 = lane >> 5;
    int half_ = h0 * 64;
    float o = 0.f;
#pragma unroll
    for (int j = 0; j < 64; ++j) {
        int jj = half_ + j;
        o += wb[w][jj] * Wg[(jj & 31) * 128 + (jj >> 5) * 32 + d];
    }
    o += __shfl_xor(o, 32);
    if (lane < 32)
        H4[(long long)node * 32 + d] = fmaxf(o + bg[d], 0.f);
}

// ===================== pool =====================
__global__ void k_pool_init(float* __restrict__ pooled, float* __restrict__ cnt) {
    int i = blockIdx.x * blockDim.x + threadIdx.x;
    if (i < NGRAPH * 32) pooled[i] = 0.f;
    if (i < NGRAPH) cnt[i] = 0.f;
}
__global__ void k_pool2(const float* __restrict__ h, const int* __restrict__ batch,
                        float* __restrict__ pooled, float* __restrict__ cnt, int n) {
    __shared__ float lp[NGRAPH * 32];
    __shared__ float lc[NGRAPH];
    int tid = threadIdx.x;
    for (int i = tid; i < NGRAPH * 32; i += 256) lp[i] = 0.f;
    for (int i = tid; i < NGRAPH; i += 256) lc[i] = 0.f;
    __syncthreads();
    int per = (n + gridDim.x - 1) / gridDim.x;
    int lo = blockIdx.x * per;
    int hi = min(n, lo + per);
    for (long long i = (long long)lo * 32 + tid; i < (long long)hi * 32; i += 256) {
        int ni = (int)(i >> 5), dd = (int)(i & 31);
        int b = batch[ni];
        atomicAdd(&lp[b * 32 + dd], h[i]);
        if (dd == 0) atomicAdd(&lc[b], 1.f);
    }
    __syncthreads();
    for (int i = tid; i < NGRAPH * 32; i += 256)
        if (lp[i] != 0.f) atomicAdd(&pooled[i], lp[i]);
    for (int i = tid; i < NGRAPH; i += 256)
        if (lc[i] != 0.f) atomicAdd(&cnt[i], lc[i]);
}

// ===================== classifier =====================
__global__ void k_classifier(const float* __restrict__ pooled, const float* __restrict__ cnt,
                             const float* __restrict__ Wc1, const float* __restrict__ bc1,
                             const float* __restrict__ Wc2, const float* __restrict__ bc2,
                             float* __restrict__ out) {
    __shared__ float pl[NGRAPH * 32];
    __shared__ float t1[NGRAPH * 16];
    int tid = threadIdx.x;
    for (int i = tid; i < NGRAPH * 32; i += blockDim.x) {
        int g = i >> 5;
        pl[i] = pooled[i] / fmaxf(cnt[g], 1.f);
    }
    __syncthreads();
    for (int i = tid; i < NGRAPH * 16; i += blockDim.x) {
        int g = i >> 4, c = i & 15;
        float acc = bc1[c];
#pragma unroll
        for (int d = 0; d < 32; ++d) acc += pl[g * 32 + d] * Wc1[d * 16 + c];
        t1[i] = fmaxf(acc, 0.f);
    }
    __syncthreads();
    for (int i = tid; i < NGRAPH * 5; i += blockDim.x) {
        int g = i / 5, c = i % 5;
        float acc = bc2[c];
#pragma unroll
        for (int k = 0; k < 16; ++k) acc += t1[g * 16 + k] * Wc2[k * 5 + c];
        out[i] = acc;
    }
}

// ===================== launch =====================
static inline dim3 gsz(long long work, int block = 256) {
    long long g = (work + block - 1) / block;
    if (g > 262144) g = 262144;
    if (g < 1) g = 1;
    return dim3((unsigned)g);
}

extern "C" void kernel_launch(void* const* d_in, const int* in_sizes, int n_in,
                              void* d_out, int out_size, void* d_ws, size_t ws_size,
                              hipStream_t stream) {
    const float* x     = (const float*)d_in[0];
    const int*   ei    = (const int*)d_in[1];
    const int*   batch = (const int*)d_in[2];
    const float* W1 = (const float*)d_in[3];  const float* b1 = (const float*)d_in[4];
    const float* W2 = (const float*)d_in[5];  const float* b2 = (const float*)d_in[6];
    const float* W3 = (const float*)d_in[7];  const float* b3 = (const float*)d_in[8];
    const float* g1 = (const float*)d_in[9];  const float* be1 = (const float*)d_in[10];
    const float* m1 = (const float*)d_in[11]; const float* v1  = (const float*)d_in[12];
    const float* g2 = (const float*)d_in[13]; const float* be2 = (const float*)d_in[14];
    const float* m2 = (const float*)d_in[15]; const float* v2  = (const float*)d_in[16];
    const float* g3 = (const float*)d_in[17]; const float* be3 = (const float*)d_in[18];
    const float* m3 = (const float*)d_in[19]; const float* v3  = (const float*)d_in[20];
    const float* Wg  = (const float*)d_in[21];
    const float* ags = (const float*)d_in[22];
    const float* agd = (const float*)d_in[23];
    const float* bg  = (const float*)d_in[24];
    const float* Wc1 = (const float*)d_in[25]; const float* bc1 = (const float*)d_in[26];
    const float* Wc2 = (const float*)d_in[27]; const float* bc2 = (const float*)d_in[28];
    float* out = (float*)d_out;

    const int N = in_sizes[0] / 64;
    const int E = in_sizes[1] / 2;
    const int* esrc = ei;
    const int* edst = ei + E;
    const int NB = (N + NPBK - 1) >> BSHIFT;

    size_t off = 0;
    auto take = [&](size_t bytes) -> void* {
        void* p = (char*)d_ws + off;
        off += bytes;
        off = (off + 255) & ~(size_t)255;
        return p;
    };
    int*    deg    = (int*)take((size_t)N * 4);
    float*  dinv   = (float*)take((size_t)N * 4);
    int*    rowptr = (int*)take((size_t)N * 4);
    int*    bsize  = (int*)take((size_t)1024 * 4);
    int*    bbase  = (int*)take((size_t)1024 * 4);
    int*    gcur   = (int*)take((size_t)1024 * 4);
    float*  wsd    = (float*)take((size_t)256 * 4);
    int*    csrc   = (int*)take((size_t)(E + N) * 4);
    half_t* bufAh  = (half_t*)take((size_t)N * 64 * 2);  // xh -> A2h -> A3h -> H4(f32,N*32)
    float*  bufB   = (float*)take((size_t)N * 64 * 4);   // Xa -> H2
    float*  bufC   = (float*)take((size_t)N * 128 * 4);  // binned (early) ; H1 (later)
    half_t* h3h    = (half_t*)take((size_t)N * 32 * 2);
    float*  a_s    = (float*)take((size_t)N * 4 * 4);
    float*  a_d    = (float*)take((size_t)N * 4 * 4);
    float*  pooled = (float*)take((size_t)NGRAPH * 32 * 4);
    float*  cnt    = (float*)take((size_t)NGRAPH * 4);
    int2*   binned = (int2*)bufC;
    float*  H4     = (float*)bufAh;   // N*32 f32 == N*64 half bytes; A3h dead before gat4 writes
    (void)ws_size; (void)n_in; (void)out_size;

    const dim3 B256(256);

    // ---- binned CSR build ----
    hipMemsetAsync(bsize, 0, (size_t)NB * 4, stream);
    hipLaunchKernelGGL(k_bin_count, dim3(512), B256, 0, stream, edst, bsize, E, NB);
    hipLaunchKernelGGL(k_bucket_scan, dim3(1), dim3(64), 0, stream, bsize, bbase, gcur, NB);
    hipLaunchKernelGGL(k_bin_write, dim3(512), B256, 0, stream, esrc, edst, gcur, binned, E, NB);
    hipLaunchKernelGGL(k_csr_build, dim3(NB), B256, 0, stream,
                       binned, bbase, bsize, rowptr, deg, dinv, csrc, N);
    hipLaunchKernelGGL(k_wsd, dim3(1), dim3(128), 0, stream, Wg, ags, agd, wsd);

    // ---- layer 1: xh = half(x*dinv); Xa = dinv*sum(xh); H1 = relu(BN(Xa@W1+b1))
    hipLaunchKernelGGL(k_cvt_xh, gsz((long long)N * 8), B256, 0, stream, x, dinv, bufAh, N);
    hipLaunchKernelGGL((k_agg4h<64, 0>), dim3((N + 3) / 4), B256, 0, stream,
                       bufAh, rowptr, deg, csrc, dinv,
                       nullptr, nullptr, nullptr, nullptr, nullptr, bufB, N);
    hipLaunchKernelGGL((k_matmul4<64, 128>), dim3((N + 7) / 8), B256, 0, stream,
                       bufB, W1, bufC, N, b1, g1, be1, m1, v1);
    // ---- layer 2: A2h = half((H1@W2)*dinv); H2 = relu(BN(dinv*sum(A2h)+b2))
    hipLaunchKernelGGL((k_matmul4h<128, 64>), dim3((N + 15) / 16), B256, 0, stream,
                       bufC, W2, bufAh, N, dinv);
    hipLaunchKernelGGL((k_agg4h<64, 1>), dim3((N + 3) / 4), B256, 0, stream,
                       bufAh, rowptr, deg, csrc, dinv, b2, g2, be2, m2, v2, bufB, N);
    // ---- layer 3: A3h = half((H2@W3)*dinv); H3h + a_s/a_d fused
    hipLaunchKernelGGL((k_matmul4h<64, 32>), dim3((N + 31) / 32), B256, 0, stream,
                       bufB, W3, bufAh, N, dinv);
    hipLaunchKernelGGL(k_agg_att, dim3((N + 3) / 4), B256, 0, stream,
                       bufAh, rowptr, deg, csrc, dinv, b3, g3, be3, m3, v3,
                       wsd, h3h, a_s, a_d, N);

    // ---- GAT (writes H4 f32 into bufAh region; A3h dead)
    hipLaunchKernelGGL(k_gat4, dim3((N + 3) / 4), B256, 0, stream,
                       h3h, a_s, a_d, rowptr, deg, csrc, Wg, bg, H4, N);

    // ---- pool + classifier
    hipLaunchKernelGGL(k_pool_init, dim3(9), B256, 0, stream, pooled, cnt);
    hipLaunchKernelGGL(k_pool2, dim3(128), B256, 0, stream, H4, batch, pooled, cnt, N);
    hipLaunchKernelGGL(k_classifier, dim3(1), B256, 0, stream, pooled, cnt, Wc1, bc1, Wc2, bc2, out);
}

// Round 8
// 601.594 us; speedup vs baseline: 5.9313x; 1.0524x over previous
//
#include <hip/hip_runtime.h>

#define EPSN   1e-5f
#define NEGS   0.2f
#define NGRAPH 64
#define BSHIFT 9
#define NPBK   512            // nodes per bucket = 1<<BSHIFT
#define GCAP   96             // GAT LDS edge cap per node

typedef _Float16 half_t;
typedef _Float16 halfv8 __attribute__((ext_vector_type(8)));
typedef _Float16 halfv4 __attribute__((ext_vector_type(4)));
typedef _Float16 halfv2 __attribute__((ext_vector_type(2)));

__device__ __forceinline__ float lrelu(float e) { return e > 0.f ? e : NEGS * e; }

// ===================== binned CSR build =====================
__global__ void k_bin_count(const int* __restrict__ ed, int* __restrict__ bsize,
                            int E, int NB) {
    __shared__ int lcnt[1024];
    for (int i = threadIdx.x; i < NB; i += 256) lcnt[i] = 0;
    __syncthreads();
    int chunk = (E + gridDim.x - 1) / gridDim.x;
    int lo = blockIdx.x * chunk;
    int hi = min(E, lo + chunk);
    for (int e = lo + threadIdx.x; e < hi; e += 256)
        atomicAdd(&lcnt[ed[e] >> BSHIFT], 1);
    __syncthreads();
    for (int b = threadIdx.x; b < NB; b += 256)
        if (lcnt[b]) atomicAdd(&bsize[b], lcnt[b]);
}
__global__ void k_bucket_scan(const int* __restrict__ bsize, int* __restrict__ bbase,
                              int* __restrict__ gcur, int NB) {
    int lane = threadIdx.x;
    if (lane >= 64) return;
    int carry = 0;
    int rounds = (NB + 63) / 64;
    for (int r = 0; r < rounds; ++r) {
        int idx = r * 64 + lane;
        int orig = (idx < NB) ? bsize[idx] : 0;
        int v = orig;
#pragma unroll
        for (int o = 1; o < 64; o <<= 1) {
            int t = __shfl_up(v, o, 64);
            if (lane >= o) v += t;
        }
        if (idx < NB) {
            int excl = carry + v - orig;
            bbase[idx] = excl;
            gcur[idx] = excl;
        }
        carry += __shfl(v, 63, 64);
    }
}
// packed: (src << 9) | (dst & 511)  -- src < 2^23, fits
__global__ void k_bin_write(const int* __restrict__ es, const int* __restrict__ ed,
                            int* __restrict__ gcur, unsigned* __restrict__ binned,
                            int E, int NB) {
    __shared__ int lcnt[1024];
    __shared__ int lofs[1024];
    int chunk = (E + gridDim.x - 1) / gridDim.x;
    int lo = blockIdx.x * chunk;
    int hi = min(E, lo + chunk);
    for (int i = threadIdx.x; i < NB; i += 256) lcnt[i] = 0;
    __syncthreads();
    for (int e = lo + threadIdx.x; e < hi; e += 256)
        atomicAdd(&lcnt[ed[e] >> BSHIFT], 1);
    __syncthreads();
    for (int b = threadIdx.x; b < NB; b += 256) {
        int c = lcnt[b];
        lofs[b] = c ? atomicAdd(&gcur[b], c) : 0;
    }
    __syncthreads();
    for (int i = threadIdx.x; i < NB; i += 256) lcnt[i] = 0;
    __syncthreads();
    for (int e = lo + threadIdx.x; e < hi; e += 256) {
        int s = es[e], t = ed[e];
        int b = t >> BSHIFT;
        int pos = lofs[b] + atomicAdd(&lcnt[b], 1);
        binned[pos] = ((unsigned)s << BSHIFT) | (unsigned)(t & (NPBK - 1));
    }
}
__global__ void k_csr_build(const unsigned* __restrict__ binned, const int* __restrict__ bbase,
                            const int* __restrict__ bsize, int* __restrict__ rowptr,
                            int* __restrict__ deg, float* __restrict__ dinv,
                            int* __restrict__ csrc, int N) {
    __shared__ int cnt_l[NPBK];
    __shared__ int ofs_l[NPBK];
    int b = blockIdx.x;
    int base = bbase[b];
    int cnt = bsize[b];
    int nlo = b << BSHIFT;
    int nhi = min(N, nlo + NPBK);
    int nv = nhi - nlo;
    int csrbase = base + nlo;
    int tid = threadIdx.x;
    for (int i = tid; i < NPBK; i += 256) cnt_l[i] = (i < nv) ? 1 : 0;
    __syncthreads();
    for (int e = tid; e < cnt; e += 256)
        atomicAdd(&cnt_l[binned[base + e] & (NPBK - 1)], 1);
    __syncthreads();
    if (tid < 64) {
        int carry = 0;
#pragma unroll
        for (int r = 0; r < NPBK / 64; ++r) {
            int idx = r * 64 + tid;
            int orig = cnt_l[idx];
            int v = orig;
#pragma unroll
            for (int o = 1; o < 64; o <<= 1) {
                int t = __shfl_up(v, o, 64);
                if (tid >= o) v += t;
            }
            ofs_l[idx] = carry + v - orig;
            carry += __shfl(v, 63, 64);
        }
    }
    __syncthreads();
    for (int i = tid; i < nv; i += 256) {
        int node = nlo + i;
        int d = cnt_l[i];
        rowptr[node] = csrbase + ofs_l[i];
        deg[node] = d;
        dinv[node] = rsqrtf((float)d);
    }
    __syncthreads();
    for (int i = tid; i < NPBK; i += 256) cnt_l[i] = ofs_l[i];
    __syncthreads();
    for (int e = tid; e < cnt; e += 256) {
        unsigned u = binned[base + e];
        int p = atomicAdd(&cnt_l[u & (NPBK - 1)], 1);
        csrc[csrbase + p] = (int)(u >> BSHIFT);
    }
    for (int i = tid; i < nv; i += 256) {
        int p = atomicAdd(&cnt_l[i], 1);
        csrc[csrbase + p] = nlo + i;
    }
}

// ===================== xh = half(x * dinv[row]) =====================
__global__ void k_cvt_xh(const float* __restrict__ x, const float* __restrict__ dinv,
                         half_t* __restrict__ xh, int n) {
    int total = n * 8;   // 64 dims / 8
    for (int q = blockIdx.x * blockDim.x + threadIdx.x; q < total;
         q += gridDim.x * blockDim.x) {
        float din = dinv[q >> 3];
        float4 a = ((const float4*)x)[q * 2];
        float4 b = ((const float4*)x)[q * 2 + 1];
        halfv8 h;
        h[0] = (half_t)(a.x * din); h[1] = (half_t)(a.y * din);
        h[2] = (half_t)(a.z * din); h[3] = (half_t)(a.w * din);
        h[4] = (half_t)(b.x * din); h[5] = (half_t)(b.y * din);
        h[6] = (half_t)(b.z * din); h[7] = (half_t)(b.w * din);
        ((halfv8*)xh)[q] = h;
    }
}

// ===== dense matmul Y[n,M] = X[n,K] @ W[K,M]; half in, half out =====
// EPI 1: +bias, BN, ReLU;  EPI 2: * dinv[row]
template <int K, int M, int EPI>
__global__ void k_matmulh(const half_t* __restrict__ X, const float* __restrict__ W,
                          half_t* __restrict__ Y, int n,
                          const float* __restrict__ b, const float* __restrict__ g,
                          const float* __restrict__ be, const float* __restrict__ m,
                          const float* __restrict__ v, const float* __restrict__ dinv) {
    __shared__ float Wl[K * M];
    for (int i = threadIdx.x; i < K * M / 4; i += 256)
        ((float4*)Wl)[i] = ((const float4*)W)[i];
    __syncthreads();
    const int TPR = M / 4;
    const int RPB = 256 / TPR;
    const int c4  = (threadIdx.x % TPR) * 4;
    int row = blockIdx.x * RPB + threadIdx.x / TPR;
    if (row >= n) return;
    const halfv8* xr = (const halfv8*)(X + (long long)row * K);
    float4 acc = make_float4(0.f, 0.f, 0.f, 0.f);
#pragma unroll
    for (int k8 = 0; k8 < K / 8; ++k8) {
        halfv8 xv = xr[k8];
#pragma unroll
        for (int j = 0; j < 8; ++j) {
            float xs = (float)xv[j];
            float4 wv = *(const float4*)&Wl[(k8 * 8 + j) * M + c4];
            acc.x += xs * wv.x; acc.y += xs * wv.y;
            acc.z += xs * wv.z; acc.w += xs * wv.w;
        }
    }
    if (EPI == 1) {
        float4 bb = *(const float4*)(b + c4);
        float4 mm = *(const float4*)(m + c4);
        float4 vv = *(const float4*)(v + c4);
        float4 gg = *(const float4*)(g + c4);
        float4 ee = *(const float4*)(be + c4);
        acc.x = fmaxf((acc.x + bb.x - mm.x) * rsqrtf(vv.x + EPSN) * gg.x + ee.x, 0.f);
        acc.y = fmaxf((acc.y + bb.y - mm.y) * rsqrtf(vv.y + EPSN) * gg.y + ee.y, 0.f);
        acc.z = fmaxf((acc.z + bb.z - mm.z) * rsqrtf(vv.z + EPSN) * gg.z + ee.z, 0.f);
        acc.w = fmaxf((acc.w + bb.w - mm.w) * rsqrtf(vv.w + EPSN) * gg.w + ee.w, 0.f);
    } else {
        float din = dinv[row];
        acc.x *= din; acc.y *= din; acc.z *= din; acc.w *= din;
    }
    halfv4 hv;
    hv[0] = (half_t)acc.x; hv[1] = (half_t)acc.y;
    hv[2] = (half_t)acc.z; hv[3] = (half_t)acc.w;
    *(halfv4*)(Y + (long long)row * M + c4) = hv;
}

// ===== CSR sum-aggregation over half rows, 8 dims/lane, unroll-2; half out =====
// EPI 0: out = half(acc*dinv[node]);  EPI 1: + bias, BN, ReLU
template <int M, int EPI>
__global__ void k_agg4h(const half_t* __restrict__ A, const int* __restrict__ rowptr,
                        const int* __restrict__ deg, const int* __restrict__ csrc,
                        const float* __restrict__ dinv,
                        const float* __restrict__ b, const float* __restrict__ g,
                        const float* __restrict__ be, const float* __restrict__ m,
                        const float* __restrict__ v,
                        half_t* __restrict__ B, int n) {
    const int LPE = M / 8;
    const int EPW = 64 / LPE;
    int node = blockIdx.x * 4 + (threadIdx.x >> 6);
    if (node >= n) return;
    int lane = threadIdx.x & 63;
    int eg = lane / LPE;
    int dl = lane % LPE;
    int beg = rowptr[node];
    int end = beg + deg[node];
    float acc[8];
#pragma unroll
    for (int j = 0; j < 8; ++j) acc[j] = 0.f;
    int i = beg + eg;
    for (; i + EPW < end; i += 2 * EPW) {
        int s0 = csrc[i];
        int s1 = csrc[i + EPW];
        halfv8 x0 = *(const halfv8*)(A + (long long)s0 * M + dl * 8);
        halfv8 x1 = *(const halfv8*)(A + (long long)s1 * M + dl * 8);
#pragma unroll
        for (int j = 0; j < 8; ++j) acc[j] += (float)x0[j] + (float)x1[j];
    }
    if (i < end) {
        int s = csrc[i];
        halfv8 xv = *(const halfv8*)(A + (long long)s * M + dl * 8);
#pragma unroll
        for (int j = 0; j < 8; ++j) acc[j] += (float)xv[j];
    }
#pragma unroll
    for (int off = LPE; off < 64; off <<= 1) {
#pragma unroll
        for (int j = 0; j < 8; ++j) acc[j] += __shfl_xor(acc[j], off);
    }
    if (eg == 0) {
        float din = dinv[node];
        int d0 = dl * 8;
        float o[8];
#pragma unroll
        for (int j = 0; j < 8; ++j) o[j] = acc[j] * din;
        if (EPI == 1) {
#pragma unroll
            for (int j = 0; j < 8; ++j) {
                int d = d0 + j;
                o[j] = fmaxf((o[j] + b[d] - m[d]) * rsqrtf(v[d] + EPSN) * g[d] + be[d], 0.f);
            }
        }
        halfv8 hw;
#pragma unroll
        for (int j = 0; j < 8; ++j) hw[j] = (half_t)o[j];
        *(halfv8*)(B + (long long)node * M + d0) = hw;
    }
}

// ===== tiny: Ws/Wd = Wg folded with ags/agd -> wsd[2][32][4] =====
__global__ void k_wsd(const float* __restrict__ Wg, const float* __restrict__ ags,
                      const float* __restrict__ agd, float* __restrict__ wsd) {
    int j = threadIdx.x;
    if (j < 128) {
        int k = j >> 2, h = j & 3;
        float ss = 0.f, dd = 0.f;
        for (int d2 = 0; d2 < 32; ++d2) {
            float wv = Wg[k * 128 + h * 32 + d2];
            ss += wv * ags[h * 32 + d2];
            dd += wv * agd[h * 32 + d2];
        }
        wsd[j] = ss;         // Ws[k][h]
        wsd[128 + j] = dd;   // Wd[k][h]
    }
}

// ===== layer-3 agg (M=32, half in) + BN/ReLU + fused attention coefs; H3 half out =====
__global__ void k_agg_att(const half_t* __restrict__ A, const int* __restrict__ rowptr,
                          const int* __restrict__ deg, const int* __restrict__ csrc,
                          const float* __restrict__ dinv,
                          const float* __restrict__ b, const float* __restrict__ g,
                          const float* __restrict__ be, const float* __restrict__ m,
                          const float* __restrict__ v, const float* __restrict__ wsd,
                          half_t* __restrict__ H3h, float* __restrict__ a_s,
                          float* __restrict__ a_d, int n) {
    __shared__ float Wl[256];
    for (int i = threadIdx.x; i < 256; i += 256) Wl[i] = wsd[i];
    __syncthreads();
    const int M = 32, EPW = 16;
    int node = blockIdx.x * 4 + (threadIdx.x >> 6);
    if (node >= n) return;
    int lane = threadIdx.x & 63;
    int eg = lane >> 2;      // 16 edge slots
    int dl = lane & 3;       // 4 lanes/row, 8 dims each
    int beg = rowptr[node];
    int end = beg + deg[node];
    float acc[8];
#pragma unroll
    for (int j = 0; j < 8; ++j) acc[j] = 0.f;
    int i = beg + eg;
    for (; i + EPW < end; i += 2 * EPW) {
        int s0 = csrc[i];
        int s1 = csrc[i + EPW];
        halfv8 x0 = *(const halfv8*)(A + (long long)s0 * M + dl * 8);
        halfv8 x1 = *(const halfv8*)(A + (long long)s1 * M + dl * 8);
#pragma unroll
        for (int j = 0; j < 8; ++j) acc[j] += (float)x0[j] + (float)x1[j];
    }
    if (i < end) {
        int s = csrc[i];
        halfv8 xv = *(const halfv8*)(A + (long long)s * M + dl * 8);
#pragma unroll
        for (int j = 0; j < 8; ++j) acc[j] += (float)xv[j];
    }
#pragma unroll
    for (int off = 4; off < 64; off <<= 1) {
#pragma unroll
        for (int j = 0; j < 8; ++j) acc[j] += __shfl_xor(acc[j], off);
    }
    float din = dinv[node];
    int d0 = dl * 8;
    float hv[8];
#pragma unroll
    for (int j = 0; j < 8; ++j) {
        int d = d0 + j;
        hv[j] = fmaxf((acc[j] * din + b[d] - m[d]) * rsqrtf(v[d] + EPSN) * g[d] + be[d], 0.f);
    }
    if (eg == 0) {
        halfv8 hw;
#pragma unroll
        for (int j = 0; j < 8; ++j) hw[j] = (half_t)hv[j];
        *(halfv8*)(H3h + (long long)node * M + d0) = hw;
    }
    // attention coefs via shfl from lanes 0..3 (dl=0..3, eg=0)
    int h = lane & 3, sel = (lane >> 2) & 1;
    const float* wp = &Wl[sel * 128];
    float o = 0.f;
#pragma unroll
    for (int src = 0; src < 4; ++src) {
#pragma unroll
        for (int j = 0; j < 8; ++j) {
            float xv = __shfl(hv[j], src);
            o += xv * wp[(src * 8 + j) * 4 + h];
        }
    }
    if (lane < 4) a_s[node * 4 + h] = o;
    else if (lane < 8) a_d[node * 4 + h] = o;
}

// ===== fused GAT: edge-per-lane softmax + quarter-wave half2 gather + Wg epilogue =====
__global__ void k_gat4(const half_t* __restrict__ H3h, const float* __restrict__ a_s,
                       const float* __restrict__ a_d, const int* __restrict__ rowptr,
                       const int* __restrict__ deg, const int* __restrict__ csrc,
                       const float* __restrict__ Wg, const float* __restrict__ bg,
                       float* __restrict__ H4, int n) {
    __shared__ float sc[4][GCAP * 4];   // [w][e*4+h]
    __shared__ int   srcb[4][GCAP];
    __shared__ float wb[4][128];
    int w = threadIdx.x >> 6;
    int node = blockIdx.x * 4 + w;
    if (node >= n) return;
    int lane = threadIdx.x & 63;
    int beg = rowptr[node];
    int cnt = deg[node];
    bool fits = (cnt <= GCAP);
    float4 ad4 = ((const float4*)a_d)[node];
    float m0 = -1e30f, m1 = -1e30f, m2 = -1e30f, m3 = -1e30f;
    if (fits) {
        for (int e = lane; e < cnt; e += 64) {
            int s = csrc[beg + e];
            srcb[w][e] = s;
            float4 as = ((const float4*)a_s)[s];
            float e0 = lrelu(as.x + ad4.x);
            float e1 = lrelu(as.y + ad4.y);
            float e2 = lrelu(as.z + ad4.z);
            float e3 = lrelu(as.w + ad4.w);
            *(float4*)&sc[w][e * 4] = make_float4(e0, e1, e2, e3);
            m0 = fmaxf(m0, e0); m1 = fmaxf(m1, e1);
            m2 = fmaxf(m2, e2); m3 = fmaxf(m3, e3);
        }
    } else {
        for (int e = lane; e < cnt; e += 64) {
            int s = csrc[beg + e];
            float4 as = ((const float4*)a_s)[s];
            m0 = fmaxf(m0, lrelu(as.x + ad4.x));
            m1 = fmaxf(m1, lrelu(as.y + ad4.y));
            m2 = fmaxf(m2, lrelu(as.z + ad4.z));
            m3 = fmaxf(m3, lrelu(as.w + ad4.w));
        }
    }
#pragma unroll
    for (int o = 1; o < 64; o <<= 1) {
        m0 = fmaxf(m0, __shfl_xor(m0, o));
        m1 = fmaxf(m1, __shfl_xor(m1, o));
        m2 = fmaxf(m2, __shfl_xor(m2, o));
        m3 = fmaxf(m3, __shfl_xor(m3, o));
    }
    float s0 = 0.f, s1 = 0.f, s2 = 0.f, s3 = 0.f;
    if (fits) {
        for (int e = lane; e < cnt; e += 64) {
            float4 sv = *(float4*)&sc[w][e * 4];
            float p0 = __expf(sv.x - m0);
            float p1 = __expf(sv.y - m1);
            float p2 = __expf(sv.z - m2);
            float p3 = __expf(sv.w - m3);
            *(float4*)&sc[w][e * 4] = make_float4(p0, p1, p2, p3);
            s0 += p0; s1 += p1; s2 += p2; s3 += p3;
        }
    } else {
        for (int e = lane; e < cnt; e += 64) {
            int s = csrc[beg + e];
            float4 as = ((const float4*)a_s)[s];
            s0 += __expf(lrelu(as.x + ad4.x) - m0);
            s1 += __expf(lrelu(as.y + ad4.y) - m1);
            s2 += __expf(lrelu(as.z + ad4.z) - m2);
            s3 += __expf(lrelu(as.w + ad4.w) - m3);
        }
    }
#pragma unroll
    for (int o = 1; o < 64; o <<= 1) {
        s0 += __shfl_xor(s0, o);
        s1 += __shfl_xor(s1, o);
        s2 += __shfl_xor(s2, o);
        s3 += __shfl_xor(s3, o);
    }
    float inv0 = 0.25f / s0, inv1 = 0.25f / s1, inv2 = 0.25f / s2, inv3 = 0.25f / s3;
    // phase 2: quarter-wave per edge; lane -> q=lane>>4 (edge offset), k=lane&15 (dims 2k,2k+1)
    int q = lane >> 4;
    int k = lane & 15;
    float acc[8];
#pragma unroll
    for (int j = 0; j < 8; ++j) acc[j] = 0.f;
    if (fits) {
        int i = q;
        for (; i + 4 < cnt; i += 8) {
            int sA = srcb[w][i];
            int sB = srcb[w][i + 4];
            halfv2 xA = *(const halfv2*)(H3h + (long long)sA * 32 + 2 * k);
            halfv2 xB = *(const halfv2*)(H3h + (long long)sB * 32 + 2 * k);
            float4 wA = *(float4*)&sc[w][i * 4];
            float4 wB = *(float4*)&sc[w][(i + 4) * 4];
            float a0 = (float)xA[0], a1 = (float)xA[1];
            float b0 = (float)xB[0], b1 = (float)xB[1];
            acc[0] += wA.x * a0 + wB.x * b0; acc[1] += wA.x * a1 + wB.x * b1;
            acc[2] += wA.y * a0 + wB.y * b0; acc[3] += wA.y * a1 + wB.y * b1;
            acc[4] += wA.z * a0 + wB.z * b0; acc[5] += wA.z * a1 + wB.z * b1;
            acc[6] += wA.w * a0 + wB.w * b0; acc[7] += wA.w * a1 + wB.w * b1;
        }
        if (i < cnt) {
            int s = srcb[w][i];
            halfv2 xv = *(const halfv2*)(H3h + (long long)s * 32 + 2 * k);
            float4 wv = *(float4*)&sc[w][i * 4];
            float x0 = (float)xv[0], x1 = (float)xv[1];
            acc[0] += wv.x * x0; acc[1] += wv.x * x1;
            acc[2] += wv.y * x0; acc[3] += wv.y * x1;
            acc[4] += wv.z * x0; acc[5] += wv.z * x1;
            acc[6] += wv.w * x0; acc[7] += wv.w * x1;
        }
    } else {
        for (int i = q; i < cnt; i += 4) {
            int s = csrc[beg + i];
            float4 as = ((const float4*)a_s)[s];
            float p0 = __expf(lrelu(as.x + ad4.x) - m0);
            float p1 = __expf(lrelu(as.y + ad4.y) - m1);
            float p2 = __expf(lrelu(as.z + ad4.z) - m2);
            float p3 = __expf(lrelu(as.w + ad4.w) - m3);
            halfv2 xv = *(const halfv2*)(H3h + (long long)s * 32 + 2 * k);
            float x0 = (float)xv[0], x1 = (float)xv[1];
            acc[0] += p0 * x0; acc[1] += p0 * x1;
            acc[2] += p1 * x0; acc[3] += p1 * x1;
            acc[4] += p2 * x0; acc[5] += p2 * x1;
            acc[6] += p3 * x0; acc[7] += p3 * x1;
        }
    }
#pragma unroll
    for (int o = 16; o < 64; o <<= 1) {
#pragma unroll
        for (int j = 0; j < 8; ++j) acc[j] += __shfl_xor(acc[j], o);
    }
    if (q == 0) {
        float invh[4] = {inv0, inv1, inv2, inv3};
#pragma unroll
        for (int h = 0; h < 4; ++h) {
            wb[w][h * 32 + 2 * k]     = acc[h * 2]     * invh[h];
            wb[w][h * 32 + 2 * k + 1] = acc[h * 2 + 1] * invh[h];
        }
    }
    // epilogue: out[d] = relu(sum_j wb[j]*Wg[(j&31)*128+(j>>5)*32+d] + bg[d])
    int d = lane & 31;
    int h0 = lane >> 5;
    int half_ = h0 * 64;
    float o = 0.f;
#pragma unroll
    for (int j = 0; j < 64; ++j) {
        int jj = half_ + j;
        o += wb[w][jj] * Wg[(jj & 31) * 128 + (jj >> 5) * 32 + d];
    }
    o += __shfl_xor(o, 32);
    if (lane < 32)
        H4[(long long)node * 32 + d] = fmaxf(o + bg[d], 0.f);
}

// ===================== pool =====================
__global__ void k_pool_init(float* __restrict__ pooled, float* __restrict__ cnt) {
    int i = blockIdx.x * blockDim.x + threadIdx.x;
    if (i < NGRAPH * 32) pooled[i] = 0.f;
    if (i < NGRAPH) cnt[i] = 0.f;
}
__global__ void k_pool2(const float* __restrict__ h, const int* __restrict__ batch,
                        float* __restrict__ pooled, float* __restrict__ cnt, int n) {
    __shared__ float lp[NGRAPH * 32];
    __shared__ float lc[NGRAPH];
    int tid = threadIdx.x;
    for (int i = tid; i < NGRAPH * 32; i += 256) lp[i] = 0.f;
    for (int i = tid; i < NGRAPH; i += 256) lc[i] = 0.f;
    __syncthreads();
    int per = (n + gridDim.x - 1) / gridDim.x;
    int lo = blockIdx.x * per;
    int hi = min(n, lo + per);
    for (long long i = (long long)lo * 32 + tid; i < (long long)hi * 32; i += 256) {
        int ni = (int)(i >> 5), dd = (int)(i & 31);
        int b = batch[ni];
        atomicAdd(&lp[b * 32 + dd], h[i]);
        if (dd == 0) atomicAdd(&lc[b], 1.f);
    }
    __syncthreads();
    for (int i = tid; i < NGRAPH * 32; i += 256)
        if (lp[i] != 0.f) atomicAdd(&pooled[i], lp[i]);
    for (int i = tid; i < NGRAPH; i += 256)
        if (lc[i] != 0.f) atomicAdd(&cnt[i], lc[i]);
}

// ===================== classifier =====================
__global__ void k_classifier(const float* __restrict__ pooled, const float* __restrict__ cnt,
                             const float* __restrict__ Wc1, const float* __restrict__ bc1,
                             const float* __restrict__ Wc2, const float* __restrict__ bc2,
                             float* __restrict__ out) {
    __shared__ float pl[NGRAPH * 32];
    __shared__ float t1[NGRAPH * 16];
    int tid = threadIdx.x;
    for (int i = tid; i < NGRAPH * 32; i += blockDim.x) {
        int g = i >> 5;
        pl[i] = pooled[i] / fmaxf(cnt[g], 1.f);
    }
    __syncthreads();
    for (int i = tid; i < NGRAPH * 16; i += blockDim.x) {
        int g = i >> 4, c = i & 15;
        float acc = bc1[c];
#pragma unroll
        for (int d = 0; d < 32; ++d) acc += pl[g * 32 + d] * Wc1[d * 16 + c];
        t1[i] = fmaxf(acc, 0.f);
    }
    __syncthreads();
    for (int i = tid; i < NGRAPH * 5; i += blockDim.x) {
        int g = i / 5, c = i % 5;
        float acc = bc2[c];
#pragma unroll
        for (int k = 0; k < 16; ++k) acc += t1[g * 16 + k] * Wc2[k * 5 + c];
        out[i] = acc;
    }
}

// ===================== launch =====================
static inline dim3 gsz(long long work, int block = 256) {
    long long g = (work + block - 1) / block;
    if (g > 262144) g = 262144;
    if (g < 1) g = 1;
    return dim3((unsigned)g);
}

extern "C" void kernel_launch(void* const* d_in, const int* in_sizes, int n_in,
                              void* d_out, int out_size, void* d_ws, size_t ws_size,
                              hipStream_t stream) {
    const float* x     = (const float*)d_in[0];
    const int*   ei    = (const int*)d_in[1];
    const int*   batch = (const int*)d_in[2];
    const float* W1 = (const float*)d_in[3];  const float* b1 = (const float*)d_in[4];
    const float* W2 = (const float*)d_in[5];  const float* b2 = (const float*)d_in[6];
    const float* W3 = (const float*)d_in[7];  const float* b3 = (const float*)d_in[8];
    const float* g1 = (const float*)d_in[9];  const float* be1 = (const float*)d_in[10];
    const float* m1 = (const float*)d_in[11]; const float* v1  = (const float*)d_in[12];
    const float* g2 = (const float*)d_in[13]; const float* be2 = (const float*)d_in[14];
    const float* m2 = (const float*)d_in[15]; const float* v2  = (const float*)d_in[16];
    const float* g3 = (const float*)d_in[17]; const float* be3 = (const float*)d_in[18];
    const float* m3 = (const float*)d_in[19]; const float* v3  = (const float*)d_in[20];
    const float* Wg  = (const float*)d_in[21];
    const float* ags = (const float*)d_in[22];
    const float* agd = (const float*)d_in[23];
    const float* bg  = (const float*)d_in[24];
    const float* Wc1 = (const float*)d_in[25]; const float* bc1 = (const float*)d_in[26];
    const float* Wc2 = (const float*)d_in[27]; const float* bc2 = (const float*)d_in[28];
    float* out = (float*)d_out;

    const int N = in_sizes[0] / 64;
    const int E = in_sizes[1] / 2;
    const int* esrc = ei;
    const int* edst = ei + E;
    const int NB = (N + NPBK - 1) >> BSHIFT;

    size_t off = 0;
    auto take = [&](size_t bytes) -> void* {
        void* p = (char*)d_ws + off;
        off += bytes;
        off = (off + 255) & ~(size_t)255;
        return p;
    };
    int*    deg    = (int*)take((size_t)N * 4);
    float*  dinv   = (float*)take((size_t)N * 4);
    int*    rowptr = (int*)take((size_t)N * 4);
    int*    bsize  = (int*)take((size_t)1024 * 4);
    int*    bbase  = (int*)take((size_t)1024 * 4);
    int*    gcur   = (int*)take((size_t)1024 * 4);
    float*  wsd    = (float*)take((size_t)256 * 4);
    int*    csrc   = (int*)take((size_t)(E + N) * 4);
    half_t* bufAh  = (half_t*)take((size_t)N * 64 * 2);  // xh -> A2h -> A3h -> H4(f32,N*32)
    half_t* bufBh  = (half_t*)take((size_t)N * 64 * 2);  // Xa -> H2
    float*  bufC   = (float*)take((size_t)N * 128 * 4);  // binned(u32,E) ; H1h (half,N*128)
    half_t* h3h    = (half_t*)take((size_t)N * 32 * 2);
    float*  a_s    = (float*)take((size_t)N * 4 * 4);
    float*  a_d    = (float*)take((size_t)N * 4 * 4);
    float*  pooled = (float*)take((size_t)NGRAPH * 32 * 4);
    float*  cnt    = (float*)take((size_t)NGRAPH * 4);
    unsigned* binned = (unsigned*)bufC;
    half_t* H1h    = (half_t*)bufC;   // binned dead before H1 written
    float*  H4     = (float*)bufAh;   // N*32 f32 == N*64 half bytes; A3h dead before gat4 writes
    (void)ws_size; (void)n_in; (void)out_size;

    const dim3 B256(256);

    // ---- binned CSR build ----
    hipMemsetAsync(bsize, 0, (size_t)NB * 4, stream);
    hipLaunchKernelGGL(k_bin_count, dim3(512), B256, 0, stream, edst, bsize, E, NB);
    hipLaunchKernelGGL(k_bucket_scan, dim3(1), dim3(64), 0, stream, bsize, bbase, gcur, NB);
    hipLaunchKernelGGL(k_bin_write, dim3(512), B256, 0, stream, esrc, edst, gcur, binned, E, NB);
    hipLaunchKernelGGL(k_csr_build, dim3(NB), B256, 0, stream,
                       binned, bbase, bsize, rowptr, deg, dinv, csrc, N);
    hipLaunchKernelGGL(k_wsd, dim3(1), dim3(128), 0, stream, Wg, ags, agd, wsd);

    // ---- layer 1: xh = half(x*dinv); Xa = half(dinv*sum(xh)); H1h = half(relu(BN(Xa@W1+b1)))
    hipLaunchKernelGGL(k_cvt_xh, gsz((long long)N * 8), B256, 0, stream, x, dinv, bufAh, N);
    hipLaunchKernelGGL((k_agg4h<64, 0>), dim3((N + 3) / 4), B256, 0, stream,
                       bufAh, rowptr, deg, csrc, dinv,
                       nullptr, nullptr, nullptr, nullptr, nullptr, bufBh, N);
    hipLaunchKernelGGL((k_matmulh<64, 128, 1>), dim3((N + 7) / 8), B256, 0, stream,
                       bufBh, W1, H1h, N, b1, g1, be1, m1, v1, nullptr);
    // ---- layer 2: A2h = half((H1@W2)*dinv); H2 = half(relu(BN(dinv*sum(A2h)+b2)))
    hipLaunchKernelGGL((k_matmulh<128, 64, 2>), dim3((N + 15) / 16), B256, 0, stream,
                       H1h, W2, bufAh, N, nullptr, nullptr, nullptr, nullptr, nullptr, dinv);
    hipLaunchKernelGGL((k_agg4h<64, 1>), dim3((N + 3) / 4), B256, 0, stream,
                       bufAh, rowptr, deg, csrc, dinv, b2, g2, be2, m2, v2, bufBh, N);
    // ---- layer 3: A3h = half((H2@W3)*dinv); H3h + a_s/a_d fused
    hipLaunchKernelGGL((k_matmulh<64, 32, 2>), dim3((N + 31) / 32), B256, 0, stream,
                       bufBh, W3, bufAh, N, nullptr, nullptr, nullptr, nullptr, nullptr, dinv);
    hipLaunchKernelGGL(k_agg_att, dim3((N + 3) / 4), B256, 0, stream,
                       bufAh, rowptr, deg, csrc, dinv, b3, g3, be3, m3, v3,
                       wsd, h3h, a_s, a_d, N);

    // ---- GAT (writes H4 f32 into bufAh region; A3h dead)
    hipLaunchKernelGGL(k_gat4, dim3((N + 3) / 4), B256, 0, stream,
                       h3h, a_s, a_d, rowptr, deg, csrc, Wg, bg, H4, N);

    // ---- pool + classifier
    hipLaunchKernelGGL(k_pool_init, dim3(9), B256, 0, stream, pooled, cnt);
    hipLaunchKernelGGL(k_pool2, dim3(128), B256, 0, stream, H4, batch, pooled, cnt, N);
    hipLaunchKernelGGL(k_classifier, dim3(1), B256, 0, stream, pooled, cnt, Wc1, bc1, Wc2, bc2, out);
}